// Round 1
// baseline (1550.164 us; speedup 1.0000x reference)
//
#include <hip/hip_runtime.h>
#include <hip/hip_bf16.h>

#define NEG_SLOPE 0.2f

__device__ __forceinline__ unsigned fflip(float f) {
    unsigned u = __float_as_uint(f);
    return (u & 0x80000000u) ? ~u : (u | 0x80000000u);
}
__device__ __forceinline__ float funflip(unsigned u) {
    u = (u & 0x80000000u) ? (u & 0x7FFFFFFFu) : ~u;
    return __uint_as_float(u);
}
__device__ __forceinline__ float elu1f(float v) {
    return v > 0.f ? v : expm1f(v);
}

// ---------------- GEMM1: h1 = x @ W1 (128->128), fused a_src1/a_dst1 ----------------
__global__ __launch_bounds__(128) void k_gemm1(
    const float* __restrict__ x, const float* __restrict__ W,
    const float* __restrict__ att_s, const float* __restrict__ att_d,
    float* __restrict__ h1, float* __restrict__ as1, float* __restrict__ ad1, int N)
{
    __shared__ float sW[32][128];
    __shared__ float sX[16][32];
    const int t = threadIdx.x;          // output column 0..127
    const int row0 = blockIdx.x * 16;

    float acc[16];
#pragma unroll
    for (int r = 0; r < 16; r++) acc[r] = 0.f;

    for (int k0 = 0; k0 < 128; k0 += 32) {
        __syncthreads();
#pragma unroll
        for (int i = 0; i < 32; i++) sW[i][t] = W[(k0 + i) * 128 + t];
#pragma unroll
        for (int i = 0; i < 4; i++) {
            int idx = i * 128 + t;              // 0..511
            int r = idx >> 5, c = idx & 31;
            int row = row0 + r;
            sX[r][c] = (row < N) ? x[(long long)row * 128 + k0 + c] : 0.f;
        }
        __syncthreads();
#pragma unroll
        for (int kk = 0; kk < 32; kk++) {
            float wv = sW[kk][t];
#pragma unroll
            for (int r = 0; r < 16; r++) acc[r] = fmaf(sX[r][kk], wv, acc[r]);
        }
    }

    const float av_s = att_s[t], av_d = att_d[t];
    const int lane = t & 31;
    const int head = t >> 5;
#pragma unroll
    for (int r = 0; r < 16; r++) {
        int row = row0 + r;
        if (row >= N) break;                    // uniform across block
        float v = acc[r];
        h1[(long long)row * 128 + t] = v;
        float s = v * av_s, d = v * av_d;
#pragma unroll
        for (int off = 16; off > 0; off >>= 1) {
            s += __shfl_xor(s, off, 32);
            d += __shfl_xor(d, off, 32);
        }
        if (lane == 0) { as1[row * 4 + head] = s; ad1[row * 4 + head] = d; }
    }
}

// ---------------- GEMM2: h2 = elu(out1+b1) @ W2 (128->32), fused a_src2/a_dst2 -------
__global__ __launch_bounds__(256) void k_gemm2(
    const float* __restrict__ xin, const float* __restrict__ W,
    const float* __restrict__ b1,
    const float* __restrict__ att_s, const float* __restrict__ att_d,
    float* __restrict__ h2, float* __restrict__ as2, float* __restrict__ ad2, int N)
{
    __shared__ float sW[128][32];
    __shared__ float sX[32][128];
    const int t = threadIdx.x;
    const int row0 = blockIdx.x * 32;

#pragma unroll
    for (int i = 0; i < 16; i++) {
        int idx = i * 256 + t;                  // 0..4095
        sW[idx >> 5][idx & 31] = W[idx];
    }
#pragma unroll
    for (int i = 0; i < 16; i++) {
        int idx = i * 256 + t;
        int r = idx >> 7, c = idx & 127;
        int row = row0 + r;
        float v = (row < N) ? xin[(long long)row * 128 + c] + b1[c] : 0.f;
        sX[r][c] = elu1f(v);
    }
    __syncthreads();

    const int c = t & 31, rsub = t >> 5;
    const float av_s = att_s[c], av_d = att_d[c];
#pragma unroll
    for (int p = 0; p < 4; p++) {
        int r = p * 8 + rsub;
        int row = row0 + r;
        float a = 0.f;
#pragma unroll
        for (int k = 0; k < 128; k++) a = fmaf(sX[r][k], sW[k][c], a);
        if (row < N) {
            h2[(long long)row * 32 + c] = a;
            float s = a * av_s, d = a * av_d;
#pragma unroll
            for (int off = 16; off > 0; off >>= 1) {
                s += __shfl_xor(s, off, 32);
                d += __shfl_xor(d, off, 32);
            }
            if (c == 0) { as2[row] = s; ad2[row] = d; }
        }
    }
}

// ---------------- Edge pass A: e = lrelu(a_src[s]+a_dst[d]); segment max -------------
__global__ void k_edge_a(const int* __restrict__ ei, int E, int Et, int H,
                         const float* __restrict__ as, const float* __restrict__ ad,
                         float* __restrict__ ebuf, unsigned* __restrict__ m)
{
    int i = blockIdx.x * 256 + threadIdx.x;
    if (i >= Et) return;
    int s, d;
    if (i < E) { s = ei[i]; d = ei[E + i]; } else { s = i - E; d = s; }
    for (int h = 0; h < H; h++) {
        float e = as[s * H + h] + ad[d * H + h];
        e = e >= 0.f ? e : NEG_SLOPE * e;
        ebuf[(long long)i * H + h] = e;
        atomicMax(&m[d * H + h], fflip(e));
    }
}

// ---------------- Edge pass B: ex = exp(e - m[d]); segment sum -----------------------
__global__ void k_edge_b(const int* __restrict__ ei, int E, int Et, int H,
                         const unsigned* __restrict__ m,
                         float* __restrict__ ebuf, float* __restrict__ den)
{
    int i = blockIdx.x * 256 + threadIdx.x;
    if (i >= Et) return;
    int d = (i < E) ? ei[E + i] : i - E;
    for (int h = 0; h < H; h++) {
        float mx = funflip(m[d * H + h]);
        float ex = expf(ebuf[(long long)i * H + h] - mx);
        ebuf[(long long)i * H + h] = ex;
        atomicAdd(&den[d * H + h], ex);
    }
}

// ---------------- Edge pass C: out[d] += alpha * h[src] ------------------------------
template <int H>
__global__ void k_edge_c(const int* __restrict__ ei, int E, int Et,
                         const float* __restrict__ ebuf, const float* __restrict__ den,
                         const float* __restrict__ hin, float* __restrict__ out)
{
    long long gid = (long long)blockIdx.x * 256 + threadIdx.x;
    int c = (int)(gid & 31);
    long long eh = gid >> 5;
    if (eh >= (long long)Et * H) return;
    int i, h;
    if (H == 4) { i = (int)(eh >> 2); h = (int)(eh & 3); }
    else        { i = (int)eh; h = 0; }
    int s, d;
    if (i < E) { s = ei[i]; d = ei[E + i]; } else { s = i - E; d = s; }
    float alpha = ebuf[(long long)i * H + h] / (den[d * H + h] + 1e-16f);
    float v = alpha * hin[(long long)s * (H * 32) + h * 32 + c];
    atomicAdd(&out[(long long)d * (H * 32) + h * 32 + c], v);
}

// ---------------- Pool gate: hF = elu(out2+b2); gate MLP; segment max ----------------
__global__ __launch_bounds__(256) void k_pool_gate(
    const float* __restrict__ out2, const float* __restrict__ b2,
    const float* __restrict__ gw1, const float* __restrict__ gb1,
    const float* __restrict__ gw2, const float* __restrict__ gb2,
    const int* __restrict__ batch,
    float* __restrict__ hF, float* __restrict__ gate, unsigned* __restrict__ gm, int N)
{
    const int c = threadIdx.x & 31, g = threadIdx.x >> 5;
    const int n = blockIdx.x * 8 + g;
    if (n >= N) return;                          // uniform per 32-lane group
    float v = out2[(long long)n * 32 + c] + b2[c];
    v = elu1f(v);
    hF[(long long)n * 32 + c] = v;
    float t1 = gb1[c];
#pragma unroll
    for (int k = 0; k < 32; k++) {
        float hk = __shfl(v, k, 32);
        t1 = fmaf(hk, gw1[k * 32 + c], t1);
    }
    t1 = fmaxf(t1, 0.f);
    float gsum = t1 * gw2[c];
#pragma unroll
    for (int off = 16; off > 0; off >>= 1) gsum += __shfl_xor(gsum, off, 32);
    if (c == 0) {
        float gv = gsum + gb2[0];
        gate[n] = gv;
        atomicMax(&gm[batch[n]], fflip(gv));
    }
}

__global__ void k_pool_b(const int* __restrict__ batch, const unsigned* __restrict__ gm,
                         float* __restrict__ gate, float* __restrict__ gs, int N)
{
    int n = blockIdx.x * 256 + threadIdx.x;
    if (n >= N) return;
    int b = batch[n];
    float ge = expf(gate[n] - funflip(gm[b]));
    gate[n] = ge;
    atomicAdd(&gs[b], ge);
}

__global__ void k_pool_c(const int* __restrict__ batch, const float* __restrict__ gate,
                         const float* __restrict__ gs, const float* __restrict__ hF,
                         float* __restrict__ out, int N)
{
    int gid = blockIdx.x * 256 + threadIdx.x;
    int n = gid >> 5, c = gid & 31;
    if (n >= N) return;
    int b = batch[n];
    float w = gate[n] / (gs[b] + 1e-16f);
    atomicAdd(&out[b * 32 + c], w * hF[(long long)n * 32 + c]);
}

extern "C" void kernel_launch(void* const* d_in, const int* in_sizes, int n_in,
                              void* d_out, int out_size, void* d_ws, size_t ws_size,
                              hipStream_t stream)
{
    const float* x    = (const float*)d_in[0];
    const int*   ei   = (const int*)d_in[1];
    const int*   batch= (const int*)d_in[2];
    const float* W1   = (const float*)d_in[3];
    const float* as1w = (const float*)d_in[4];
    const float* ad1w = (const float*)d_in[5];
    const float* b1   = (const float*)d_in[6];
    const float* W2   = (const float*)d_in[7];
    const float* as2w = (const float*)d_in[8];
    const float* ad2w = (const float*)d_in[9];
    const float* b2   = (const float*)d_in[10];
    const float* gw1  = (const float*)d_in[11];
    const float* gb1  = (const float*)d_in[12];
    const float* gw2  = (const float*)d_in[13];
    const float* gb2  = (const float*)d_in[14];

    const int N  = in_sizes[2];          // batch has N elements
    const int E  = in_sizes[1] / 2;
    const int Et = E + N;

    float* ws = (float*)d_ws;
    size_t o = 0;
    float* h1   = ws + o; o += (size_t)N * 128;
    float* a_s1 = ws + o; o += (size_t)N * 4;
    float* a_d1 = ws + o; o += (size_t)N * 4;
    float* e1   = ws + o; o += (size_t)Et * 4;
    float* h2   = ws + o; o += (size_t)N * 32;
    float* a_s2 = ws + o; o += (size_t)N;
    float* a_d2 = ws + o; o += (size_t)N;
    float* e2   = ws + o; o += (size_t)Et;
    float* hF   = ws + o; o += (size_t)N * 32;
    float* gate = ws + o; o += (size_t)N;
    // ---- zeroed region (one memset) ----
    size_t zstart = o;
    float*    out1 = ws + o; o += (size_t)N * 128;
    unsigned* m1   = (unsigned*)(ws + o); o += (size_t)N * 4;
    float*    den1 = ws + o; o += (size_t)N * 4;
    float*    out2 = ws + o; o += (size_t)N * 32;
    unsigned* m2   = (unsigned*)(ws + o); o += (size_t)N;
    float*    den2 = ws + o; o += (size_t)N;
    unsigned* gm   = (unsigned*)(ws + o); o += 64;
    float*    gs   = ws + o; o += 64;
    size_t zbytes = (o - zstart) * sizeof(float);

    hipMemsetAsync(ws + zstart, 0, zbytes, stream);
    hipMemsetAsync(d_out, 0, (size_t)out_size * sizeof(float), stream);

    // ---- GAT layer 1 ----
    k_gemm1<<<(N + 15) / 16, 128, 0, stream>>>(x, W1, as1w, ad1w, h1, a_s1, a_d1, N);
    k_edge_a<<<(Et + 255) / 256, 256, 0, stream>>>(ei, E, Et, 4, a_s1, a_d1, e1, m1);
    k_edge_b<<<(Et + 255) / 256, 256, 0, stream>>>(ei, E, Et, 4, m1, e1, den1);
    {
        long long tt = (long long)Et * 4 * 32;
        k_edge_c<4><<<(int)((tt + 255) / 256), 256, 0, stream>>>(ei, E, Et, e1, den1, h1, out1);
    }

    // ---- GAT layer 2 (elu(out1+b1) fused into gemm2 load) ----
    k_gemm2<<<(N + 31) / 32, 256, 0, stream>>>(out1, W2, b1, as2w, ad2w, h2, a_s2, a_d2, N);
    k_edge_a<<<(Et + 255) / 256, 256, 0, stream>>>(ei, E, Et, 1, a_s2, a_d2, e2, m2);
    k_edge_b<<<(Et + 255) / 256, 256, 0, stream>>>(ei, E, Et, 1, m2, e2, den2);
    {
        long long tt = (long long)Et * 32;
        k_edge_c<1><<<(int)((tt + 255) / 256), 256, 0, stream>>>(ei, E, Et, e2, den2, h2, out2);
    }

    // ---- attentional pooling ----
    k_pool_gate<<<(N + 7) / 8, 256, 0, stream>>>(out2, b2, gw1, gb1, gw2, gb2, batch,
                                                 hF, gate, gm, N);
    k_pool_b<<<(N + 255) / 256, 256, 0, stream>>>(batch, gm, gate, gs, N);
    k_pool_c<<<((N * 32) + 255) / 256, 256, 0, stream>>>(batch, gate, gs, hF, (float*)d_out, N);
}

// Round 2
// 1103.477 us; speedup vs baseline: 1.4048x; 1.4048x over previous
//
#include <hip/hip_runtime.h>
#include <hip/hip_bf16.h>

#define NEG_SLOPE 0.2f

__device__ __forceinline__ unsigned fflip(float f) {
    unsigned u = __float_as_uint(f);
    return (u & 0x80000000u) ? ~u : (u | 0x80000000u);
}
__device__ __forceinline__ float funflip(unsigned u) {
    u = (u & 0x80000000u) ? (u & 0x7FFFFFFFu) : ~u;
    return __uint_as_float(u);
}
__device__ __forceinline__ float elu1f(float v) {
    return v > 0.f ? v : expm1f(v);
}

// ======================= CSR build (by dst) =======================
__global__ void k_deg(const int* __restrict__ ei, int E, int Et, int* __restrict__ deg)
{
    int i = blockIdx.x * 256 + threadIdx.x;
    if (i >= Et) return;
    int d = (i < E) ? ei[E + i] : i - E;
    atomicAdd(&deg[d], 1);
}

__global__ __launch_bounds__(256) void k_scan1(const int* __restrict__ deg, int N,
                                               int* __restrict__ row, int* __restrict__ bsum)
{
    __shared__ int s[256];
    int i = blockIdx.x * 256 + threadIdx.x;
    int v = (i < N) ? deg[i] : 0;
    s[threadIdx.x] = v;
    __syncthreads();
#pragma unroll
    for (int off = 1; off < 256; off <<= 1) {
        int t = (threadIdx.x >= off) ? s[threadIdx.x - off] : 0;
        __syncthreads();
        s[threadIdx.x] += t;
        __syncthreads();
    }
    if (i < N) row[i] = s[threadIdx.x] - v;          // exclusive
    if (threadIdx.x == 255) bsum[blockIdx.x] = s[255];
}

__global__ __launch_bounds__(256) void k_scan2(int* __restrict__ bsum, int nb)
{
    __shared__ int s[256];
    int v = (threadIdx.x < nb) ? bsum[threadIdx.x] : 0;
    s[threadIdx.x] = v;
    __syncthreads();
#pragma unroll
    for (int off = 1; off < 256; off <<= 1) {
        int t = (threadIdx.x >= off) ? s[threadIdx.x - off] : 0;
        __syncthreads();
        s[threadIdx.x] += t;
        __syncthreads();
    }
    if (threadIdx.x < nb) bsum[threadIdx.x] = s[threadIdx.x] - v;   // exclusive
}

__global__ void k_scan3(int* __restrict__ row, const int* __restrict__ bsum,
                        int N, int Et, int* __restrict__ cursor)
{
    int i = blockIdx.x * 256 + threadIdx.x;
    if (i < N) {
        int r = row[i] + bsum[blockIdx.x];
        row[i] = r;
        cursor[i] = r;
    }
    if (i == 0) row[N] = Et;
}

__global__ void k_scatter(const int* __restrict__ ei, int E, int Et,
                          int* __restrict__ cursor, int* __restrict__ esrc)
{
    int i = blockIdx.x * 256 + threadIdx.x;
    if (i >= Et) return;
    int s, d;
    if (i < E) { s = ei[i]; d = ei[E + i]; } else { s = i - E; d = s; }
    int pos = atomicAdd(&cursor[d], 1);
    esrc[pos] = s;
}

// ---------------- GEMM1: h1 = x @ W1 (128->128), fused a_src1/a_dst1 ----------------
__global__ __launch_bounds__(128) void k_gemm1(
    const float* __restrict__ x, const float* __restrict__ W,
    const float* __restrict__ att_s, const float* __restrict__ att_d,
    float* __restrict__ h1, float* __restrict__ as1, float* __restrict__ ad1, int N)
{
    __shared__ float sW[32][128];
    __shared__ float sX[16][32];
    const int t = threadIdx.x;          // output column 0..127
    const int row0 = blockIdx.x * 16;

    float acc[16];
#pragma unroll
    for (int r = 0; r < 16; r++) acc[r] = 0.f;

    for (int k0 = 0; k0 < 128; k0 += 32) {
        __syncthreads();
#pragma unroll
        for (int i = 0; i < 32; i++) sW[i][t] = W[(k0 + i) * 128 + t];
#pragma unroll
        for (int i = 0; i < 4; i++) {
            int idx = i * 128 + t;              // 0..511
            int r = idx >> 5, c = idx & 31;
            int row = row0 + r;
            sX[r][c] = (row < N) ? x[(long long)row * 128 + k0 + c] : 0.f;
        }
        __syncthreads();
#pragma unroll
        for (int kk = 0; kk < 32; kk++) {
            float wv = sW[kk][t];
#pragma unroll
            for (int r = 0; r < 16; r++) acc[r] = fmaf(sX[r][kk], wv, acc[r]);
        }
    }

    const float av_s = att_s[t], av_d = att_d[t];
    const int lane = t & 31;
    const int head = t >> 5;
#pragma unroll
    for (int r = 0; r < 16; r++) {
        int row = row0 + r;
        if (row >= N) break;                    // uniform across block
        float v = acc[r];
        h1[(long long)row * 128 + t] = v;
        float s = v * av_s, d = v * av_d;
#pragma unroll
        for (int off = 16; off > 0; off >>= 1) {
            s += __shfl_xor(s, off, 32);
            d += __shfl_xor(d, off, 32);
        }
        if (lane == 0) { as1[row * 4 + head] = s; ad1[row * 4 + head] = d; }
    }
}

// ---------------- GEMM2: h2 = elu(out1+b1) @ W2 (128->32), fused a_src2/a_dst2 -------
__global__ __launch_bounds__(256) void k_gemm2(
    const float* __restrict__ xin, const float* __restrict__ W,
    const float* __restrict__ b1,
    const float* __restrict__ att_s, const float* __restrict__ att_d,
    float* __restrict__ h2, float* __restrict__ as2, float* __restrict__ ad2, int N)
{
    __shared__ float sW[128][32];
    __shared__ float sX[32][128];
    const int t = threadIdx.x;
    const int row0 = blockIdx.x * 32;

#pragma unroll
    for (int i = 0; i < 16; i++) {
        int idx = i * 256 + t;                  // 0..4095
        sW[idx >> 5][idx & 31] = W[idx];
    }
#pragma unroll
    for (int i = 0; i < 16; i++) {
        int idx = i * 256 + t;
        int r = idx >> 7, c = idx & 127;
        int row = row0 + r;
        float v = (row < N) ? xin[(long long)row * 128 + c] + b1[c] : 0.f;
        sX[r][c] = elu1f(v);
    }
    __syncthreads();

    const int c = t & 31, rsub = t >> 5;
    const float av_s = att_s[c], av_d = att_d[c];
#pragma unroll
    for (int p = 0; p < 4; p++) {
        int r = p * 8 + rsub;
        int row = row0 + r;
        float a = 0.f;
#pragma unroll
        for (int k = 0; k < 128; k++) a = fmaf(sX[r][k], sW[k][c], a);
        if (row < N) {
            h2[(long long)row * 32 + c] = a;
            float s = a * av_s, d = a * av_d;
#pragma unroll
            for (int off = 16; off > 0; off >>= 1) {
                s += __shfl_xor(s, off, 32);
                d += __shfl_xor(d, off, 32);
            }
            if (c == 0) { as2[row] = s; ad2[row] = d; }
        }
    }
}

// ========== Fused GAT aggregation, layer 1 (H=4, C=32): one wave per dst ==========
// Online softmax over the dst node's in-edges; lane handles cols lane*2, lane*2+1
// (both in head lane>>4). No atomics, coalesced 512B gather of h1[src] per edge.
__global__ __launch_bounds__(256) void k_agg1(
    const int* __restrict__ row, const int* __restrict__ esrc,
    const float* __restrict__ as, const float* __restrict__ ad,   // [N][4]
    const float* __restrict__ h,                                  // [N][128]
    float* __restrict__ out, int N)                               // [N][128]
{
    const int lane = threadIdx.x & 63;
    const int wid  = threadIdx.x >> 6;
    const int n = blockIdx.x * 4 + wid;
    if (n >= N) return;
    const int hsel = lane >> 4;                 // head of this lane's 2 columns

    const float4 ad4 = *(const float4*)&ad[n * 4];
    const float adh = hsel == 0 ? ad4.x : hsel == 1 ? ad4.y : hsel == 2 ? ad4.z : ad4.w;

    float m = -INFINITY, den = 0.f, acc0 = 0.f, acc1 = 0.f;
    const int e0 = row[n], e1 = row[n + 1];
    for (int e = e0; e < e1; ++e) {
        const int s = esrc[e];                  // broadcast
        const float4 as4 = *(const float4*)&as[s * 4];
        const float ash = hsel == 0 ? as4.x : hsel == 1 ? as4.y : hsel == 2 ? as4.z : as4.w;
        float ev = ash + adh;
        ev = ev >= 0.f ? ev : NEG_SLOPE * ev;
        const float mn = fmaxf(m, ev);
        const float r = __expf(m - mn);         // m=-inf first iter -> r=0
        const float w = __expf(ev - mn);
        const float2 hv = *(const float2*)&h[(long long)s * 128 + lane * 2];
        den  = fmaf(den, r, w);
        acc0 = fmaf(w, hv.x, acc0 * r);
        acc1 = fmaf(w, hv.y, acc1 * r);
        m = mn;
    }
    const float inv = 1.f / (den + 1e-16f);
    float2 o; o.x = acc0 * inv; o.y = acc1 * inv;
    *(float2*)&out[(long long)n * 128 + lane * 2] = o;
}

// ========== Fused GAT aggregation, layer 2 (H=1, C=32): one dst per 32 lanes ==========
__global__ __launch_bounds__(256) void k_agg2(
    const int* __restrict__ row, const int* __restrict__ esrc,
    const float* __restrict__ as, const float* __restrict__ ad,   // [N]
    const float* __restrict__ h,                                  // [N][32]
    float* __restrict__ out, int N)                               // [N][32]
{
    const int lane = threadIdx.x & 31;
    const int half = threadIdx.x >> 5;          // 0..7
    const int n = blockIdx.x * 8 + half;
    if (n >= N) return;

    const float adv = ad[n];
    float m = -INFINITY, den = 0.f, acc = 0.f;
    const int e0 = row[n], e1 = row[n + 1];
    for (int e = e0; e < e1; ++e) {
        const int s = esrc[e];
        float ev = as[s] + adv;
        ev = ev >= 0.f ? ev : NEG_SLOPE * ev;
        const float mn = fmaxf(m, ev);
        const float r = __expf(m - mn);
        const float w = __expf(ev - mn);
        const float hv = h[(long long)s * 32 + lane];
        den = fmaf(den, r, w);
        acc = fmaf(w, hv, acc * r);
        m = mn;
    }
    out[(long long)n * 32 + lane] = acc / (den + 1e-16f);
}

// ---------------- Pool gate: hF = elu(out2+b2); gate MLP; segment max ----------------
__global__ __launch_bounds__(256) void k_pool_gate(
    const float* __restrict__ out2, const float* __restrict__ b2,
    const float* __restrict__ gw1, const float* __restrict__ gb1,
    const float* __restrict__ gw2, const float* __restrict__ gb2,
    const int* __restrict__ batch,
    float* __restrict__ hF, float* __restrict__ gate, unsigned* __restrict__ gm, int N)
{
    const int c = threadIdx.x & 31, g = threadIdx.x >> 5;
    const int n = blockIdx.x * 8 + g;
    if (n >= N) return;
    float v = out2[(long long)n * 32 + c] + b2[c];
    v = elu1f(v);
    hF[(long long)n * 32 + c] = v;
    float t1 = gb1[c];
#pragma unroll
    for (int k = 0; k < 32; k++) {
        float hk = __shfl(v, k, 32);
        t1 = fmaf(hk, gw1[k * 32 + c], t1);
    }
    t1 = fmaxf(t1, 0.f);
    float gsum = t1 * gw2[c];
#pragma unroll
    for (int off = 16; off > 0; off >>= 1) gsum += __shfl_xor(gsum, off, 32);
    if (c == 0) {
        float gv = gsum + gb2[0];
        gate[n] = gv;
        atomicMax(&gm[batch[n]], fflip(gv));
    }
}

__global__ void k_pool_b(const int* __restrict__ batch, const unsigned* __restrict__ gm,
                         float* __restrict__ gate, float* __restrict__ gs, int N)
{
    int n = blockIdx.x * 256 + threadIdx.x;
    if (n >= N) return;
    int b = batch[n];
    float ge = expf(gate[n] - funflip(gm[b]));
    gate[n] = ge;
    atomicAdd(&gs[b], ge);
}

__global__ void k_pool_c(const int* __restrict__ batch, const float* __restrict__ gate,
                         const float* __restrict__ gs, const float* __restrict__ hF,
                         float* __restrict__ out, int N)
{
    int gid = blockIdx.x * 256 + threadIdx.x;
    int n = gid >> 5, c = gid & 31;
    if (n >= N) return;
    int b = batch[n];
    float w = gate[n] / (gs[b] + 1e-16f);
    atomicAdd(&out[b * 32 + c], w * hF[(long long)n * 32 + c]);
}

extern "C" void kernel_launch(void* const* d_in, const int* in_sizes, int n_in,
                              void* d_out, int out_size, void* d_ws, size_t ws_size,
                              hipStream_t stream)
{
    const float* x    = (const float*)d_in[0];
    const int*   ei   = (const int*)d_in[1];
    const int*   batch= (const int*)d_in[2];
    const float* W1   = (const float*)d_in[3];
    const float* as1w = (const float*)d_in[4];
    const float* ad1w = (const float*)d_in[5];
    const float* b1   = (const float*)d_in[6];
    const float* W2   = (const float*)d_in[7];
    const float* as2w = (const float*)d_in[8];
    const float* ad2w = (const float*)d_in[9];
    const float* b2   = (const float*)d_in[10];
    const float* gw1  = (const float*)d_in[11];
    const float* gb1  = (const float*)d_in[12];
    const float* gw2  = (const float*)d_in[13];
    const float* gb2  = (const float*)d_in[14];

    const int N  = in_sizes[2];
    const int E  = in_sizes[1] / 2;
    const int Et = E + N;
    const int nb = (N + 255) / 256;      // scan blocks (196 for N=50000, fits k_scan2)

    float* ws = (float*)d_ws;
    size_t o = 0;
    float* h1   = ws + o; o += (size_t)N * 128;
    float* out1 = ws + o; o += (size_t)N * 128;
    float* h2   = ws + o; o += (size_t)N * 32;
    float* out2 = ws + o; o += (size_t)N * 32;
    float* hF   = ws + o; o += (size_t)N * 32;
    float* a_s1 = ws + o; o += (size_t)N * 4;
    float* a_d1 = ws + o; o += (size_t)N * 4;
    float* a_s2 = ws + o; o += (size_t)N;
    float* a_d2 = ws + o; o += (size_t)N;
    float* gate = ws + o; o += (size_t)N;
    int*   rowp = (int*)(ws + o); o += (size_t)N + 1;
    int*   curs = (int*)(ws + o); o += (size_t)N;
    int*   esrc = (int*)(ws + o); o += (size_t)Et;
    int*   bsum = (int*)(ws + o); o += 256;
    // ---- zeroed region (one memset): deg, gm, gs ----
    size_t zstart = o;
    int*      deg = (int*)(ws + o); o += (size_t)N;
    unsigned* gm  = (unsigned*)(ws + o); o += 64;
    float*    gs  = ws + o; o += 64;
    size_t zbytes = (o - zstart) * sizeof(float);

    hipMemsetAsync(ws + zstart, 0, zbytes, stream);
    hipMemsetAsync(d_out, 0, (size_t)out_size * sizeof(float), stream);

    // ---- CSR build (shared by both layers) ----
    k_deg    <<<(Et + 255) / 256, 256, 0, stream>>>(ei, E, Et, deg);
    k_scan1  <<<nb, 256, 0, stream>>>(deg, N, rowp, bsum);
    k_scan2  <<<1, 256, 0, stream>>>(bsum, nb);
    k_scan3  <<<nb, 256, 0, stream>>>(rowp, bsum, N, Et, curs);
    k_scatter<<<(Et + 255) / 256, 256, 0, stream>>>(ei, E, Et, curs, esrc);

    // ---- GAT layer 1 ----
    k_gemm1<<<(N + 15) / 16, 128, 0, stream>>>(x, W1, as1w, ad1w, h1, a_s1, a_d1, N);
    k_agg1 <<<(N + 3) / 4, 256, 0, stream>>>(rowp, esrc, a_s1, a_d1, h1, out1, N);

    // ---- GAT layer 2 (elu(out1+b1) fused into gemm2 load) ----
    k_gemm2<<<(N + 31) / 32, 256, 0, stream>>>(out1, W2, b1, as2w, ad2w, h2, a_s2, a_d2, N);
    k_agg2 <<<(N + 7) / 8, 256, 0, stream>>>(rowp, esrc, a_s2, a_d2, h2, out2, N);

    // ---- attentional pooling ----
    k_pool_gate<<<(N + 7) / 8, 256, 0, stream>>>(out2, b2, gw1, gb1, gw2, gb2, batch,
                                                 hF, gate, gm, N);
    k_pool_b<<<(N + 255) / 256, 256, 0, stream>>>(batch, gm, gate, gs, N);
    k_pool_c<<<((N * 32) + 255) / 256, 256, 0, stream>>>(batch, gate, gs, hF, (float*)d_out, N);
}

// Round 3
// 581.193 us; speedup vs baseline: 2.6672x; 1.8986x over previous
//
#include <hip/hip_runtime.h>
#include <hip/hip_bf16.h>

#define NEG_SLOPE 0.2f

__device__ __forceinline__ float elu1f(float v) {
    return v > 0.f ? v : expm1f(v);
}

// ======================= CSR build (by dst) =======================
__global__ void k_deg(const int* __restrict__ ei, int E, int Et, int* __restrict__ deg)
{
    int i = blockIdx.x * 256 + threadIdx.x;
    if (i >= Et) return;
    int d = (i < E) ? ei[E + i] : i - E;
    atomicAdd(&deg[d], 1);
}

__global__ __launch_bounds__(256) void k_scan1(const int* __restrict__ deg, int N,
                                               int* __restrict__ row, int* __restrict__ bsum)
{
    __shared__ int s[256];
    int i = blockIdx.x * 256 + threadIdx.x;
    int v = (i < N) ? deg[i] : 0;
    s[threadIdx.x] = v;
    __syncthreads();
#pragma unroll
    for (int off = 1; off < 256; off <<= 1) {
        int t = (threadIdx.x >= off) ? s[threadIdx.x - off] : 0;
        __syncthreads();
        s[threadIdx.x] += t;
        __syncthreads();
    }
    if (i < N) row[i] = s[threadIdx.x] - v;          // exclusive
    if (threadIdx.x == 255) bsum[blockIdx.x] = s[255];
}

__global__ __launch_bounds__(256) void k_scan2(int* __restrict__ bsum, int nb)
{
    __shared__ int s[256];
    int v = (threadIdx.x < nb) ? bsum[threadIdx.x] : 0;
    s[threadIdx.x] = v;
    __syncthreads();
#pragma unroll
    for (int off = 1; off < 256; off <<= 1) {
        int t = (threadIdx.x >= off) ? s[threadIdx.x - off] : 0;
        __syncthreads();
        s[threadIdx.x] += t;
        __syncthreads();
    }
    if (threadIdx.x < nb) bsum[threadIdx.x] = s[threadIdx.x] - v;   // exclusive
}

__global__ void k_scan3(int* __restrict__ row, const int* __restrict__ bsum,
                        int N, int Et, int* __restrict__ cursor)
{
    int i = blockIdx.x * 256 + threadIdx.x;
    if (i < N) {
        int r = row[i] + bsum[blockIdx.x];
        row[i] = r;
        cursor[i] = r;
    }
    if (i == 0) row[N] = Et;
}

__global__ void k_scatter(const int* __restrict__ ei, int E, int Et,
                          int* __restrict__ cursor, int* __restrict__ esrc)
{
    int i = blockIdx.x * 256 + threadIdx.x;
    if (i >= Et) return;
    int s, d;
    if (i < E) { s = ei[i]; d = ei[E + i]; } else { s = i - E; d = s; }
    int pos = atomicAdd(&cursor[d], 1);
    esrc[pos] = s;
}

// ---------------- GEMM1: h1 = x @ W1 (128->128), fused a_src1/a_dst1 ----------------
__global__ __launch_bounds__(128) void k_gemm1(
    const float* __restrict__ x, const float* __restrict__ W,
    const float* __restrict__ att_s, const float* __restrict__ att_d,
    float* __restrict__ h1, float* __restrict__ as1, float* __restrict__ ad1, int N)
{
    __shared__ float sW[32][128];
    __shared__ float sX[16][32];
    const int t = threadIdx.x;          // output column 0..127
    const int row0 = blockIdx.x * 16;

    float acc[16];
#pragma unroll
    for (int r = 0; r < 16; r++) acc[r] = 0.f;

    for (int k0 = 0; k0 < 128; k0 += 32) {
        __syncthreads();
#pragma unroll
        for (int i = 0; i < 32; i++) sW[i][t] = W[(k0 + i) * 128 + t];
#pragma unroll
        for (int i = 0; i < 4; i++) {
            int idx = i * 128 + t;              // 0..511
            int r = idx >> 5, c = idx & 31;
            int row = row0 + r;
            sX[r][c] = (row < N) ? x[(long long)row * 128 + k0 + c] : 0.f;
        }
        __syncthreads();
#pragma unroll
        for (int kk = 0; kk < 32; kk++) {
            float wv = sW[kk][t];
#pragma unroll
            for (int r = 0; r < 16; r++) acc[r] = fmaf(sX[r][kk], wv, acc[r]);
        }
    }

    const float av_s = att_s[t], av_d = att_d[t];
    const int lane = t & 31;
    const int head = t >> 5;
#pragma unroll
    for (int r = 0; r < 16; r++) {
        int row = row0 + r;
        if (row >= N) break;                    // uniform across block
        float v = acc[r];
        h1[(long long)row * 128 + t] = v;
        float s = v * av_s, d = v * av_d;
#pragma unroll
        for (int off = 16; off > 0; off >>= 1) {
            s += __shfl_xor(s, off, 32);
            d += __shfl_xor(d, off, 32);
        }
        if (lane == 0) { as1[row * 4 + head] = s; ad1[row * 4 + head] = d; }
    }
}

// ---------------- GEMM2: h2 = elu(out1+b1) @ W2 (128->32), fused a_src2/a_dst2 -------
__global__ __launch_bounds__(256) void k_gemm2(
    const float* __restrict__ xin, const float* __restrict__ W,
    const float* __restrict__ b1,
    const float* __restrict__ att_s, const float* __restrict__ att_d,
    float* __restrict__ h2, float* __restrict__ as2, float* __restrict__ ad2, int N)
{
    __shared__ float sW[128][32];
    __shared__ float sX[32][128];
    const int t = threadIdx.x;
    const int row0 = blockIdx.x * 32;

#pragma unroll
    for (int i = 0; i < 16; i++) {
        int idx = i * 256 + t;                  // 0..4095
        sW[idx >> 5][idx & 31] = W[idx];
    }
#pragma unroll
    for (int i = 0; i < 16; i++) {
        int idx = i * 256 + t;
        int r = idx >> 7, c = idx & 127;
        int row = row0 + r;
        float v = (row < N) ? xin[(long long)row * 128 + c] + b1[c] : 0.f;
        sX[r][c] = elu1f(v);
    }
    __syncthreads();

    const int c = t & 31, rsub = t >> 5;
    const float av_s = att_s[c], av_d = att_d[c];
#pragma unroll
    for (int p = 0; p < 4; p++) {
        int r = p * 8 + rsub;
        int row = row0 + r;
        float a = 0.f;
#pragma unroll
        for (int k = 0; k < 128; k++) a = fmaf(sX[r][k], sW[k][c], a);
        if (row < N) {
            h2[(long long)row * 32 + c] = a;
            float s = a * av_s, d = a * av_d;
#pragma unroll
            for (int off = 16; off > 0; off >>= 1) {
                s += __shfl_xor(s, off, 32);
                d += __shfl_xor(d, off, 32);
            }
            if (c == 0) { as2[row] = s; ad2[row] = d; }
        }
    }
}

// ========== Fused GAT aggregation, layer 1 (H=4, C=32): one wave per dst ==========
__global__ __launch_bounds__(256) void k_agg1(
    const int* __restrict__ row, const int* __restrict__ esrc,
    const float* __restrict__ as, const float* __restrict__ ad,   // [N][4]
    const float* __restrict__ h,                                  // [N][128]
    float* __restrict__ out, int N)                               // [N][128]
{
    const int lane = threadIdx.x & 63;
    const int wid  = threadIdx.x >> 6;
    const int n = blockIdx.x * 4 + wid;
    if (n >= N) return;
    const int hsel = lane >> 4;                 // head of this lane's 2 columns

    const float4 ad4 = *(const float4*)&ad[n * 4];
    const float adh = hsel == 0 ? ad4.x : hsel == 1 ? ad4.y : hsel == 2 ? ad4.z : ad4.w;

    float m = -INFINITY, den = 0.f, acc0 = 0.f, acc1 = 0.f;
    const int e0 = row[n], e1 = row[n + 1];
    for (int e = e0; e < e1; ++e) {
        const int s = esrc[e];                  // wave-uniform
        const float4 as4 = *(const float4*)&as[s * 4];
        const float ash = hsel == 0 ? as4.x : hsel == 1 ? as4.y : hsel == 2 ? as4.z : as4.w;
        float ev = ash + adh;
        ev = ev >= 0.f ? ev : NEG_SLOPE * ev;
        const float mn = fmaxf(m, ev);
        const float r = __expf(m - mn);         // m=-inf first iter -> r=0
        const float w = __expf(ev - mn);
        const float2 hv = *(const float2*)&h[(long long)s * 128 + lane * 2];
        den  = fmaf(den, r, w);
        acc0 = fmaf(w, hv.x, acc0 * r);
        acc1 = fmaf(w, hv.y, acc1 * r);
        m = mn;
    }
    const float inv = 1.f / (den + 1e-16f);
    float2 o; o.x = acc0 * inv; o.y = acc1 * inv;
    *(float2*)&out[(long long)n * 128 + lane * 2] = o;
}

// ========== Fused GAT aggregation, layer 2 (H=1, C=32): one dst per 32 lanes ==========
__global__ __launch_bounds__(256) void k_agg2(
    const int* __restrict__ row, const int* __restrict__ esrc,
    const float* __restrict__ as, const float* __restrict__ ad,   // [N]
    const float* __restrict__ h,                                  // [N][32]
    float* __restrict__ out, int N)                               // [N][32]
{
    const int lane = threadIdx.x & 31;
    const int half = threadIdx.x >> 5;          // 0..7
    const int n = blockIdx.x * 8 + half;
    if (n >= N) return;

    const float adv = ad[n];
    float m = -INFINITY, den = 0.f, acc = 0.f;
    const int e0 = row[n], e1 = row[n + 1];
    for (int e = e0; e < e1; ++e) {
        const int s = esrc[e];
        float ev = as[s] + adv;
        ev = ev >= 0.f ? ev : NEG_SLOPE * ev;
        const float mn = fmaxf(m, ev);
        const float r = __expf(m - mn);
        const float w = __expf(ev - mn);
        const float hv = h[(long long)s * 32 + lane];
        den = fmaf(den, r, w);
        acc = fmaf(w, hv, acc * r);
        m = mn;
    }
    out[(long long)n * 32 + lane] = acc / (den + 1e-16f);
}

// ========== Attentional pooling: one block per graph, ZERO atomics ==========
// batch is sorted, so graph g owns contiguous nodes [s0,s1) found by binary search.
// Pass A: gate MLP per node + block max. Pass B: exp-weighted accumulation.
__global__ __launch_bounds__(256) void k_pool(
    const float* __restrict__ out2, const float* __restrict__ b2,
    const float* __restrict__ gw1, const float* __restrict__ gb1,
    const float* __restrict__ gw2, const float* __restrict__ gb2,
    const int* __restrict__ batch, float* __restrict__ gate,
    float* __restrict__ out, int N)
{
    const int g   = blockIdx.x;
    const int t   = threadIdx.x;
    const int c   = t & 31;          // column / lane-in-group
    const int grp = t >> 5;          // 0..7

    __shared__ int   sbound[2];
    __shared__ float sred[4];
    __shared__ float sacc[8][32];
    __shared__ float swsum[8];

    if (t < 2) {
        int target = g + t;
        int lo = 0, hi = N;
        while (lo < hi) { int mid = (lo + hi) >> 1; if (batch[mid] < target) lo = mid + 1; else hi = mid; }
        sbound[t] = lo;
    }
    __syncthreads();
    const int s0 = sbound[0], s1 = sbound[1];

    // ---- Pass A: gate[n] + running max ----
    float mloc = -INFINITY;
    for (int n = s0 + grp; n < s1; n += 8) {
        float v = out2[(long long)n * 32 + c] + b2[c];
        v = elu1f(v);
        float t1 = gb1[c];
#pragma unroll
        for (int k = 0; k < 32; k++) {
            float hk = __shfl(v, k, 32);
            t1 = fmaf(hk, gw1[k * 32 + c], t1);
        }
        t1 = fmaxf(t1, 0.f);
        float gv = t1 * gw2[c];
#pragma unroll
        for (int off = 16; off > 0; off >>= 1) gv += __shfl_xor(gv, off, 32);
        gv += gb2[0];
        if (c == 0) gate[n] = gv;
        mloc = fmaxf(mloc, gv);
    }
#pragma unroll
    for (int off = 32; off > 0; off >>= 1) mloc = fmaxf(mloc, __shfl_xor(mloc, off, 64));
    if ((t & 63) == 0) sred[t >> 6] = mloc;
    __syncthreads();
    const float gm = fmaxf(fmaxf(sred[0], sred[1]), fmaxf(sred[2], sred[3]));

    // ---- Pass B: weighted accumulation (visibility of gate[] ensured by syncthreads) ----
    float acc = 0.f, wsum = 0.f;
    for (int n = s0 + grp; n < s1; n += 8) {
        float v = out2[(long long)n * 32 + c] + b2[c];
        v = elu1f(v);
        float ge = __expf(gate[n] - gm);
        acc = fmaf(ge, v, acc);
        wsum += ge;                  // same value on all 32 lanes; use lane 0's copy later
    }
    sacc[grp][c] = acc;
    if (c == 0) swsum[grp] = wsum;
    __syncthreads();

    if (grp == 0) {
        float a = 0.f, wtot = 0.f;
#pragma unroll
        for (int i = 0; i < 8; i++) { a += sacc[i][c]; wtot += swsum[i]; }
        out[g * 32 + c] = a / (wtot + 1e-16f);
    }
}

extern "C" void kernel_launch(void* const* d_in, const int* in_sizes, int n_in,
                              void* d_out, int out_size, void* d_ws, size_t ws_size,
                              hipStream_t stream)
{
    const float* x    = (const float*)d_in[0];
    const int*   ei   = (const int*)d_in[1];
    const int*   batch= (const int*)d_in[2];
    const float* W1   = (const float*)d_in[3];
    const float* as1w = (const float*)d_in[4];
    const float* ad1w = (const float*)d_in[5];
    const float* b1   = (const float*)d_in[6];
    const float* W2   = (const float*)d_in[7];
    const float* as2w = (const float*)d_in[8];
    const float* ad2w = (const float*)d_in[9];
    const float* b2   = (const float*)d_in[10];
    const float* gw1  = (const float*)d_in[11];
    const float* gb1  = (const float*)d_in[12];
    const float* gw2  = (const float*)d_in[13];
    const float* gb2  = (const float*)d_in[14];

    const int N  = in_sizes[2];
    const int E  = in_sizes[1] / 2;
    const int Et = E + N;
    const int nb = (N + 255) / 256;      // scan blocks (196 for N=50000, fits k_scan2)

    float* ws = (float*)d_ws;
    size_t o = 0;
    float* h1   = ws + o; o += (size_t)N * 128;
    float* out1 = ws + o; o += (size_t)N * 128;
    float* h2   = ws + o; o += (size_t)N * 32;
    float* out2 = ws + o; o += (size_t)N * 32;
    float* a_s1 = ws + o; o += (size_t)N * 4;
    float* a_d1 = ws + o; o += (size_t)N * 4;
    float* a_s2 = ws + o; o += (size_t)N;
    float* a_d2 = ws + o; o += (size_t)N;
    float* gate = ws + o; o += (size_t)N;
    int*   rowp = (int*)(ws + o); o += (size_t)N + 1;
    int*   curs = (int*)(ws + o); o += (size_t)N;
    int*   esrc = (int*)(ws + o); o += (size_t)Et;
    int*   bsum = (int*)(ws + o); o += 256;
    // ---- zeroed region (one memset): deg ----
    size_t zstart = o;
    int*   deg  = (int*)(ws + o); o += (size_t)N;
    size_t zbytes = (o - zstart) * sizeof(float);

    hipMemsetAsync(ws + zstart, 0, zbytes, stream);

    // ---- CSR build (shared by both layers) ----
    k_deg    <<<(Et + 255) / 256, 256, 0, stream>>>(ei, E, Et, deg);
    k_scan1  <<<nb, 256, 0, stream>>>(deg, N, rowp, bsum);
    k_scan2  <<<1, 256, 0, stream>>>(bsum, nb);
    k_scan3  <<<nb, 256, 0, stream>>>(rowp, bsum, N, Et, curs);
    k_scatter<<<(Et + 255) / 256, 256, 0, stream>>>(ei, E, Et, curs, esrc);

    // ---- GAT layer 1 ----
    k_gemm1<<<(N + 15) / 16, 128, 0, stream>>>(x, W1, as1w, ad1w, h1, a_s1, a_d1, N);
    k_agg1 <<<(N + 3) / 4, 256, 0, stream>>>(rowp, esrc, a_s1, a_d1, h1, out1, N);

    // ---- GAT layer 2 (elu(out1+b1) fused into gemm2 load) ----
    k_gemm2<<<(N + 31) / 32, 256, 0, stream>>>(out1, W2, b1, as2w, ad2w, h2, a_s2, a_d2, N);
    k_agg2 <<<(N + 7) / 8, 256, 0, stream>>>(rowp, esrc, a_s2, a_d2, h2, out2, N);

    // ---- attentional pooling (one block per graph, no atomics) ----
    k_pool<<<64, 256, 0, stream>>>(out2, b2, gw1, gb1, gw2, gb2, batch, gate,
                                   (float*)d_out, N);
}

// Round 4
// 473.096 us; speedup vs baseline: 3.2766x; 1.2285x over previous
//
#include <hip/hip_runtime.h>
#include <hip/hip_bf16.h>

#define NEG_SLOPE 0.2f

__device__ __forceinline__ float elu1f(float v) {
    return v > 0.f ? v : expm1f(v);
}

// ======================= CSR build (by dst) =======================
__global__ void k_deg(const int* __restrict__ ei, int E, int Et, int* __restrict__ deg)
{
    int i = blockIdx.x * 256 + threadIdx.x;
    if (i >= Et) return;
    int d = (i < E) ? ei[E + i] : i - E;
    atomicAdd(&deg[d], 1);
}

__global__ __launch_bounds__(256) void k_scan1(const int* __restrict__ deg, int N,
                                               int* __restrict__ row, int* __restrict__ bsum)
{
    __shared__ int s[256];
    int i = blockIdx.x * 256 + threadIdx.x;
    int v = (i < N) ? deg[i] : 0;
    s[threadIdx.x] = v;
    __syncthreads();
#pragma unroll
    for (int off = 1; off < 256; off <<= 1) {
        int t = (threadIdx.x >= off) ? s[threadIdx.x - off] : 0;
        __syncthreads();
        s[threadIdx.x] += t;
        __syncthreads();
    }
    if (i < N) row[i] = s[threadIdx.x] - v;          // exclusive
    if (threadIdx.x == 255) bsum[blockIdx.x] = s[255];
}

__global__ __launch_bounds__(256) void k_scan2(int* __restrict__ bsum, int nb)
{
    __shared__ int s[256];
    int v = (threadIdx.x < nb) ? bsum[threadIdx.x] : 0;
    s[threadIdx.x] = v;
    __syncthreads();
#pragma unroll
    for (int off = 1; off < 256; off <<= 1) {
        int t = (threadIdx.x >= off) ? s[threadIdx.x - off] : 0;
        __syncthreads();
        s[threadIdx.x] += t;
        __syncthreads();
    }
    if (threadIdx.x < nb) bsum[threadIdx.x] = s[threadIdx.x] - v;   // exclusive
}

__global__ void k_scan3(int* __restrict__ row, const int* __restrict__ bsum,
                        int N, int Et, int* __restrict__ cursor)
{
    int i = blockIdx.x * 256 + threadIdx.x;
    if (i < N) {
        int r = row[i] + bsum[blockIdx.x];
        row[i] = r;
        cursor[i] = r;
    }
    if (i == 0) row[N] = Et;
}

__global__ void k_scatter(const int* __restrict__ ei, int E, int Et,
                          int* __restrict__ cursor, int* __restrict__ esrc)
{
    int i = blockIdx.x * 256 + threadIdx.x;
    if (i >= Et) return;
    int s, d;
    if (i < E) { s = ei[i]; d = ei[E + i]; } else { s = i - E; d = s; }
    int pos = atomicAdd(&cursor[d], 1);
    esrc[pos] = s;
}

// ---------------- GEMM1: h1 = x @ W1 (128->128), fused a_src1/a_dst1 ----------------
__global__ __launch_bounds__(128) void k_gemm1(
    const float* __restrict__ x, const float* __restrict__ W,
    const float* __restrict__ att_s, const float* __restrict__ att_d,
    float* __restrict__ h1, float* __restrict__ as1, float* __restrict__ ad1, int N)
{
    __shared__ __align__(16) float sW[32][128];
    __shared__ __align__(16) float sX[16][32];
    const int t = threadIdx.x;          // output column 0..127
    const int row0 = blockIdx.x * 16;
    const float4* W4 = (const float4*)W;     // row stride 32 float4

    float acc[16];
#pragma unroll
    for (int r = 0; r < 16; r++) acc[r] = 0.f;

    for (int k0 = 0; k0 < 128; k0 += 32) {
        __syncthreads();
#pragma unroll
        for (int j = 0; j < 8; j++) {
            int idx = j * 128 + t;           // 0..1023 float4s of the 32x128 tile
            int i = idx >> 5, c4 = idx & 31;
            *(float4*)&sW[i][c4 * 4] = W4[(k0 + i) * 32 + c4];
        }
        {
            int r = t >> 3, c4 = t & 7;      // 16 rows x 8 float4
            int row = row0 + r;
            float4 v = {0.f, 0.f, 0.f, 0.f};
            if (row < N) v = *(const float4*)&x[(long long)row * 128 + k0 + c4 * 4];
            *(float4*)&sX[r][c4 * 4] = v;
        }
        __syncthreads();
#pragma unroll
        for (int kk = 0; kk < 32; kk += 4) {
            float w0 = sW[kk][t], w1 = sW[kk + 1][t], w2 = sW[kk + 2][t], w3 = sW[kk + 3][t];
#pragma unroll
            for (int r = 0; r < 16; r++) {
                float4 xv = *(const float4*)&sX[r][kk];
                acc[r] = fmaf(xv.x, w0, acc[r]);
                acc[r] = fmaf(xv.y, w1, acc[r]);
                acc[r] = fmaf(xv.z, w2, acc[r]);
                acc[r] = fmaf(xv.w, w3, acc[r]);
            }
        }
    }

    const float av_s = att_s[t], av_d = att_d[t];
    const int lane = t & 31;
    const int head = t >> 5;
#pragma unroll
    for (int r = 0; r < 16; r++) {
        int row = row0 + r;
        if (row >= N) break;                    // uniform across block
        float v = acc[r];
        h1[(long long)row * 128 + t] = v;
        float s = v * av_s, d = v * av_d;
#pragma unroll
        for (int off = 16; off > 0; off >>= 1) {
            s += __shfl_xor(s, off, 32);
            d += __shfl_xor(d, off, 32);
        }
        if (lane == 0) { as1[row * 4 + head] = s; ad1[row * 4 + head] = d; }
    }
}

// ---------------- GEMM2: h2 = elu(out1+b1) @ W2 (128->32), fused a_src2/a_dst2 -------
__global__ __launch_bounds__(256) void k_gemm2(
    const float* __restrict__ xin, const float* __restrict__ W,
    const float* __restrict__ b1,
    const float* __restrict__ att_s, const float* __restrict__ att_d,
    float* __restrict__ h2, float* __restrict__ as2, float* __restrict__ ad2, int N)
{
    __shared__ __align__(16) float sW[128][32];
    __shared__ __align__(16) float sX[32][128];
    const int t = threadIdx.x;
    const int row0 = blockIdx.x * 32;
    const float4* W4 = (const float4*)W;

#pragma unroll
    for (int j = 0; j < 4; j++) {
        int idx = j * 256 + t;               // 1024 float4s of W (128x32)
        int r = idx >> 3, c4 = idx & 7;
        *(float4*)&sW[r][c4 * 4] = W4[idx];
    }
#pragma unroll
    for (int j = 0; j < 4; j++) {
        int idx = j * 256 + t;               // 1024 float4s of X (32x128)
        int r = idx >> 5, c4 = idx & 31;
        int row = row0 + r;
        float4 v = {0.f, 0.f, 0.f, 0.f};
        if (row < N) {
            v = *(const float4*)&xin[(long long)row * 128 + c4 * 4];
            float4 b = *(const float4*)&b1[c4 * 4];
            v.x = elu1f(v.x + b.x); v.y = elu1f(v.y + b.y);
            v.z = elu1f(v.z + b.z); v.w = elu1f(v.w + b.w);
        }
        *(float4*)&sX[r][c4 * 4] = v;
    }
    __syncthreads();

    const int c = t & 31, rsub = t >> 5;
    const float av_s = att_s[c], av_d = att_d[c];
#pragma unroll
    for (int p = 0; p < 4; p++) {
        int r = p * 8 + rsub;
        int row = row0 + r;
        float a = 0.f;
#pragma unroll
        for (int k = 0; k < 128; k += 4) {
            float4 xv = *(const float4*)&sX[r][k];
            a = fmaf(xv.x, sW[k][c], a);
            a = fmaf(xv.y, sW[k + 1][c], a);
            a = fmaf(xv.z, sW[k + 2][c], a);
            a = fmaf(xv.w, sW[k + 3][c], a);
        }
        if (row < N) {
            h2[(long long)row * 32 + c] = a;
            float s = a * av_s, d = a * av_d;
#pragma unroll
            for (int off = 16; off > 0; off >>= 1) {
                s += __shfl_xor(s, off, 32);
                d += __shfl_xor(d, off, 32);
            }
            if (c == 0) { as2[row] = s; ad2[row] = d; }
        }
    }
}

// ========== Fused GAT aggregation, layer 1 (H=4, C=32): one wave per dst ==========
// Phase 1: lane-parallel segment max (edge e0+lane+64k per lane) + wave reduce.
// Phase 2: plain weighted accumulation, 2 edges/iter (one per 32-lane half),
//          lane carries float4 of h (4 cols); den accumulated alongside.
__global__ __launch_bounds__(256) void k_agg1(
    const int* __restrict__ row, const int* __restrict__ esrc,
    const float* __restrict__ as, const float* __restrict__ ad,   // [N][4]
    const float* __restrict__ h,                                  // [N][128]
    float* __restrict__ out, int N)                               // [N][128]
{
    const int lane = threadIdx.x & 63;
    const int wid  = threadIdx.x >> 6;
    const int n = blockIdx.x * 4 + wid;
    if (n >= N) return;
    const int e0 = row[n], e1 = row[n + 1];

    const float4 ad4 = *(const float4*)&ad[n * 4];

    // ---- phase 1: per-head max over in-edges ----
    float m0 = -INFINITY, m1 = -INFINITY, m2 = -INFINITY, m3 = -INFINITY;
    for (int e = e0 + lane; e < e1; e += 64) {
        const int s = esrc[e];
        const float4 a4 = *(const float4*)&as[s * 4];
        float v0 = a4.x + ad4.x; v0 = v0 >= 0.f ? v0 : NEG_SLOPE * v0;
        float v1 = a4.y + ad4.y; v1 = v1 >= 0.f ? v1 : NEG_SLOPE * v1;
        float v2 = a4.z + ad4.z; v2 = v2 >= 0.f ? v2 : NEG_SLOPE * v2;
        float v3 = a4.w + ad4.w; v3 = v3 >= 0.f ? v3 : NEG_SLOPE * v3;
        m0 = fmaxf(m0, v0); m1 = fmaxf(m1, v1);
        m2 = fmaxf(m2, v2); m3 = fmaxf(m3, v3);
    }
#pragma unroll
    for (int off = 32; off > 0; off >>= 1) {
        m0 = fmaxf(m0, __shfl_xor(m0, off, 64));
        m1 = fmaxf(m1, __shfl_xor(m1, off, 64));
        m2 = fmaxf(m2, __shfl_xor(m2, off, 64));
        m3 = fmaxf(m3, __shfl_xor(m3, off, 64));
    }

    // ---- phase 2: weighted accumulation, 2 edges per iteration ----
    const int half = lane >> 5;
    const int l    = lane & 31;                 // 4 cols per lane: l*4..l*4+3
    const int hd   = l >> 3;                    // head of those cols
    const float adh = hd == 0 ? ad4.x : hd == 1 ? ad4.y : hd == 2 ? ad4.z : ad4.w;
    const float mh  = hd == 0 ? m0  : hd == 1 ? m1  : hd == 2 ? m2  : m3;

    float4 acc = {0.f, 0.f, 0.f, 0.f};
    float wsum = 0.f;
    for (int base = e0; base < e1; base += 2) {
        const int e = base + half;
        if (e < e1) {
            const int s = esrc[e];
            const float4 a4 = *(const float4*)&as[s * 4];
            float ash = hd == 0 ? a4.x : hd == 1 ? a4.y : hd == 2 ? a4.z : a4.w;
            float ev = ash + adh;
            ev = ev >= 0.f ? ev : NEG_SLOPE * ev;
            const float w = __expf(ev - mh);
            const float4 hv = *(const float4*)&h[(long long)s * 128 + l * 4];
            acc.x = fmaf(w, hv.x, acc.x);
            acc.y = fmaf(w, hv.y, acc.y);
            acc.z = fmaf(w, hv.z, acc.z);
            acc.w = fmaf(w, hv.w, acc.w);
            wsum += w;
        }
    }
    acc.x += __shfl_xor(acc.x, 32, 64);
    acc.y += __shfl_xor(acc.y, 32, 64);
    acc.z += __shfl_xor(acc.z, 32, 64);
    acc.w += __shfl_xor(acc.w, 32, 64);
    wsum  += __shfl_xor(wsum, 32, 64);

    if (half == 0) {
        const float inv = 1.f / (wsum + 1e-16f);
        float4 o; o.x = acc.x * inv; o.y = acc.y * inv; o.z = acc.z * inv; o.w = acc.w * inv;
        *(float4*)&out[(long long)n * 128 + l * 4] = o;
    }
}

// ========== Fused GAT aggregation, layer 2 (H=1, C=32): one wave per dst ==========
// Phase 1: lane-parallel max. Phase 2: 8 edges/iter, 8 lanes (float4) per edge.
__global__ __launch_bounds__(256) void k_agg2(
    const int* __restrict__ row, const int* __restrict__ esrc,
    const float* __restrict__ as, const float* __restrict__ ad,   // [N]
    const float* __restrict__ h,                                  // [N][32]
    float* __restrict__ out, int N)                               // [N][32]
{
    const int lane = threadIdx.x & 63;
    const int wid  = threadIdx.x >> 6;
    const int n = blockIdx.x * 4 + wid;
    if (n >= N) return;
    const int e0 = row[n], e1 = row[n + 1];
    const float adv = ad[n];

    float m = -INFINITY;
    for (int e = e0 + lane; e < e1; e += 64) {
        float ev = as[esrc[e]] + adv;
        ev = ev >= 0.f ? ev : NEG_SLOPE * ev;
        m = fmaxf(m, ev);
    }
#pragma unroll
    for (int off = 32; off > 0; off >>= 1) m = fmaxf(m, __shfl_xor(m, off, 64));

    const int g  = lane >> 3;                    // edge slot 0..7
    const int l8 = lane & 7;                     // 4 cols: l8*4..l8*4+3
    float4 acc = {0.f, 0.f, 0.f, 0.f};
    float wsum = 0.f;
    for (int base = e0; base < e1; base += 8) {
        const int e = base + g;
        if (e < e1) {
            const int s = esrc[e];
            float ev = as[s] + adv;
            ev = ev >= 0.f ? ev : NEG_SLOPE * ev;
            const float w = __expf(ev - m);
            const float4 hv = *(const float4*)&h[(long long)s * 32 + l8 * 4];
            acc.x = fmaf(w, hv.x, acc.x);
            acc.y = fmaf(w, hv.y, acc.y);
            acc.z = fmaf(w, hv.z, acc.z);
            acc.w = fmaf(w, hv.w, acc.w);
            wsum += w;
        }
    }
#pragma unroll
    for (int off = 8; off < 64; off <<= 1) {
        acc.x += __shfl_xor(acc.x, off, 64);
        acc.y += __shfl_xor(acc.y, off, 64);
        acc.z += __shfl_xor(acc.z, off, 64);
        acc.w += __shfl_xor(acc.w, off, 64);
        wsum  += __shfl_xor(wsum, off, 64);
    }
    if (lane < 8) {
        const float inv = 1.f / (wsum + 1e-16f);
        float4 o; o.x = acc.x * inv; o.y = acc.y * inv; o.z = acc.z * inv; o.w = acc.w * inv;
        *(float4*)&out[(long long)n * 32 + lane * 4] = o;
    }
}

// ========== Attentional pooling: one block per graph, ZERO atomics ==========
__global__ __launch_bounds__(256) void k_pool(
    const float* __restrict__ out2, const float* __restrict__ b2,
    const float* __restrict__ gw1, const float* __restrict__ gb1,
    const float* __restrict__ gw2, const float* __restrict__ gb2,
    const int* __restrict__ batch, float* __restrict__ gate,
    float* __restrict__ out, int N)
{
    const int g   = blockIdx.x;
    const int t   = threadIdx.x;
    const int c   = t & 31;
    const int grp = t >> 5;

    __shared__ int   sbound[2];
    __shared__ float sred[4];
    __shared__ float sacc[8][32];
    __shared__ float swsum[8];

    if (t < 2) {
        int target = g + t;
        int lo = 0, hi = N;
        while (lo < hi) { int mid = (lo + hi) >> 1; if (batch[mid] < target) lo = mid + 1; else hi = mid; }
        sbound[t] = lo;
    }
    __syncthreads();
    const int s0 = sbound[0], s1 = sbound[1];

    float mloc = -INFINITY;
    for (int n = s0 + grp; n < s1; n += 8) {
        float v = out2[(long long)n * 32 + c] + b2[c];
        v = elu1f(v);
        float t1 = gb1[c];
#pragma unroll
        for (int k = 0; k < 32; k++) {
            float hk = __shfl(v, k, 32);
            t1 = fmaf(hk, gw1[k * 32 + c], t1);
        }
        t1 = fmaxf(t1, 0.f);
        float gv = t1 * gw2[c];
#pragma unroll
        for (int off = 16; off > 0; off >>= 1) gv += __shfl_xor(gv, off, 32);
        gv += gb2[0];
        if (c == 0) gate[n] = gv;
        mloc = fmaxf(mloc, gv);
    }
#pragma unroll
    for (int off = 32; off > 0; off >>= 1) mloc = fmaxf(mloc, __shfl_xor(mloc, off, 64));
    if ((t & 63) == 0) sred[t >> 6] = mloc;
    __syncthreads();
    const float gm = fmaxf(fmaxf(sred[0], sred[1]), fmaxf(sred[2], sred[3]));

    float acc = 0.f, wsum = 0.f;
    for (int n = s0 + grp; n < s1; n += 8) {
        float v = out2[(long long)n * 32 + c] + b2[c];
        v = elu1f(v);
        float ge = __expf(gate[n] - gm);
        acc = fmaf(ge, v, acc);
        wsum += ge;
    }
    sacc[grp][c] = acc;
    if (c == 0) swsum[grp] = wsum;
    __syncthreads();

    if (grp == 0) {
        float a = 0.f, wtot = 0.f;
#pragma unroll
        for (int i = 0; i < 8; i++) { a += sacc[i][c]; wtot += swsum[i]; }
        out[g * 32 + c] = a / (wtot + 1e-16f);
    }
}

extern "C" void kernel_launch(void* const* d_in, const int* in_sizes, int n_in,
                              void* d_out, int out_size, void* d_ws, size_t ws_size,
                              hipStream_t stream)
{
    const float* x    = (const float*)d_in[0];
    const int*   ei   = (const int*)d_in[1];
    const int*   batch= (const int*)d_in[2];
    const float* W1   = (const float*)d_in[3];
    const float* as1w = (const float*)d_in[4];
    const float* ad1w = (const float*)d_in[5];
    const float* b1   = (const float*)d_in[6];
    const float* W2   = (const float*)d_in[7];
    const float* as2w = (const float*)d_in[8];
    const float* ad2w = (const float*)d_in[9];
    const float* b2   = (const float*)d_in[10];
    const float* gw1  = (const float*)d_in[11];
    const float* gb1  = (const float*)d_in[12];
    const float* gw2  = (const float*)d_in[13];
    const float* gb2  = (const float*)d_in[14];

    const int N  = in_sizes[2];
    const int E  = in_sizes[1] / 2;
    const int Et = E + N;
    const int nb = (N + 255) / 256;

    float* ws = (float*)d_ws;
    size_t o = 0;
    float* h1   = ws + o; o += (size_t)N * 128;
    float* out1 = ws + o; o += (size_t)N * 128;
    float* h2   = ws + o; o += (size_t)N * 32;
    float* out2 = ws + o; o += (size_t)N * 32;
    float* a_s1 = ws + o; o += (size_t)N * 4;
    float* a_d1 = ws + o; o += (size_t)N * 4;
    float* a_s2 = ws + o; o += (size_t)N;
    float* a_d2 = ws + o; o += (size_t)N;
    float* gate = ws + o; o += (size_t)N;
    int*   rowp = (int*)(ws + o); o += (size_t)N + 1;
    int*   curs = (int*)(ws + o); o += (size_t)N;
    int*   esrc = (int*)(ws + o); o += (size_t)Et;
    int*   bsum = (int*)(ws + o); o += 256;
    // ---- zeroed region (one memset): deg ----
    size_t zstart = o;
    int*   deg  = (int*)(ws + o); o += (size_t)N;
    size_t zbytes = (o - zstart) * sizeof(float);

    hipMemsetAsync(ws + zstart, 0, zbytes, stream);

    // ---- CSR build (shared by both layers) ----
    k_deg    <<<(Et + 255) / 256, 256, 0, stream>>>(ei, E, Et, deg);
    k_scan1  <<<nb, 256, 0, stream>>>(deg, N, rowp, bsum);
    k_scan2  <<<1, 256, 0, stream>>>(bsum, nb);
    k_scan3  <<<nb, 256, 0, stream>>>(rowp, bsum, N, Et, curs);
    k_scatter<<<(Et + 255) / 256, 256, 0, stream>>>(ei, E, Et, curs, esrc);

    // ---- GAT layer 1 ----
    k_gemm1<<<(N + 15) / 16, 128, 0, stream>>>(x, W1, as1w, ad1w, h1, a_s1, a_d1, N);
    k_agg1 <<<(N + 3) / 4, 256, 0, stream>>>(rowp, esrc, a_s1, a_d1, h1, out1, N);

    // ---- GAT layer 2 (elu(out1+b1) fused into gemm2 load) ----
    k_gemm2<<<(N + 31) / 32, 256, 0, stream>>>(out1, W2, b1, as2w, ad2w, h2, a_s2, a_d2, N);
    k_agg2 <<<(N + 3) / 4, 256, 0, stream>>>(rowp, esrc, a_s2, a_d2, h2, out2, N);

    // ---- attentional pooling (one block per graph, no atomics) ----
    k_pool<<<64, 256, 0, stream>>>(out2, b2, gw1, gb1, gw2, gb2, batch, gate,
                                   (float*)d_out, N);
}

// Round 5
// 412.449 us; speedup vs baseline: 3.7584x; 1.1470x over previous
//
#include <hip/hip_runtime.h>
#include <hip/hip_bf16.h>

#define NEG_SLOPE 0.2f

__device__ __forceinline__ float elu1f(float v) {
    return v > 0.f ? v : expm1f(v);
}

// ======================= CSR build (by dst) =======================
__global__ void k_deg(const int* __restrict__ ei, int E, int Et, int* __restrict__ deg)
{
    int i = blockIdx.x * 256 + threadIdx.x;
    if (i >= Et) return;
    int d = (i < E) ? ei[E + i] : i - E;
    atomicAdd(&deg[d], 1);
}

__global__ __launch_bounds__(256) void k_scan1(const int* __restrict__ deg, int N,
                                               int* __restrict__ row, int* __restrict__ bsum)
{
    __shared__ int s[256];
    int i = blockIdx.x * 256 + threadIdx.x;
    int v = (i < N) ? deg[i] : 0;
    s[threadIdx.x] = v;
    __syncthreads();
#pragma unroll
    for (int off = 1; off < 256; off <<= 1) {
        int t = (threadIdx.x >= off) ? s[threadIdx.x - off] : 0;
        __syncthreads();
        s[threadIdx.x] += t;
        __syncthreads();
    }
    if (i < N) row[i] = s[threadIdx.x] - v;          // exclusive
    if (threadIdx.x == 255) bsum[blockIdx.x] = s[255];
}

__global__ __launch_bounds__(256) void k_scan2(int* __restrict__ bsum, int nb)
{
    __shared__ int s[256];
    int v = (threadIdx.x < nb) ? bsum[threadIdx.x] : 0;
    s[threadIdx.x] = v;
    __syncthreads();
#pragma unroll
    for (int off = 1; off < 256; off <<= 1) {
        int t = (threadIdx.x >= off) ? s[threadIdx.x - off] : 0;
        __syncthreads();
        s[threadIdx.x] += t;
        __syncthreads();
    }
    if (threadIdx.x < nb) bsum[threadIdx.x] = s[threadIdx.x] - v;   // exclusive
}

__global__ void k_scan3(int* __restrict__ row, const int* __restrict__ bsum,
                        int N, int Et, int* __restrict__ cursor)
{
    int i = blockIdx.x * 256 + threadIdx.x;
    if (i < N) {
        int r = row[i] + bsum[blockIdx.x];
        row[i] = r;
        cursor[i] = r;
    }
    if (i == 0) row[N] = Et;
}

__global__ void k_scatter(const int* __restrict__ ei, int E, int Et,
                          int* __restrict__ cursor, int* __restrict__ esrc)
{
    int i = blockIdx.x * 256 + threadIdx.x;
    if (i >= Et) return;
    int s, d;
    if (i < E) { s = ei[i]; d = ei[E + i]; } else { s = i - E; d = s; }
    int pos = atomicAdd(&cursor[d], 1);
    esrc[pos] = s;
}

// ---------------- GEMM1: h1 = x @ W1 (128->128), fused a_src1/a_dst1 ----------------
__global__ __launch_bounds__(128) void k_gemm1(
    const float* __restrict__ x, const float* __restrict__ W,
    const float* __restrict__ att_s, const float* __restrict__ att_d,
    float* __restrict__ h1, float* __restrict__ as1, float* __restrict__ ad1, int N)
{
    __shared__ __align__(16) float sW[32][128];
    __shared__ __align__(16) float sX[16][32];
    const int t = threadIdx.x;          // output column 0..127
    const int row0 = blockIdx.x * 16;
    const float4* W4 = (const float4*)W;     // row stride 32 float4

    float acc[16];
#pragma unroll
    for (int r = 0; r < 16; r++) acc[r] = 0.f;

    for (int k0 = 0; k0 < 128; k0 += 32) {
        __syncthreads();
#pragma unroll
        for (int j = 0; j < 8; j++) {
            int idx = j * 128 + t;           // 0..1023 float4s of the 32x128 tile
            int i = idx >> 5, c4 = idx & 31;
            *(float4*)&sW[i][c4 * 4] = W4[(k0 + i) * 32 + c4];
        }
        {
            int r = t >> 3, c4 = t & 7;      // 16 rows x 8 float4
            int row = row0 + r;
            float4 v = {0.f, 0.f, 0.f, 0.f};
            if (row < N) v = *(const float4*)&x[(long long)row * 128 + k0 + c4 * 4];
            *(float4*)&sX[r][c4 * 4] = v;
        }
        __syncthreads();
#pragma unroll
        for (int kk = 0; kk < 32; kk += 4) {
            float w0 = sW[kk][t], w1 = sW[kk + 1][t], w2 = sW[kk + 2][t], w3 = sW[kk + 3][t];
#pragma unroll
            for (int r = 0; r < 16; r++) {
                float4 xv = *(const float4*)&sX[r][kk];
                acc[r] = fmaf(xv.x, w0, acc[r]);
                acc[r] = fmaf(xv.y, w1, acc[r]);
                acc[r] = fmaf(xv.z, w2, acc[r]);
                acc[r] = fmaf(xv.w, w3, acc[r]);
            }
        }
    }

    const float av_s = att_s[t], av_d = att_d[t];
    const int lane = t & 31;
    const int head = t >> 5;
#pragma unroll
    for (int r = 0; r < 16; r++) {
        int row = row0 + r;
        if (row >= N) break;                    // uniform across block
        float v = acc[r];
        h1[(long long)row * 128 + t] = v;
        float s = v * av_s, d = v * av_d;
#pragma unroll
        for (int off = 16; off > 0; off >>= 1) {
            s += __shfl_xor(s, off, 32);
            d += __shfl_xor(d, off, 32);
        }
        if (lane == 0) { as1[row * 4 + head] = s; ad1[row * 4 + head] = d; }
    }
}

// ---------------- GEMM2: h2 = elu(out1+b1) @ W2 (128->32), fused a_src2/a_dst2 -------
__global__ __launch_bounds__(256) void k_gemm2(
    const float* __restrict__ xin, const float* __restrict__ W,
    const float* __restrict__ b1,
    const float* __restrict__ att_s, const float* __restrict__ att_d,
    float* __restrict__ h2, float* __restrict__ as2, float* __restrict__ ad2, int N)
{
    __shared__ __align__(16) float sW[128][32];
    __shared__ __align__(16) float sX[32][128];
    const int t = threadIdx.x;
    const int row0 = blockIdx.x * 32;
    const float4* W4 = (const float4*)W;

#pragma unroll
    for (int j = 0; j < 4; j++) {
        int idx = j * 256 + t;               // 1024 float4s of W (128x32)
        int r = idx >> 3, c4 = idx & 7;
        *(float4*)&sW[r][c4 * 4] = W4[idx];
    }
#pragma unroll
    for (int j = 0; j < 4; j++) {
        int idx = j * 256 + t;               // 1024 float4s of X (32x128)
        int r = idx >> 5, c4 = idx & 31;
        int row = row0 + r;
        float4 v = {0.f, 0.f, 0.f, 0.f};
        if (row < N) {
            v = *(const float4*)&xin[(long long)row * 128 + c4 * 4];
            float4 b = *(const float4*)&b1[c4 * 4];
            v.x = elu1f(v.x + b.x); v.y = elu1f(v.y + b.y);
            v.z = elu1f(v.z + b.z); v.w = elu1f(v.w + b.w);
        }
        *(float4*)&sX[r][c4 * 4] = v;
    }
    __syncthreads();

    const int c = t & 31, rsub = t >> 5;
    const float av_s = att_s[c], av_d = att_d[c];
#pragma unroll
    for (int p = 0; p < 4; p++) {
        int r = p * 8 + rsub;
        int row = row0 + r;
        float a = 0.f;
#pragma unroll
        for (int k = 0; k < 128; k += 4) {
            float4 xv = *(const float4*)&sX[r][k];
            a = fmaf(xv.x, sW[k][c], a);
            a = fmaf(xv.y, sW[k + 1][c], a);
            a = fmaf(xv.z, sW[k + 2][c], a);
            a = fmaf(xv.w, sW[k + 3][c], a);
        }
        if (row < N) {
            h2[(long long)row * 32 + c] = a;
            float s = a * av_s, d = a * av_d;
#pragma unroll
            for (int off = 16; off > 0; off >>= 1) {
                s += __shfl_xor(s, off, 32);
                d += __shfl_xor(d, off, 32);
            }
            if (c == 0) { as2[row] = s; ad2[row] = d; }
        }
    }
}

// ========== Fused GAT aggregation, layer 1 (H=4, C=32): one wave per dst ==========
__global__ __launch_bounds__(256) void k_agg1(
    const int* __restrict__ row, const int* __restrict__ esrc,
    const float* __restrict__ as, const float* __restrict__ ad,   // [N][4]
    const float* __restrict__ h,                                  // [N][128]
    float* __restrict__ out, int N)                               // [N][128]
{
    const int lane = threadIdx.x & 63;
    const int wid  = threadIdx.x >> 6;
    const int n = blockIdx.x * 4 + wid;
    if (n >= N) return;
    const int e0 = row[n], e1 = row[n + 1];

    const float4 ad4 = *(const float4*)&ad[n * 4];

    // ---- phase 1: per-head max over in-edges ----
    float m0 = -INFINITY, m1 = -INFINITY, m2 = -INFINITY, m3 = -INFINITY;
    for (int e = e0 + lane; e < e1; e += 64) {
        const int s = esrc[e];
        const float4 a4 = *(const float4*)&as[s * 4];
        float v0 = a4.x + ad4.x; v0 = v0 >= 0.f ? v0 : NEG_SLOPE * v0;
        float v1 = a4.y + ad4.y; v1 = v1 >= 0.f ? v1 : NEG_SLOPE * v1;
        float v2 = a4.z + ad4.z; v2 = v2 >= 0.f ? v2 : NEG_SLOPE * v2;
        float v3 = a4.w + ad4.w; v3 = v3 >= 0.f ? v3 : NEG_SLOPE * v3;
        m0 = fmaxf(m0, v0); m1 = fmaxf(m1, v1);
        m2 = fmaxf(m2, v2); m3 = fmaxf(m3, v3);
    }
#pragma unroll
    for (int off = 32; off > 0; off >>= 1) {
        m0 = fmaxf(m0, __shfl_xor(m0, off, 64));
        m1 = fmaxf(m1, __shfl_xor(m1, off, 64));
        m2 = fmaxf(m2, __shfl_xor(m2, off, 64));
        m3 = fmaxf(m3, __shfl_xor(m3, off, 64));
    }

    // ---- phase 2: weighted accumulation, 2 edges per iteration ----
    const int half = lane >> 5;
    const int l    = lane & 31;                 // 4 cols per lane: l*4..l*4+3
    const int hd   = l >> 3;                    // head of those cols
    const float adh = hd == 0 ? ad4.x : hd == 1 ? ad4.y : hd == 2 ? ad4.z : ad4.w;
    const float mh  = hd == 0 ? m0  : hd == 1 ? m1  : hd == 2 ? m2  : m3;

    float4 acc = {0.f, 0.f, 0.f, 0.f};
    float wsum = 0.f;
    for (int base = e0; base < e1; base += 2) {
        const int e = base + half;
        if (e < e1) {
            const int s = esrc[e];
            const float4 a4 = *(const float4*)&as[s * 4];
            float ash = hd == 0 ? a4.x : hd == 1 ? a4.y : hd == 2 ? a4.z : a4.w;
            float ev = ash + adh;
            ev = ev >= 0.f ? ev : NEG_SLOPE * ev;
            const float w = __expf(ev - mh);
            const float4 hv = *(const float4*)&h[(long long)s * 128 + l * 4];
            acc.x = fmaf(w, hv.x, acc.x);
            acc.y = fmaf(w, hv.y, acc.y);
            acc.z = fmaf(w, hv.z, acc.z);
            acc.w = fmaf(w, hv.w, acc.w);
            wsum += w;
        }
    }
    acc.x += __shfl_xor(acc.x, 32, 64);
    acc.y += __shfl_xor(acc.y, 32, 64);
    acc.z += __shfl_xor(acc.z, 32, 64);
    acc.w += __shfl_xor(acc.w, 32, 64);
    wsum  += __shfl_xor(wsum, 32, 64);

    if (half == 0) {
        const float inv = 1.f / (wsum + 1e-16f);
        float4 o; o.x = acc.x * inv; o.y = acc.y * inv; o.z = acc.z * inv; o.w = acc.w * inv;
        *(float4*)&out[(long long)n * 128 + l * 4] = o;
    }
}

// ========== Fused GAT aggregation, layer 2 (H=1, C=32): one wave per dst ==========
__global__ __launch_bounds__(256) void k_agg2(
    const int* __restrict__ row, const int* __restrict__ esrc,
    const float* __restrict__ as, const float* __restrict__ ad,   // [N]
    const float* __restrict__ h,                                  // [N][32]
    float* __restrict__ out, int N)                               // [N][32]
{
    const int lane = threadIdx.x & 63;
    const int wid  = threadIdx.x >> 6;
    const int n = blockIdx.x * 4 + wid;
    if (n >= N) return;
    const int e0 = row[n], e1 = row[n + 1];
    const float adv = ad[n];

    float m = -INFINITY;
    for (int e = e0 + lane; e < e1; e += 64) {
        float ev = as[esrc[e]] + adv;
        ev = ev >= 0.f ? ev : NEG_SLOPE * ev;
        m = fmaxf(m, ev);
    }
#pragma unroll
    for (int off = 32; off > 0; off >>= 1) m = fmaxf(m, __shfl_xor(m, off, 64));

    const int g  = lane >> 3;                    // edge slot 0..7
    const int l8 = lane & 7;                     // 4 cols: l8*4..l8*4+3
    float4 acc = {0.f, 0.f, 0.f, 0.f};
    float wsum = 0.f;
    for (int base = e0; base < e1; base += 8) {
        const int e = base + g;
        if (e < e1) {
            const int s = esrc[e];
            float ev = as[s] + adv;
            ev = ev >= 0.f ? ev : NEG_SLOPE * ev;
            const float w = __expf(ev - m);
            const float4 hv = *(const float4*)&h[(long long)s * 32 + l8 * 4];
            acc.x = fmaf(w, hv.x, acc.x);
            acc.y = fmaf(w, hv.y, acc.y);
            acc.z = fmaf(w, hv.z, acc.z);
            acc.w = fmaf(w, hv.w, acc.w);
            wsum += w;
        }
    }
#pragma unroll
    for (int off = 8; off < 64; off <<= 1) {
        acc.x += __shfl_xor(acc.x, off, 64);
        acc.y += __shfl_xor(acc.y, off, 64);
        acc.z += __shfl_xor(acc.z, off, 64);
        acc.w += __shfl_xor(acc.w, off, 64);
        wsum  += __shfl_xor(wsum, off, 64);
    }
    if (lane < 8) {
        const float inv = 1.f / (wsum + 1e-16f);
        float4 o; o.x = acc.x * inv; o.y = acc.y * inv; o.z = acc.z * inv; o.w = acc.w * inv;
        *(float4*)&out[(long long)n * 32 + lane * 4] = o;
    }
}

// ========== Gate MLP: full-grid parallel, one 32-lane group per node ==========
__global__ __launch_bounds__(256) void k_gate(
    const float* __restrict__ out2, const float* __restrict__ b2,
    const float* __restrict__ gw1, const float* __restrict__ gb1,
    const float* __restrict__ gw2, const float* __restrict__ gb2,
    float* __restrict__ gate, int N)
{
    const int c = threadIdx.x & 31, grp = threadIdx.x >> 5;
    const int n = blockIdx.x * 8 + grp;
    if (n >= N) return;
    float v = out2[(long long)n * 32 + c] + b2[c];
    v = elu1f(v);
    float t1 = gb1[c];
#pragma unroll
    for (int k = 0; k < 32; k++) {
        float hk = __shfl(v, k, 32);
        t1 = fmaf(hk, gw1[k * 32 + c], t1);
    }
    t1 = fmaxf(t1, 0.f);
    float gv = t1 * gw2[c];
#pragma unroll
    for (int off = 16; off > 0; off >>= 1) gv += __shfl_xor(gv, off, 32);
    if (c == 0) gate[n] = gv + gb2[0];
}

// ========== Pool reduce: one block per graph, zero atomics, no MLP inside ==========
__global__ __launch_bounds__(256) void k_pool2(
    const float* __restrict__ out2, const float* __restrict__ b2,
    const float* __restrict__ gate, const int* __restrict__ batch,
    float* __restrict__ out, int N)
{
    const int g   = blockIdx.x;
    const int t   = threadIdx.x;
    const int c   = t & 31;
    const int grp = t >> 5;

    __shared__ int   sbound[2];
    __shared__ float sred[4];
    __shared__ float sacc[8][32];
    __shared__ float swsum[8];

    if (t < 2) {
        int target = g + t;
        int lo = 0, hi = N;
        while (lo < hi) { int mid = (lo + hi) >> 1; if (batch[mid] < target) lo = mid + 1; else hi = mid; }
        sbound[t] = lo;
    }
    __syncthreads();
    const int s0 = sbound[0], s1 = sbound[1];

    // ---- pass A: max over gate[s0:s1), thread-strided ----
    float mloc = -INFINITY;
    for (int n = s0 + t; n < s1; n += 256) mloc = fmaxf(mloc, gate[n]);
#pragma unroll
    for (int off = 32; off > 0; off >>= 1) mloc = fmaxf(mloc, __shfl_xor(mloc, off, 64));
    if ((t & 63) == 0) sred[t >> 6] = mloc;
    __syncthreads();
    const float gm = fmaxf(fmaxf(sred[0], sred[1]), fmaxf(sred[2], sred[3]));

    // ---- pass B: weighted accumulation ----
    float acc = 0.f, wsum = 0.f;
    const float bc = b2[c];
    for (int n = s0 + grp; n < s1; n += 8) {
        float v = elu1f(out2[(long long)n * 32 + c] + bc);
        float ge = __expf(gate[n] - gm);
        acc = fmaf(ge, v, acc);
        wsum += ge;
    }
    sacc[grp][c] = acc;
    if (c == 0) swsum[grp] = wsum;
    __syncthreads();

    if (grp == 0) {
        float a = 0.f, wtot = 0.f;
#pragma unroll
        for (int i = 0; i < 8; i++) { a += sacc[i][c]; wtot += swsum[i]; }
        out[g * 32 + c] = a / (wtot + 1e-16f);
    }
}

extern "C" void kernel_launch(void* const* d_in, const int* in_sizes, int n_in,
                              void* d_out, int out_size, void* d_ws, size_t ws_size,
                              hipStream_t stream)
{
    const float* x    = (const float*)d_in[0];
    const int*   ei   = (const int*)d_in[1];
    const int*   batch= (const int*)d_in[2];
    const float* W1   = (const float*)d_in[3];
    const float* as1w = (const float*)d_in[4];
    const float* ad1w = (const float*)d_in[5];
    const float* b1   = (const float*)d_in[6];
    const float* W2   = (const float*)d_in[7];
    const float* as2w = (const float*)d_in[8];
    const float* ad2w = (const float*)d_in[9];
    const float* b2   = (const float*)d_in[10];
    const float* gw1  = (const float*)d_in[11];
    const float* gb1  = (const float*)d_in[12];
    const float* gw2  = (const float*)d_in[13];
    const float* gb2  = (const float*)d_in[14];

    const int N  = in_sizes[2];
    const int E  = in_sizes[1] / 2;
    const int Et = E + N;
    const int nb = (N + 255) / 256;

    float* ws = (float*)d_ws;
    size_t o = 0;
    float* h1   = ws + o; o += (size_t)N * 128;
    float* out1 = ws + o; o += (size_t)N * 128;
    float* h2   = ws + o; o += (size_t)N * 32;
    float* out2 = ws + o; o += (size_t)N * 32;
    float* a_s1 = ws + o; o += (size_t)N * 4;
    float* a_d1 = ws + o; o += (size_t)N * 4;
    float* a_s2 = ws + o; o += (size_t)N;
    float* a_d2 = ws + o; o += (size_t)N;
    float* gate = ws + o; o += (size_t)N;
    int*   rowp = (int*)(ws + o); o += (size_t)N + 1;
    int*   curs = (int*)(ws + o); o += (size_t)N;
    int*   esrc = (int*)(ws + o); o += (size_t)Et;
    int*   bsum = (int*)(ws + o); o += 256;
    // ---- zeroed region (one memset): deg ----
    size_t zstart = o;
    int*   deg  = (int*)(ws + o); o += (size_t)N;
    size_t zbytes = (o - zstart) * sizeof(float);

    hipMemsetAsync(ws + zstart, 0, zbytes, stream);

    // ---- CSR build (shared by both layers) ----
    k_deg    <<<(Et + 255) / 256, 256, 0, stream>>>(ei, E, Et, deg);
    k_scan1  <<<nb, 256, 0, stream>>>(deg, N, rowp, bsum);
    k_scan2  <<<1, 256, 0, stream>>>(bsum, nb);
    k_scan3  <<<nb, 256, 0, stream>>>(rowp, bsum, N, Et, curs);
    k_scatter<<<(Et + 255) / 256, 256, 0, stream>>>(ei, E, Et, curs, esrc);

    // ---- GAT layer 1 ----
    k_gemm1<<<(N + 15) / 16, 128, 0, stream>>>(x, W1, as1w, ad1w, h1, a_s1, a_d1, N);
    k_agg1 <<<(N + 3) / 4, 256, 0, stream>>>(rowp, esrc, a_s1, a_d1, h1, out1, N);

    // ---- GAT layer 2 (elu(out1+b1) fused into gemm2 load) ----
    k_gemm2<<<(N + 31) / 32, 256, 0, stream>>>(out1, W2, b1, as2w, ad2w, h2, a_s2, a_d2, N);
    k_agg2 <<<(N + 3) / 4, 256, 0, stream>>>(rowp, esrc, a_s2, a_d2, h2, out2, N);

    // ---- attentional pooling: parallel gate, then per-graph reduce ----
    k_gate <<<(N + 7) / 8, 256, 0, stream>>>(out2, b2, gw1, gb1, gw2, gb2, gate, N);
    k_pool2<<<64, 256, 0, stream>>>(out2, b2, gate, batch, (float*)d_out, N);
}

// Round 6
// 403.961 us; speedup vs baseline: 3.8374x; 1.0210x over previous
//
#include <hip/hip_runtime.h>
#include <hip/hip_bf16.h>

#define NEG_SLOPE 0.2f

__device__ __forceinline__ float elu1f(float v) {
    return v > 0.f ? v : expm1f(v);
}

// ======================= CSR build (by dst) =======================
__global__ void k_deg(const int* __restrict__ ei, int E, int Et, int* __restrict__ deg)
{
    int i = blockIdx.x * 256 + threadIdx.x;
    if (i >= Et) return;
    int d = (i < E) ? ei[E + i] : i - E;
    atomicAdd(&deg[d], 1);
}

__global__ __launch_bounds__(256) void k_scan1(const int* __restrict__ deg, int N,
                                               int* __restrict__ row, int* __restrict__ bsum)
{
    __shared__ int s[256];
    int i = blockIdx.x * 256 + threadIdx.x;
    int v = (i < N) ? deg[i] : 0;
    s[threadIdx.x] = v;
    __syncthreads();
#pragma unroll
    for (int off = 1; off < 256; off <<= 1) {
        int t = (threadIdx.x >= off) ? s[threadIdx.x - off] : 0;
        __syncthreads();
        s[threadIdx.x] += t;
        __syncthreads();
    }
    if (i < N) row[i] = s[threadIdx.x] - v;          // exclusive
    if (threadIdx.x == 255) bsum[blockIdx.x] = s[255];
}

__global__ __launch_bounds__(256) void k_scan2(int* __restrict__ bsum, int nb)
{
    __shared__ int s[256];
    int v = (threadIdx.x < nb) ? bsum[threadIdx.x] : 0;
    s[threadIdx.x] = v;
    __syncthreads();
#pragma unroll
    for (int off = 1; off < 256; off <<= 1) {
        int t = (threadIdx.x >= off) ? s[threadIdx.x - off] : 0;
        __syncthreads();
        s[threadIdx.x] += t;
        __syncthreads();
    }
    if (threadIdx.x < nb) bsum[threadIdx.x] = s[threadIdx.x] - v;   // exclusive
}

__global__ void k_scan3(int* __restrict__ row, const int* __restrict__ bsum,
                        int N, int Et, int* __restrict__ cursor)
{
    int i = blockIdx.x * 256 + threadIdx.x;
    if (i < N) {
        int r = row[i] + bsum[blockIdx.x];
        row[i] = r;
        cursor[i] = r;
    }
    if (i == 0) row[N] = Et;
}

__global__ void k_scatter(const int* __restrict__ ei, int E, int Et,
                          int* __restrict__ cursor, int* __restrict__ esrc)
{
    int i = blockIdx.x * 256 + threadIdx.x;
    if (i >= Et) return;
    int s, d;
    if (i < E) { s = ei[i]; d = ei[E + i]; } else { s = i - E; d = s; }
    int pos = atomicAdd(&cursor[d], 1);
    esrc[pos] = s;
}

// ---------------- GEMM1 v2: h1 = x @ W1 (128->128), fused a_src1/a_dst1 --------------
// 256 threads, 32-row tile, KT=16 -> LDS 10.25KB (occupancy knee was 18.4KB @ 18%).
__global__ __launch_bounds__(256) void k_gemm1(
    const float* __restrict__ x, const float* __restrict__ W,
    const float* __restrict__ att_s, const float* __restrict__ att_d,
    float* __restrict__ h1, float* __restrict__ as1, float* __restrict__ ad1, int N)
{
    __shared__ __align__(16) float sW[16][128];   // 8 KB
    __shared__ __align__(16) float sX[32][16];    // 2 KB
    const int t  = threadIdx.x;
    const int c  = t & 127;            // output column
    const int rh = t >> 7;             // row half: rows rh*16 .. rh*16+15
    const int row0 = blockIdx.x * 32;
    const float4* W4 = (const float4*)W;   // W row = 32 float4

    float acc[16];
#pragma unroll
    for (int i = 0; i < 16; i++) acc[i] = 0.f;

    for (int k0 = 0; k0 < 128; k0 += 16) {
        __syncthreads();
        // stage W tile: 16x128 = 512 float4, 2 per thread
#pragma unroll
        for (int j = 0; j < 2; j++) {
            int idx = j * 256 + t;                 // 0..511
            int r = idx >> 5, c4 = idx & 31;
            *(float4*)&sW[r][c4 * 4] = W4[(k0 + r) * 32 + c4];
        }
        // stage X tile: 32x16 = 128 float4, threads 0..127
        if (t < 128) {
            int r = t >> 2, c4 = t & 3;
            int row = row0 + r;
            float4 v = {0.f, 0.f, 0.f, 0.f};
            if (row < N) v = *(const float4*)&x[(long long)row * 128 + k0 + c4 * 4];
            *(float4*)&sX[r][c4 * 4] = v;
        }
        __syncthreads();
#pragma unroll
        for (int kk = 0; kk < 16; kk += 4) {
            float w0 = sW[kk][c], w1 = sW[kk + 1][c], w2 = sW[kk + 2][c], w3 = sW[kk + 3][c];
#pragma unroll
            for (int i = 0; i < 16; i++) {
                float4 xv = *(const float4*)&sX[rh * 16 + i][kk];   // broadcast
                acc[i] = fmaf(xv.x, w0, acc[i]);
                acc[i] = fmaf(xv.y, w1, acc[i]);
                acc[i] = fmaf(xv.z, w2, acc[i]);
                acc[i] = fmaf(xv.w, w3, acc[i]);
            }
        }
    }

    const float av_s = att_s[c], av_d = att_d[c];
    const int lane = t & 31;
    const int head = c >> 5;
#pragma unroll
    for (int i = 0; i < 16; i++) {
        int row = row0 + rh * 16 + i;
        if (row >= N) break;                    // uniform across each half
        float v = acc[i];
        h1[(long long)row * 128 + c] = v;
        float s = v * av_s, d = v * av_d;
#pragma unroll
        for (int off = 16; off > 0; off >>= 1) {
            s += __shfl_xor(s, off, 32);
            d += __shfl_xor(d, off, 32);
        }
        if (lane == 0) { as1[row * 4 + head] = s; ad1[row * 4 + head] = d; }
    }
}

// ---------------- GEMM2 v2: h2 = elu(out1+b1) @ W2 (128->32), KT=32, LDS 8KB ---------
__global__ __launch_bounds__(256) void k_gemm2(
    const float* __restrict__ xin, const float* __restrict__ W,
    const float* __restrict__ b1,
    const float* __restrict__ att_s, const float* __restrict__ att_d,
    float* __restrict__ h2, float* __restrict__ as2, float* __restrict__ ad2, int N)
{
    __shared__ __align__(16) float sW[32][32];    // 4 KB
    __shared__ __align__(16) float sX[32][32];    // 4 KB
    const int t = threadIdx.x;
    const int row0 = blockIdx.x * 32;
    const int c = t & 31, rsub = t >> 5;
    const float4* W4 = (const float4*)W;          // W row = 8 float4

    float acc[4] = {0.f, 0.f, 0.f, 0.f};

    for (int k0 = 0; k0 < 128; k0 += 32) {
        __syncthreads();
        {   // stage W tile: 32x32 = 256 float4, 1 per thread
            int r = t >> 3, c4 = t & 7;
            *(float4*)&sW[r][c4 * 4] = W4[(k0 + r) * 8 + c4];
        }
        {   // stage X tile (elu(x+b1)): 32x32 = 256 float4, 1 per thread
            int r = t >> 3, c4 = t & 7;
            int row = row0 + r;
            float4 v = {0.f, 0.f, 0.f, 0.f};
            if (row < N) {
                v = *(const float4*)&xin[(long long)row * 128 + k0 + c4 * 4];
                float4 b = *(const float4*)&b1[k0 + c4 * 4];
                v.x = elu1f(v.x + b.x); v.y = elu1f(v.y + b.y);
                v.z = elu1f(v.z + b.z); v.w = elu1f(v.w + b.w);
            }
            *(float4*)&sX[r][c4 * 4] = v;
        }
        __syncthreads();
#pragma unroll
        for (int p = 0; p < 4; p++) {
            int r = p * 8 + rsub;
#pragma unroll
            for (int k = 0; k < 32; k += 4) {
                float4 xv = *(const float4*)&sX[r][k];
                acc[p] = fmaf(xv.x, sW[k][c], acc[p]);
                acc[p] = fmaf(xv.y, sW[k + 1][c], acc[p]);
                acc[p] = fmaf(xv.z, sW[k + 2][c], acc[p]);
                acc[p] = fmaf(xv.w, sW[k + 3][c], acc[p]);
            }
        }
    }

    const float av_s = att_s[c], av_d = att_d[c];
#pragma unroll
    for (int p = 0; p < 4; p++) {
        int row = row0 + p * 8 + rsub;
        if (row < N) {
            float a = acc[p];
            h2[(long long)row * 32 + c] = a;
            float s = a * av_s, d = a * av_d;
#pragma unroll
            for (int off = 16; off > 0; off >>= 1) {
                s += __shfl_xor(s, off, 32);
                d += __shfl_xor(d, off, 32);
            }
            if (c == 0) { as2[row] = s; ad2[row] = d; }
        }
    }
}

// ========== Fused GAT aggregation, layer 1 (H=4, C=32): one wave per dst ==========
__global__ __launch_bounds__(256) void k_agg1(
    const int* __restrict__ row, const int* __restrict__ esrc,
    const float* __restrict__ as, const float* __restrict__ ad,   // [N][4]
    const float* __restrict__ h,                                  // [N][128]
    float* __restrict__ out, int N)                               // [N][128]
{
    const int lane = threadIdx.x & 63;
    const int wid  = threadIdx.x >> 6;
    const int n = blockIdx.x * 4 + wid;
    if (n >= N) return;
    const int e0 = row[n], e1 = row[n + 1];

    const float4 ad4 = *(const float4*)&ad[n * 4];

    // ---- phase 1: per-head max over in-edges ----
    float m0 = -INFINITY, m1 = -INFINITY, m2 = -INFINITY, m3 = -INFINITY;
    for (int e = e0 + lane; e < e1; e += 64) {
        const int s = esrc[e];
        const float4 a4 = *(const float4*)&as[s * 4];
        float v0 = a4.x + ad4.x; v0 = v0 >= 0.f ? v0 : NEG_SLOPE * v0;
        float v1 = a4.y + ad4.y; v1 = v1 >= 0.f ? v1 : NEG_SLOPE * v1;
        float v2 = a4.z + ad4.z; v2 = v2 >= 0.f ? v2 : NEG_SLOPE * v2;
        float v3 = a4.w + ad4.w; v3 = v3 >= 0.f ? v3 : NEG_SLOPE * v3;
        m0 = fmaxf(m0, v0); m1 = fmaxf(m1, v1);
        m2 = fmaxf(m2, v2); m3 = fmaxf(m3, v3);
    }
#pragma unroll
    for (int off = 32; off > 0; off >>= 1) {
        m0 = fmaxf(m0, __shfl_xor(m0, off, 64));
        m1 = fmaxf(m1, __shfl_xor(m1, off, 64));
        m2 = fmaxf(m2, __shfl_xor(m2, off, 64));
        m3 = fmaxf(m3, __shfl_xor(m3, off, 64));
    }

    // ---- phase 2: weighted accumulation, 2 edges per iteration ----
    const int half = lane >> 5;
    const int l    = lane & 31;                 // 4 cols per lane: l*4..l*4+3
    const int hd   = l >> 3;                    // head of those cols
    const float adh = hd == 0 ? ad4.x : hd == 1 ? ad4.y : hd == 2 ? ad4.z : ad4.w;
    const float mh  = hd == 0 ? m0  : hd == 1 ? m1  : hd == 2 ? m2  : m3;

    float4 acc = {0.f, 0.f, 0.f, 0.f};
    float wsum = 0.f;
    for (int base = e0; base < e1; base += 2) {
        const int e = base + half;
        if (e < e1) {
            const int s = esrc[e];
            const float4 a4 = *(const float4*)&as[s * 4];
            float ash = hd == 0 ? a4.x : hd == 1 ? a4.y : hd == 2 ? a4.z : a4.w;
            float ev = ash + adh;
            ev = ev >= 0.f ? ev : NEG_SLOPE * ev;
            const float w = __expf(ev - mh);
            const float4 hv = *(const float4*)&h[(long long)s * 128 + l * 4];
            acc.x = fmaf(w, hv.x, acc.x);
            acc.y = fmaf(w, hv.y, acc.y);
            acc.z = fmaf(w, hv.z, acc.z);
            acc.w = fmaf(w, hv.w, acc.w);
            wsum += w;
        }
    }
    acc.x += __shfl_xor(acc.x, 32, 64);
    acc.y += __shfl_xor(acc.y, 32, 64);
    acc.z += __shfl_xor(acc.z, 32, 64);
    acc.w += __shfl_xor(acc.w, 32, 64);
    wsum  += __shfl_xor(wsum, 32, 64);

    if (half == 0) {
        const float inv = 1.f / (wsum + 1e-16f);
        float4 o; o.x = acc.x * inv; o.y = acc.y * inv; o.z = acc.z * inv; o.w = acc.w * inv;
        *(float4*)&out[(long long)n * 128 + l * 4] = o;
    }
}

// ========== Fused GAT aggregation, layer 2 (H=1, C=32): one wave per dst ==========
__global__ __launch_bounds__(256) void k_agg2(
    const int* __restrict__ row, const int* __restrict__ esrc,
    const float* __restrict__ as, const float* __restrict__ ad,   // [N]
    const float* __restrict__ h,                                  // [N][32]
    float* __restrict__ out, int N)                               // [N][32]
{
    const int lane = threadIdx.x & 63;
    const int wid  = threadIdx.x >> 6;
    const int n = blockIdx.x * 4 + wid;
    if (n >= N) return;
    const int e0 = row[n], e1 = row[n + 1];
    const float adv = ad[n];

    float m = -INFINITY;
    for (int e = e0 + lane; e < e1; e += 64) {
        float ev = as[esrc[e]] + adv;
        ev = ev >= 0.f ? ev : NEG_SLOPE * ev;
        m = fmaxf(m, ev);
    }
#pragma unroll
    for (int off = 32; off > 0; off >>= 1) m = fmaxf(m, __shfl_xor(m, off, 64));

    const int g  = lane >> 3;                    // edge slot 0..7
    const int l8 = lane & 7;                     // 4 cols: l8*4..l8*4+3
    float4 acc = {0.f, 0.f, 0.f, 0.f};
    float wsum = 0.f;
    for (int base = e0; base < e1; base += 8) {
        const int e = base + g;
        if (e < e1) {
            const int s = esrc[e];
            float ev = as[s] + adv;
            ev = ev >= 0.f ? ev : NEG_SLOPE * ev;
            const float w = __expf(ev - m);
            const float4 hv = *(const float4*)&h[(long long)s * 32 + l8 * 4];
            acc.x = fmaf(w, hv.x, acc.x);
            acc.y = fmaf(w, hv.y, acc.y);
            acc.z = fmaf(w, hv.z, acc.z);
            acc.w = fmaf(w, hv.w, acc.w);
            wsum += w;
        }
    }
#pragma unroll
    for (int off = 8; off < 64; off <<= 1) {
        acc.x += __shfl_xor(acc.x, off, 64);
        acc.y += __shfl_xor(acc.y, off, 64);
        acc.z += __shfl_xor(acc.z, off, 64);
        acc.w += __shfl_xor(acc.w, off, 64);
        wsum  += __shfl_xor(wsum, off, 64);
    }
    if (lane < 8) {
        const float inv = 1.f / (wsum + 1e-16f);
        float4 o; o.x = acc.x * inv; o.y = acc.y * inv; o.z = acc.z * inv; o.w = acc.w * inv;
        *(float4*)&out[(long long)n * 32 + lane * 4] = o;
    }
}

// ========== Gate MLP: full-grid parallel, one 32-lane group per node ==========
__global__ __launch_bounds__(256) void k_gate(
    const float* __restrict__ out2, const float* __restrict__ b2,
    const float* __restrict__ gw1, const float* __restrict__ gb1,
    const float* __restrict__ gw2, const float* __restrict__ gb2,
    float* __restrict__ gate, int N)
{
    const int c = threadIdx.x & 31, grp = threadIdx.x >> 5;
    const int n = blockIdx.x * 8 + grp;
    if (n >= N) return;
    float v = out2[(long long)n * 32 + c] + b2[c];
    v = elu1f(v);
    float t1 = gb1[c];
#pragma unroll
    for (int k = 0; k < 32; k++) {
        float hk = __shfl(v, k, 32);
        t1 = fmaf(hk, gw1[k * 32 + c], t1);
    }
    t1 = fmaxf(t1, 0.f);
    float gv = t1 * gw2[c];
#pragma unroll
    for (int off = 16; off > 0; off >>= 1) gv += __shfl_xor(gv, off, 32);
    if (c == 0) gate[n] = gv + gb2[0];
}

// ========== Pool reduce: one block per graph, zero atomics, no MLP inside ==========
__global__ __launch_bounds__(256) void k_pool2(
    const float* __restrict__ out2, const float* __restrict__ b2,
    const float* __restrict__ gate, const int* __restrict__ batch,
    float* __restrict__ out, int N)
{
    const int g   = blockIdx.x;
    const int t   = threadIdx.x;
    const int c   = t & 31;
    const int grp = t >> 5;

    __shared__ int   sbound[2];
    __shared__ float sred[4];
    __shared__ float sacc[8][32];
    __shared__ float swsum[8];

    if (t < 2) {
        int target = g + t;
        int lo = 0, hi = N;
        while (lo < hi) { int mid = (lo + hi) >> 1; if (batch[mid] < target) lo = mid + 1; else hi = mid; }
        sbound[t] = lo;
    }
    __syncthreads();
    const int s0 = sbound[0], s1 = sbound[1];

    // ---- pass A: max over gate[s0:s1), thread-strided ----
    float mloc = -INFINITY;
    for (int n = s0 + t; n < s1; n += 256) mloc = fmaxf(mloc, gate[n]);
#pragma unroll
    for (int off = 32; off > 0; off >>= 1) mloc = fmaxf(mloc, __shfl_xor(mloc, off, 64));
    if ((t & 63) == 0) sred[t >> 6] = mloc;
    __syncthreads();
    const float gm = fmaxf(fmaxf(sred[0], sred[1]), fmaxf(sred[2], sred[3]));

    // ---- pass B: weighted accumulation ----
    float acc = 0.f, wsum = 0.f;
    const float bc = b2[c];
    for (int n = s0 + grp; n < s1; n += 8) {
        float v = elu1f(out2[(long long)n * 32 + c] + bc);
        float ge = __expf(gate[n] - gm);
        acc = fmaf(ge, v, acc);
        wsum += ge;
    }
    sacc[grp][c] = acc;
    if (c == 0) swsum[grp] = wsum;
    __syncthreads();

    if (grp == 0) {
        float a = 0.f, wtot = 0.f;
#pragma unroll
        for (int i = 0; i < 8; i++) { a += sacc[i][c]; wtot += swsum[i]; }
        out[g * 32 + c] = a / (wtot + 1e-16f);
    }
}

extern "C" void kernel_launch(void* const* d_in, const int* in_sizes, int n_in,
                              void* d_out, int out_size, void* d_ws, size_t ws_size,
                              hipStream_t stream)
{
    const float* x    = (const float*)d_in[0];
    const int*   ei   = (const int*)d_in[1];
    const int*   batch= (const int*)d_in[2];
    const float* W1   = (const float*)d_in[3];
    const float* as1w = (const float*)d_in[4];
    const float* ad1w = (const float*)d_in[5];
    const float* b1   = (const float*)d_in[6];
    const float* W2   = (const float*)d_in[7];
    const float* as2w = (const float*)d_in[8];
    const float* ad2w = (const float*)d_in[9];
    const float* b2   = (const float*)d_in[10];
    const float* gw1  = (const float*)d_in[11];
    const float* gb1  = (const float*)d_in[12];
    const float* gw2  = (const float*)d_in[13];
    const float* gb2  = (const float*)d_in[14];

    const int N  = in_sizes[2];
    const int E  = in_sizes[1] / 2;
    const int Et = E + N;
    const int nb = (N + 255) / 256;

    float* ws = (float*)d_ws;
    size_t o = 0;
    float* h1   = ws + o; o += (size_t)N * 128;
    float* out1 = ws + o; o += (size_t)N * 128;
    float* h2   = ws + o; o += (size_t)N * 32;
    float* out2 = ws + o; o += (size_t)N * 32;
    float* a_s1 = ws + o; o += (size_t)N * 4;
    float* a_d1 = ws + o; o += (size_t)N * 4;
    float* a_s2 = ws + o; o += (size_t)N;
    float* a_d2 = ws + o; o += (size_t)N;
    float* gate = ws + o; o += (size_t)N;
    int*   rowp = (int*)(ws + o); o += (size_t)N + 1;
    int*   curs = (int*)(ws + o); o += (size_t)N;
    int*   esrc = (int*)(ws + o); o += (size_t)Et;
    int*   bsum = (int*)(ws + o); o += 256;
    // ---- zeroed region (one memset): deg ----
    size_t zstart = o;
    int*   deg  = (int*)(ws + o); o += (size_t)N;
    size_t zbytes = (o - zstart) * sizeof(float);

    hipMemsetAsync(ws + zstart, 0, zbytes, stream);

    // ---- CSR build (shared by both layers) ----
    k_deg    <<<(Et + 255) / 256, 256, 0, stream>>>(ei, E, Et, deg);
    k_scan1  <<<nb, 256, 0, stream>>>(deg, N, rowp, bsum);
    k_scan2  <<<1, 256, 0, stream>>>(bsum, nb);
    k_scan3  <<<nb, 256, 0, stream>>>(rowp, bsum, N, Et, curs);
    k_scatter<<<(Et + 255) / 256, 256, 0, stream>>>(ei, E, Et, curs, esrc);

    // ---- GAT layer 1 ----
    k_gemm1<<<(N + 31) / 32, 256, 0, stream>>>(x, W1, as1w, ad1w, h1, a_s1, a_d1, N);
    k_agg1 <<<(N + 3) / 4, 256, 0, stream>>>(rowp, esrc, a_s1, a_d1, h1, out1, N);

    // ---- GAT layer 2 (elu(out1+b1) fused into gemm2 load) ----
    k_gemm2<<<(N + 31) / 32, 256, 0, stream>>>(out1, W2, b1, as2w, ad2w, h2, a_s2, a_d2, N);
    k_agg2 <<<(N + 3) / 4, 256, 0, stream>>>(rowp, esrc, a_s2, a_d2, h2, out2, N);

    // ---- attentional pooling: parallel gate, then per-graph reduce ----
    k_gate <<<(N + 7) / 8, 256, 0, stream>>>(out2, b2, gw1, gb1, gw2, gb2, gate, N);
    k_pool2<<<64, 256, 0, stream>>>(out2, b2, gate, batch, (float*)d_out, N);
}

// Round 7
// 374.615 us; speedup vs baseline: 4.1380x; 1.0783x over previous
//
#include <hip/hip_runtime.h>
#include <hip/hip_bf16.h>

#define NEG_SLOPE 0.2f

__device__ __forceinline__ float elu1f(float v) {
    return v > 0.f ? v : expm1f(v);
}
__device__ __forceinline__ float bf2f(ushort u) {
    return __uint_as_float(((unsigned)u) << 16);
}

// ======================= CSR build (by dst) =======================
__global__ void k_deg(const int* __restrict__ ei, int E, int Et, int* __restrict__ deg)
{
    int i = blockIdx.x * 256 + threadIdx.x;
    if (i >= Et) return;
    int d = (i < E) ? ei[E + i] : i - E;
    atomicAdd(&deg[d], 1);
}

__global__ __launch_bounds__(256) void k_scan1(const int* __restrict__ deg, int N,
                                               int* __restrict__ row, int* __restrict__ bsum)
{
    __shared__ int s[256];
    int i = blockIdx.x * 256 + threadIdx.x;
    int v = (i < N) ? deg[i] : 0;
    s[threadIdx.x] = v;
    __syncthreads();
#pragma unroll
    for (int off = 1; off < 256; off <<= 1) {
        int t = (threadIdx.x >= off) ? s[threadIdx.x - off] : 0;
        __syncthreads();
        s[threadIdx.x] += t;
        __syncthreads();
    }
    if (i < N) row[i] = s[threadIdx.x] - v;          // exclusive
    if (threadIdx.x == 255) bsum[blockIdx.x] = s[255];
}

__global__ __launch_bounds__(256) void k_scan2(int* __restrict__ bsum, int nb)
{
    __shared__ int s[256];
    int v = (threadIdx.x < nb) ? bsum[threadIdx.x] : 0;
    s[threadIdx.x] = v;
    __syncthreads();
#pragma unroll
    for (int off = 1; off < 256; off <<= 1) {
        int t = (threadIdx.x >= off) ? s[threadIdx.x - off] : 0;
        __syncthreads();
        s[threadIdx.x] += t;
        __syncthreads();
    }
    if (threadIdx.x < nb) bsum[threadIdx.x] = s[threadIdx.x] - v;   // exclusive
}

__global__ void k_scan3(int* __restrict__ row, const int* __restrict__ bsum,
                        int N, int Et, int* __restrict__ cursor)
{
    int i = blockIdx.x * 256 + threadIdx.x;
    if (i < N) {
        int r = row[i] + bsum[blockIdx.x];
        row[i] = r;
        cursor[i] = r;
    }
    if (i == 0) row[N] = Et;
}

__global__ void k_scatter(const int* __restrict__ ei, int E, int Et,
                          int* __restrict__ cursor, int* __restrict__ esrc)
{
    int i = blockIdx.x * 256 + threadIdx.x;
    if (i >= Et) return;
    int s, d;
    if (i < E) { s = ei[i]; d = ei[E + i]; } else { s = i - E; d = s; }
    int pos = atomicAdd(&cursor[d], 1);
    esrc[pos] = s;
}

// ---------------- GEMM1: h1(bf16) = x @ W1 (128->128), fused a_src1/a_dst1 -----------
__global__ __launch_bounds__(256) void k_gemm1(
    const float* __restrict__ x, const float* __restrict__ W,
    const float* __restrict__ att_s, const float* __restrict__ att_d,
    ushort* __restrict__ h1, float* __restrict__ as1, float* __restrict__ ad1, int N)
{
    __shared__ __align__(16) float sW[16][128];   // 8 KB
    __shared__ __align__(16) float sX[32][16];    // 2 KB
    const int t  = threadIdx.x;
    const int c  = t & 127;            // output column
    const int rh = t >> 7;             // row half: rows rh*16 .. rh*16+15
    const int row0 = blockIdx.x * 32;
    const float4* W4 = (const float4*)W;   // W row = 32 float4

    float acc[16];
#pragma unroll
    for (int i = 0; i < 16; i++) acc[i] = 0.f;

    for (int k0 = 0; k0 < 128; k0 += 16) {
        __syncthreads();
#pragma unroll
        for (int j = 0; j < 2; j++) {
            int idx = j * 256 + t;                 // 0..511
            int r = idx >> 5, c4 = idx & 31;
            *(float4*)&sW[r][c4 * 4] = W4[(k0 + r) * 32 + c4];
        }
        if (t < 128) {
            int r = t >> 2, c4 = t & 3;
            int row = row0 + r;
            float4 v = {0.f, 0.f, 0.f, 0.f};
            if (row < N) v = *(const float4*)&x[(long long)row * 128 + k0 + c4 * 4];
            *(float4*)&sX[r][c4 * 4] = v;
        }
        __syncthreads();
#pragma unroll
        for (int kk = 0; kk < 16; kk += 4) {
            float w0 = sW[kk][c], w1 = sW[kk + 1][c], w2 = sW[kk + 2][c], w3 = sW[kk + 3][c];
#pragma unroll
            for (int i = 0; i < 16; i++) {
                float4 xv = *(const float4*)&sX[rh * 16 + i][kk];   // broadcast
                acc[i] = fmaf(xv.x, w0, acc[i]);
                acc[i] = fmaf(xv.y, w1, acc[i]);
                acc[i] = fmaf(xv.z, w2, acc[i]);
                acc[i] = fmaf(xv.w, w3, acc[i]);
            }
        }
    }

    const float av_s = att_s[c], av_d = att_d[c];
    const int lane = t & 31;
    const int head = c >> 5;
#pragma unroll
    for (int i = 0; i < 16; i++) {
        int row = row0 + rh * 16 + i;
        if (row >= N) break;                    // uniform across each half
        float v = acc[i];
        h1[(long long)row * 128 + c] = __bfloat16_as_ushort(__float2bfloat16(v));
        float s = v * av_s, d = v * av_d;
#pragma unroll
        for (int off = 16; off > 0; off >>= 1) {
            s += __shfl_xor(s, off, 32);
            d += __shfl_xor(d, off, 32);
        }
        if (lane == 0) { as1[row * 4 + head] = s; ad1[row * 4 + head] = d; }
    }
}

// ---------------- GEMM2: h2 = elu(out1+b1) @ W2 (128->32), KT=32, LDS 8KB ------------
__global__ __launch_bounds__(256) void k_gemm2(
    const float* __restrict__ xin, const float* __restrict__ W,
    const float* __restrict__ b1,
    const float* __restrict__ att_s, const float* __restrict__ att_d,
    float* __restrict__ h2, float* __restrict__ as2, float* __restrict__ ad2, int N)
{
    __shared__ __align__(16) float sW[32][32];    // 4 KB
    __shared__ __align__(16) float sX[32][32];    // 4 KB
    const int t = threadIdx.x;
    const int row0 = blockIdx.x * 32;
    const int c = t & 31, rsub = t >> 5;
    const float4* W4 = (const float4*)W;          // W row = 8 float4

    float acc[4] = {0.f, 0.f, 0.f, 0.f};

    for (int k0 = 0; k0 < 128; k0 += 32) {
        __syncthreads();
        {   // stage W tile: 32x32 = 256 float4, 1 per thread
            int r = t >> 3, c4 = t & 7;
            *(float4*)&sW[r][c4 * 4] = W4[(k0 + r) * 8 + c4];
        }
        {   // stage X tile (elu(x+b1)): 32x32 = 256 float4, 1 per thread
            int r = t >> 3, c4 = t & 7;
            int row = row0 + r;
            float4 v = {0.f, 0.f, 0.f, 0.f};
            if (row < N) {
                v = *(const float4*)&xin[(long long)row * 128 + k0 + c4 * 4];
                float4 b = *(const float4*)&b1[k0 + c4 * 4];
                v.x = elu1f(v.x + b.x); v.y = elu1f(v.y + b.y);
                v.z = elu1f(v.z + b.z); v.w = elu1f(v.w + b.w);
            }
            *(float4*)&sX[r][c4 * 4] = v;
        }
        __syncthreads();
#pragma unroll
        for (int p = 0; p < 4; p++) {
            int r = p * 8 + rsub;
#pragma unroll
            for (int k = 0; k < 32; k += 4) {
                float4 xv = *(const float4*)&sX[r][k];
                acc[p] = fmaf(xv.x, sW[k][c], acc[p]);
                acc[p] = fmaf(xv.y, sW[k + 1][c], acc[p]);
                acc[p] = fmaf(xv.z, sW[k + 2][c], acc[p]);
                acc[p] = fmaf(xv.w, sW[k + 3][c], acc[p]);
            }
        }
    }

    const float av_s = att_s[c], av_d = att_d[c];
#pragma unroll
    for (int p = 0; p < 4; p++) {
        int row = row0 + p * 8 + rsub;
        if (row < N) {
            float a = acc[p];
            h2[(long long)row * 32 + c] = a;
            float s = a * av_s, d = a * av_d;
#pragma unroll
            for (int off = 16; off > 0; off >>= 1) {
                s += __shfl_xor(s, off, 32);
                d += __shfl_xor(d, off, 32);
            }
            if (c == 0) { as2[row] = s; ad2[row] = d; }
        }
    }
}

// ========== Fused GAT aggregation, layer 1 (H=4, C=32): one wave per dst ==========
// Phase 1: lane-parallel segment max. Phase 2: 4 edges in flight per iteration
// (2 per 32-lane half), h gathered as bf16 ushort4 (8 B/lane, 256 B/edge).
__global__ __launch_bounds__(256) void k_agg1(
    const int* __restrict__ row, const int* __restrict__ esrc,
    const float* __restrict__ as, const float* __restrict__ ad,   // [N][4]
    const ushort* __restrict__ h,                                 // [N][128] bf16
    float* __restrict__ out, int N)                               // [N][128]
{
    const int lane = threadIdx.x & 63;
    const int wid  = threadIdx.x >> 6;
    const int n = blockIdx.x * 4 + wid;
    if (n >= N) return;
    const int e0 = row[n], e1 = row[n + 1];

    const float4 ad4 = *(const float4*)&ad[n * 4];

    // ---- phase 1: per-head max over in-edges ----
    float m0 = -INFINITY, m1 = -INFINITY, m2 = -INFINITY, m3 = -INFINITY;
    for (int e = e0 + lane; e < e1; e += 64) {
        const int s = esrc[e];
        const float4 a4 = *(const float4*)&as[s * 4];
        float v0 = a4.x + ad4.x; v0 = v0 >= 0.f ? v0 : NEG_SLOPE * v0;
        float v1 = a4.y + ad4.y; v1 = v1 >= 0.f ? v1 : NEG_SLOPE * v1;
        float v2 = a4.z + ad4.z; v2 = v2 >= 0.f ? v2 : NEG_SLOPE * v2;
        float v3 = a4.w + ad4.w; v3 = v3 >= 0.f ? v3 : NEG_SLOPE * v3;
        m0 = fmaxf(m0, v0); m1 = fmaxf(m1, v1);
        m2 = fmaxf(m2, v2); m3 = fmaxf(m3, v3);
    }
#pragma unroll
    for (int off = 32; off > 0; off >>= 1) {
        m0 = fmaxf(m0, __shfl_xor(m0, off, 64));
        m1 = fmaxf(m1, __shfl_xor(m1, off, 64));
        m2 = fmaxf(m2, __shfl_xor(m2, off, 64));
        m3 = fmaxf(m3, __shfl_xor(m3, off, 64));
    }

    // ---- phase 2: 4 edges per iteration, 2 per half ----
    const int half = lane >> 5;
    const int l    = lane & 31;                 // 4 cols per lane: l*4..l*4+3
    const int hd   = l >> 3;                    // head of those cols
    const float adh = hd == 0 ? ad4.x : hd == 1 ? ad4.y : hd == 2 ? ad4.z : ad4.w;
    const float mh  = hd == 0 ? m0  : hd == 1 ? m1  : hd == 2 ? m2  : m3;

    float4 acc = {0.f, 0.f, 0.f, 0.f};
    float wsum = 0.f;
    for (int base = e0; base < e1; base += 4) {
        const int eA = base + half;             // covers base, base+1
        const int eB = base + 2 + half;         // covers base+2, base+3
        const bool vA = eA < e1, vB = eB < e1;
        const int sA = vA ? esrc[eA] : 0;
        const int sB = vB ? esrc[eB] : 0;
        // batched independent gathers
        const float4 aA = *(const float4*)&as[sA * 4];
        const float4 aB = *(const float4*)&as[sB * 4];
        const ushort4 hA = *(const ushort4*)&h[(long long)sA * 128 + l * 4];
        const ushort4 hB = *(const ushort4*)&h[(long long)sB * 128 + l * 4];

        float ashA = hd == 0 ? aA.x : hd == 1 ? aA.y : hd == 2 ? aA.z : aA.w;
        float evA = ashA + adh;
        evA = evA >= 0.f ? evA : NEG_SLOPE * evA;
        const float wA = vA ? __expf(evA - mh) : 0.f;

        float ashB = hd == 0 ? aB.x : hd == 1 ? aB.y : hd == 2 ? aB.z : aB.w;
        float evB = ashB + adh;
        evB = evB >= 0.f ? evB : NEG_SLOPE * evB;
        const float wB = vB ? __expf(evB - mh) : 0.f;

        acc.x = fmaf(wA, bf2f(hA.x), acc.x);
        acc.y = fmaf(wA, bf2f(hA.y), acc.y);
        acc.z = fmaf(wA, bf2f(hA.z), acc.z);
        acc.w = fmaf(wA, bf2f(hA.w), acc.w);
        acc.x = fmaf(wB, bf2f(hB.x), acc.x);
        acc.y = fmaf(wB, bf2f(hB.y), acc.y);
        acc.z = fmaf(wB, bf2f(hB.z), acc.z);
        acc.w = fmaf(wB, bf2f(hB.w), acc.w);
        wsum += wA + wB;
    }
    acc.x += __shfl_xor(acc.x, 32, 64);
    acc.y += __shfl_xor(acc.y, 32, 64);
    acc.z += __shfl_xor(acc.z, 32, 64);
    acc.w += __shfl_xor(acc.w, 32, 64);
    wsum  += __shfl_xor(wsum, 32, 64);

    if (half == 0) {
        const float inv = 1.f / (wsum + 1e-16f);
        float4 o; o.x = acc.x * inv; o.y = acc.y * inv; o.z = acc.z * inv; o.w = acc.w * inv;
        *(float4*)&out[(long long)n * 128 + l * 4] = o;
    }
}

// ========== Fused GAT aggregation, layer 2 (H=1, C=32): one wave per dst ==========
// Phase 1: lane-parallel max. Phase 2: 16 edges in flight (8 lanes x float4 each).
__global__ __launch_bounds__(256) void k_agg2(
    const int* __restrict__ row, const int* __restrict__ esrc,
    const float* __restrict__ as, const float* __restrict__ ad,   // [N]
    const float* __restrict__ h,                                  // [N][32]
    float* __restrict__ out, int N)                               // [N][32]
{
    const int lane = threadIdx.x & 63;
    const int wid  = threadIdx.x >> 6;
    const int n = blockIdx.x * 4 + wid;
    if (n >= N) return;
    const int e0 = row[n], e1 = row[n + 1];
    const float adv = ad[n];

    float m = -INFINITY;
    for (int e = e0 + lane; e < e1; e += 64) {
        float ev = as[esrc[e]] + adv;
        ev = ev >= 0.f ? ev : NEG_SLOPE * ev;
        m = fmaxf(m, ev);
    }
#pragma unroll
    for (int off = 32; off > 0; off >>= 1) m = fmaxf(m, __shfl_xor(m, off, 64));

    const int g  = lane >> 3;                    // edge slot 0..7
    const int l8 = lane & 7;                     // 4 cols: l8*4..l8*4+3
    float4 acc = {0.f, 0.f, 0.f, 0.f};
    float wsum = 0.f;
    for (int base = e0; base < e1; base += 16) {
        const int eA = base + g, eB = base + 8 + g;
        const bool vA = eA < e1, vB = eB < e1;
        const int sA = vA ? esrc[eA] : 0;
        const int sB = vB ? esrc[eB] : 0;
        const float asA = as[sA], asB = as[sB];
        const float4 hA = *(const float4*)&h[(long long)sA * 32 + l8 * 4];
        const float4 hB = *(const float4*)&h[(long long)sB * 32 + l8 * 4];

        float evA = asA + adv; evA = evA >= 0.f ? evA : NEG_SLOPE * evA;
        const float wA = vA ? __expf(evA - m) : 0.f;
        float evB = asB + adv; evB = evB >= 0.f ? evB : NEG_SLOPE * evB;
        const float wB = vB ? __expf(evB - m) : 0.f;

        acc.x = fmaf(wA, hA.x, acc.x);
        acc.y = fmaf(wA, hA.y, acc.y);
        acc.z = fmaf(wA, hA.z, acc.z);
        acc.w = fmaf(wA, hA.w, acc.w);
        acc.x = fmaf(wB, hB.x, acc.x);
        acc.y = fmaf(wB, hB.y, acc.y);
        acc.z = fmaf(wB, hB.z, acc.z);
        acc.w = fmaf(wB, hB.w, acc.w);
        wsum += wA + wB;
    }
#pragma unroll
    for (int off = 8; off < 64; off <<= 1) {
        acc.x += __shfl_xor(acc.x, off, 64);
        acc.y += __shfl_xor(acc.y, off, 64);
        acc.z += __shfl_xor(acc.z, off, 64);
        acc.w += __shfl_xor(acc.w, off, 64);
        wsum  += __shfl_xor(wsum, off, 64);
    }
    if (lane < 8) {
        const float inv = 1.f / (wsum + 1e-16f);
        float4 o; o.x = acc.x * inv; o.y = acc.y * inv; o.z = acc.z * inv; o.w = acc.w * inv;
        *(float4*)&out[(long long)n * 32 + lane * 4] = o;
    }
}

// ========== Gate MLP: full-grid parallel, one 32-lane group per node ==========
__global__ __launch_bounds__(256) void k_gate(
    const float* __restrict__ out2, const float* __restrict__ b2,
    const float* __restrict__ gw1, const float* __restrict__ gb1,
    const float* __restrict__ gw2, const float* __restrict__ gb2,
    float* __restrict__ gate, int N)
{
    const int c = threadIdx.x & 31, grp = threadIdx.x >> 5;
    const int n = blockIdx.x * 8 + grp;
    if (n >= N) return;
    float v = out2[(long long)n * 32 + c] + b2[c];
    v = elu1f(v);
    float t1 = gb1[c];
#pragma unroll
    for (int k = 0; k < 32; k++) {
        float hk = __shfl(v, k, 32);
        t1 = fmaf(hk, gw1[k * 32 + c], t1);
    }
    t1 = fmaxf(t1, 0.f);
    float gv = t1 * gw2[c];
#pragma unroll
    for (int off = 16; off > 0; off >>= 1) gv += __shfl_xor(gv, off, 32);
    if (c == 0) gate[n] = gv + gb2[0];
}

// ========== Pool reduce: one block per graph, zero atomics ==========
__global__ __launch_bounds__(256) void k_pool2(
    const float* __restrict__ out2, const float* __restrict__ b2,
    const float* __restrict__ gate, const int* __restrict__ batch,
    float* __restrict__ out, int N)
{
    const int g   = blockIdx.x;
    const int t   = threadIdx.x;
    const int c   = t & 31;
    const int grp = t >> 5;

    __shared__ int   sbound[2];
    __shared__ float sred[4];
    __shared__ float sacc[8][32];
    __shared__ float swsum[8];

    if (t < 2) {
        int target = g + t;
        int lo = 0, hi = N;
        while (lo < hi) { int mid = (lo + hi) >> 1; if (batch[mid] < target) lo = mid + 1; else hi = mid; }
        sbound[t] = lo;
    }
    __syncthreads();
    const int s0 = sbound[0], s1 = sbound[1];

    float mloc = -INFINITY;
    for (int n = s0 + t; n < s1; n += 256) mloc = fmaxf(mloc, gate[n]);
#pragma unroll
    for (int off = 32; off > 0; off >>= 1) mloc = fmaxf(mloc, __shfl_xor(mloc, off, 64));
    if ((t & 63) == 0) sred[t >> 6] = mloc;
    __syncthreads();
    const float gm = fmaxf(fmaxf(sred[0], sred[1]), fmaxf(sred[2], sred[3]));

    float acc = 0.f, wsum = 0.f;
    const float bc = b2[c];
    for (int n = s0 + grp; n < s1; n += 8) {
        float v = elu1f(out2[(long long)n * 32 + c] + bc);
        float ge = __expf(gate[n] - gm);
        acc = fmaf(ge, v, acc);
        wsum += ge;
    }
    sacc[grp][c] = acc;
    if (c == 0) swsum[grp] = wsum;
    __syncthreads();

    if (grp == 0) {
        float a = 0.f, wtot = 0.f;
#pragma unroll
        for (int i = 0; i < 8; i++) { a += sacc[i][c]; wtot += swsum[i]; }
        out[g * 32 + c] = a / (wtot + 1e-16f);
    }
}

extern "C" void kernel_launch(void* const* d_in, const int* in_sizes, int n_in,
                              void* d_out, int out_size, void* d_ws, size_t ws_size,
                              hipStream_t stream)
{
    const float* x    = (const float*)d_in[0];
    const int*   ei   = (const int*)d_in[1];
    const int*   batch= (const int*)d_in[2];
    const float* W1   = (const float*)d_in[3];
    const float* as1w = (const float*)d_in[4];
    const float* ad1w = (const float*)d_in[5];
    const float* b1   = (const float*)d_in[6];
    const float* W2   = (const float*)d_in[7];
    const float* as2w = (const float*)d_in[8];
    const float* ad2w = (const float*)d_in[9];
    const float* b2   = (const float*)d_in[10];
    const float* gw1  = (const float*)d_in[11];
    const float* gb1  = (const float*)d_in[12];
    const float* gw2  = (const float*)d_in[13];
    const float* gb2  = (const float*)d_in[14];

    const int N  = in_sizes[2];
    const int E  = in_sizes[1] / 2;
    const int Et = E + N;
    const int nb = (N + 255) / 256;

    float* ws = (float*)d_ws;
    size_t o = 0;
    ushort* h1 = (ushort*)(ws + o); o += (size_t)N * 64;   // bf16 [N][128] = N*64 floats
    float* out1 = ws + o; o += (size_t)N * 128;
    float* h2   = ws + o; o += (size_t)N * 32;
    float* out2 = ws + o; o += (size_t)N * 32;
    float* a_s1 = ws + o; o += (size_t)N * 4;
    float* a_d1 = ws + o; o += (size_t)N * 4;
    float* a_s2 = ws + o; o += (size_t)N;
    float* a_d2 = ws + o; o += (size_t)N;
    float* gate = ws + o; o += (size_t)N;
    int*   rowp = (int*)(ws + o); o += (size_t)N + 1;
    int*   curs = (int*)(ws + o); o += (size_t)N;
    int*   esrc = (int*)(ws + o); o += (size_t)Et;
    int*   bsum = (int*)(ws + o); o += 256;
    // ---- zeroed region (one memset): deg ----
    size_t zstart = o;
    int*   deg  = (int*)(ws + o); o += (size_t)N;
    size_t zbytes = (o - zstart) * sizeof(float);

    hipMemsetAsync(ws + zstart, 0, zbytes, stream);

    // ---- CSR build (shared by both layers) ----
    k_deg    <<<(Et + 255) / 256, 256, 0, stream>>>(ei, E, Et, deg);
    k_scan1  <<<nb, 256, 0, stream>>>(deg, N, rowp, bsum);
    k_scan2  <<<1, 256, 0, stream>>>(bsum, nb);
    k_scan3  <<<nb, 256, 0, stream>>>(rowp, bsum, N, Et, curs);
    k_scatter<<<(Et + 255) / 256, 256, 0, stream>>>(ei, E, Et, curs, esrc);

    // ---- GAT layer 1 ----
    k_gemm1<<<(N + 31) / 32, 256, 0, stream>>>(x, W1, as1w, ad1w, h1, a_s1, a_d1, N);
    k_agg1 <<<(N + 3) / 4, 256, 0, stream>>>(rowp, esrc, a_s1, a_d1, h1, out1, N);

    // ---- GAT layer 2 (elu(out1+b1) fused into gemm2 load) ----
    k_gemm2<<<(N + 31) / 32, 256, 0, stream>>>(out1, W2, b1, as2w, ad2w, h2, a_s2, a_d2, N);
    k_agg2 <<<(N + 3) / 4, 256, 0, stream>>>(rowp, esrc, a_s2, a_d2, h2, out2, N);

    // ---- attentional pooling: parallel gate, then per-graph reduce ----
    k_gate <<<(N + 7) / 8, 256, 0, stream>>>(out2, b2, gw1, gb1, gw2, gb2, gate, N);
    k_pool2<<<64, 256, 0, stream>>>(out2, b2, gate, batch, (float*)d_out, N);
}

// Round 8
// 324.161 us; speedup vs baseline: 4.7821x; 1.1556x over previous
//
#include <hip/hip_runtime.h>
#include <hip/hip_bf16.h>

#define NEG_SLOPE 0.2f

__device__ __forceinline__ float elu1f(float v) {
    return v > 0.f ? v : expm1f(v);
}
__device__ __forceinline__ float bf2f(ushort u) {
    return __uint_as_float(((unsigned)u) << 16);
}
__device__ __forceinline__ ushort f2bf(float f) {
    return __bfloat16_as_ushort(__float2bfloat16(f));
}

// ======================= CSR build (by dst) =======================
__global__ void k_deg(const int* __restrict__ ei, int E, int Et, int* __restrict__ deg)
{
    int i = blockIdx.x * 256 + threadIdx.x;
    if (i >= Et) return;
    int d = (i < E) ? ei[E + i] : i - E;
    atomicAdd(&deg[d], 1);
}

__global__ __launch_bounds__(256) void k_scan1(const int* __restrict__ deg, int N,
                                               int* __restrict__ row, int* __restrict__ bsum)
{
    __shared__ int s[256];
    int i = blockIdx.x * 256 + threadIdx.x;
    int v = (i < N) ? deg[i] : 0;
    s[threadIdx.x] = v;
    __syncthreads();
#pragma unroll
    for (int off = 1; off < 256; off <<= 1) {
        int t = (threadIdx.x >= off) ? s[threadIdx.x - off] : 0;
        __syncthreads();
        s[threadIdx.x] += t;
        __syncthreads();
    }
    if (i < N) row[i] = s[threadIdx.x] - v;          // exclusive
    if (threadIdx.x == 255) bsum[blockIdx.x] = s[255];
}

__global__ __launch_bounds__(256) void k_scan2(int* __restrict__ bsum, int nb)
{
    __shared__ int s[256];
    int v = (threadIdx.x < nb) ? bsum[threadIdx.x] : 0;
    s[threadIdx.x] = v;
    __syncthreads();
#pragma unroll
    for (int off = 1; off < 256; off <<= 1) {
        int t = (threadIdx.x >= off) ? s[threadIdx.x - off] : 0;
        __syncthreads();
        s[threadIdx.x] += t;
        __syncthreads();
    }
    if (threadIdx.x < nb) bsum[threadIdx.x] = s[threadIdx.x] - v;   // exclusive
}

__global__ void k_scan3(int* __restrict__ row, const int* __restrict__ bsum,
                        int N, int Et, int* __restrict__ cursor)
{
    int i = blockIdx.x * 256 + threadIdx.x;
    if (i < N) {
        int r = row[i] + bsum[blockIdx.x];
        row[i] = r;
        cursor[i] = r;
    }
    if (i == 0) row[N] = Et;
}

__global__ void k_scatter(const int* __restrict__ ei, int E, int Et,
                          int* __restrict__ cursor, int* __restrict__ esrc)
{
    int i = blockIdx.x * 256 + threadIdx.x;
    if (i >= Et) return;
    int s, d;
    if (i < E) { s = ei[i]; d = ei[E + i]; } else { s = i - E; d = s; }
    int pos = atomicAdd(&cursor[d], 1);
    esrc[pos] = s;
}

// ---------------- GEMM1 v3: h1(bf16) = x @ W1 (128->128), 4x4 register blocking ------
// 256 threads; tile 32 rows x 128 cols; thread (rg=t>>5, c4=t&31) owns rows rg*4..+3,
// cols c4*4..+3. Per kk-group: 4 broadcast X b128 + 4 contiguous W b128 -> 64 FMA.
__global__ __launch_bounds__(256) void k_gemm1(
    const float* __restrict__ x, const float* __restrict__ W,
    const float* __restrict__ att_s, const float* __restrict__ att_d,
    ushort* __restrict__ h1, float* __restrict__ as1, float* __restrict__ ad1, int N)
{
    __shared__ __align__(16) float sW[16][128];   // 8 KB
    __shared__ __align__(16) float sX[32][16];    // 2 KB
    const int t  = threadIdx.x;
    const int c4 = t & 31;             // col group (cols c4*4 .. c4*4+3)
    const int rg = t >> 5;             // row group (rows rg*4 .. rg*4+3)
    const int row0 = blockIdx.x * 32;
    const float4* W4 = (const float4*)W;   // W row = 32 float4

    float4 acc[4];
#pragma unroll
    for (int i = 0; i < 4; i++) acc[i] = {0.f, 0.f, 0.f, 0.f};

    for (int k0 = 0; k0 < 128; k0 += 16) {
        __syncthreads();
#pragma unroll
        for (int j = 0; j < 2; j++) {
            int idx = j * 256 + t;                 // 0..511
            int r = idx >> 5, cc = idx & 31;
            *(float4*)&sW[r][cc * 4] = W4[(k0 + r) * 32 + cc];
        }
        if (t < 128) {
            int r = t >> 2, q = t & 3;
            int row = row0 + r;
            float4 v = {0.f, 0.f, 0.f, 0.f};
            if (row < N) v = *(const float4*)&x[(long long)row * 128 + k0 + q * 4];
            *(float4*)&sX[r][q * 4] = v;
        }
        __syncthreads();
#pragma unroll
        for (int g = 0; g < 4; g++) {
            const int kk = g * 4;
            const float4 w0 = *(const float4*)&sW[kk + 0][c4 * 4];
            const float4 w1 = *(const float4*)&sW[kk + 1][c4 * 4];
            const float4 w2 = *(const float4*)&sW[kk + 2][c4 * 4];
            const float4 w3 = *(const float4*)&sW[kk + 3][c4 * 4];
#pragma unroll
            for (int i = 0; i < 4; i++) {
                const float4 xv = *(const float4*)&sX[rg * 4 + i][kk];  // broadcast
                acc[i].x = fmaf(xv.x, w0.x, acc[i].x);
                acc[i].y = fmaf(xv.x, w0.y, acc[i].y);
                acc[i].z = fmaf(xv.x, w0.z, acc[i].z);
                acc[i].w = fmaf(xv.x, w0.w, acc[i].w);
                acc[i].x = fmaf(xv.y, w1.x, acc[i].x);
                acc[i].y = fmaf(xv.y, w1.y, acc[i].y);
                acc[i].z = fmaf(xv.y, w1.z, acc[i].z);
                acc[i].w = fmaf(xv.y, w1.w, acc[i].w);
                acc[i].x = fmaf(xv.z, w2.x, acc[i].x);
                acc[i].y = fmaf(xv.z, w2.y, acc[i].y);
                acc[i].z = fmaf(xv.z, w2.z, acc[i].z);
                acc[i].w = fmaf(xv.z, w2.w, acc[i].w);
                acc[i].x = fmaf(xv.w, w3.x, acc[i].x);
                acc[i].y = fmaf(xv.w, w3.y, acc[i].y);
                acc[i].z = fmaf(xv.w, w3.z, acc[i].z);
                acc[i].w = fmaf(xv.w, w3.w, acc[i].w);
            }
        }
    }

    const float4 avs = *(const float4*)&att_s[c4 * 4];
    const float4 avd = *(const float4*)&att_d[c4 * 4];
    const int hd = c4 >> 3;                        // head of this thread's 4 cols
#pragma unroll
    for (int i = 0; i < 4; i++) {
        int row = row0 + rg * 4 + i;
        if (row < N) {
            ushort4 hb;
            hb.x = f2bf(acc[i].x); hb.y = f2bf(acc[i].y);
            hb.z = f2bf(acc[i].z); hb.w = f2bf(acc[i].w);
            *(ushort4*)&h1[(long long)row * 128 + c4 * 4] = hb;
            float s = acc[i].x * avs.x + acc[i].y * avs.y + acc[i].z * avs.z + acc[i].w * avs.w;
            float d = acc[i].x * avd.x + acc[i].y * avd.y + acc[i].z * avd.z + acc[i].w * avd.w;
#pragma unroll
            for (int off = 4; off > 0; off >>= 1) {    // reduce over 8 col-threads of head
                s += __shfl_xor(s, off, 64);
                d += __shfl_xor(d, off, 64);
            }
            if ((c4 & 7) == 0) { as1[row * 4 + hd] = s; ad1[row * 4 + hd] = d; }
        }
    }
}

// ---------------- GEMM2 v3: h2 = elu(out1+b1) @ W2 (128->32), 4x4 blocking -----------
// 256 threads; tile 128 rows x 32 cols; thread (rg=t>>3, c4=t&7).
__global__ __launch_bounds__(256) void k_gemm2(
    const float* __restrict__ xin, const float* __restrict__ W,
    const float* __restrict__ b1,
    const float* __restrict__ att_s, const float* __restrict__ att_d,
    float* __restrict__ h2, float* __restrict__ as2, float* __restrict__ ad2, int N)
{
    __shared__ __align__(16) float sW[16][32];    // 2 KB
    __shared__ __align__(16) float sX[128][16];   // 8 KB
    const int t  = threadIdx.x;
    const int c4 = t & 7;              // col group (cols c4*4 .. c4*4+3)
    const int rg = t >> 3;             // row group (rows rg*4 .. rg*4+3)
    const int row0 = blockIdx.x * 128;
    const float4* W4 = (const float4*)W;          // W row = 8 float4

    float4 acc[4];
#pragma unroll
    for (int i = 0; i < 4; i++) acc[i] = {0.f, 0.f, 0.f, 0.f};

    for (int k0 = 0; k0 < 128; k0 += 16) {
        __syncthreads();
        if (t < 128) {                 // stage W tile: 16x32 = 128 float4
            int r = t >> 3, cc = t & 7;
            *(float4*)&sW[r][cc * 4] = W4[(k0 + r) * 8 + cc];
        }
#pragma unroll
        for (int j = 0; j < 2; j++) {  // stage X tile: 128x16 = 512 float4
            int idx = j * 256 + t;
            int r = idx >> 2, q = idx & 3;
            int row = row0 + r;
            float4 v = {0.f, 0.f, 0.f, 0.f};
            if (row < N) {
                v = *(const float4*)&xin[(long long)row * 128 + k0 + q * 4];
                float4 b = *(const float4*)&b1[k0 + q * 4];
                v.x = elu1f(v.x + b.x); v.y = elu1f(v.y + b.y);
                v.z = elu1f(v.z + b.z); v.w = elu1f(v.w + b.w);
            }
            *(float4*)&sX[r][q * 4] = v;
        }
        __syncthreads();
#pragma unroll
        for (int g = 0; g < 4; g++) {
            const int kk = g * 4;
            const float4 w0 = *(const float4*)&sW[kk + 0][c4 * 4];
            const float4 w1 = *(const float4*)&sW[kk + 1][c4 * 4];
            const float4 w2 = *(const float4*)&sW[kk + 2][c4 * 4];
            const float4 w3 = *(const float4*)&sW[kk + 3][c4 * 4];
#pragma unroll
            for (int i = 0; i < 4; i++) {
                const float4 xv = *(const float4*)&sX[rg * 4 + i][kk];
                acc[i].x = fmaf(xv.x, w0.x, acc[i].x);
                acc[i].y = fmaf(xv.x, w0.y, acc[i].y);
                acc[i].z = fmaf(xv.x, w0.z, acc[i].z);
                acc[i].w = fmaf(xv.x, w0.w, acc[i].w);
                acc[i].x = fmaf(xv.y, w1.x, acc[i].x);
                acc[i].y = fmaf(xv.y, w1.y, acc[i].y);
                acc[i].z = fmaf(xv.y, w1.z, acc[i].z);
                acc[i].w = fmaf(xv.y, w1.w, acc[i].w);
                acc[i].x = fmaf(xv.z, w2.x, acc[i].x);
                acc[i].y = fmaf(xv.z, w2.y, acc[i].y);
                acc[i].z = fmaf(xv.z, w2.z, acc[i].z);
                acc[i].w = fmaf(xv.z, w2.w, acc[i].w);
                acc[i].x = fmaf(xv.w, w3.x, acc[i].x);
                acc[i].y = fmaf(xv.w, w3.y, acc[i].y);
                acc[i].z = fmaf(xv.w, w3.z, acc[i].z);
                acc[i].w = fmaf(xv.w, w3.w, acc[i].w);
            }
        }
    }

    const float4 avs = *(const float4*)&att_s[c4 * 4];
    const float4 avd = *(const float4*)&att_d[c4 * 4];
#pragma unroll
    for (int i = 0; i < 4; i++) {
        int row = row0 + rg * 4 + i;
        if (row < N) {
            *(float4*)&h2[(long long)row * 32 + c4 * 4] = acc[i];
            float s = acc[i].x * avs.x + acc[i].y * avs.y + acc[i].z * avs.z + acc[i].w * avs.w;
            float d = acc[i].x * avd.x + acc[i].y * avd.y + acc[i].z * avd.z + acc[i].w * avd.w;
#pragma unroll
            for (int off = 4; off > 0; off >>= 1) {    // reduce over 8 col-threads
                s += __shfl_xor(s, off, 64);
                d += __shfl_xor(d, off, 64);
            }
            if (c4 == 0) { as2[row] = s; ad2[row] = d; }
        }
    }
}

// ========== Fused GAT aggregation, layer 1 (H=4, C=32): one wave per dst ==========
__global__ __launch_bounds__(256) void k_agg1(
    const int* __restrict__ row, const int* __restrict__ esrc,
    const float* __restrict__ as, const float* __restrict__ ad,   // [N][4]
    const ushort* __restrict__ h,                                 // [N][128] bf16
    float* __restrict__ out, int N)                               // [N][128]
{
    const int lane = threadIdx.x & 63;
    const int wid  = threadIdx.x >> 6;
    const int n = blockIdx.x * 4 + wid;
    if (n >= N) return;
    const int e0 = row[n], e1 = row[n + 1];

    const float4 ad4 = *(const float4*)&ad[n * 4];

    // ---- phase 1: per-head max over in-edges ----
    float m0 = -INFINITY, m1 = -INFINITY, m2 = -INFINITY, m3 = -INFINITY;
    for (int e = e0 + lane; e < e1; e += 64) {
        const int s = esrc[e];
        const float4 a4 = *(const float4*)&as[s * 4];
        float v0 = a4.x + ad4.x; v0 = v0 >= 0.f ? v0 : NEG_SLOPE * v0;
        float v1 = a4.y + ad4.y; v1 = v1 >= 0.f ? v1 : NEG_SLOPE * v1;
        float v2 = a4.z + ad4.z; v2 = v2 >= 0.f ? v2 : NEG_SLOPE * v2;
        float v3 = a4.w + ad4.w; v3 = v3 >= 0.f ? v3 : NEG_SLOPE * v3;
        m0 = fmaxf(m0, v0); m1 = fmaxf(m1, v1);
        m2 = fmaxf(m2, v2); m3 = fmaxf(m3, v3);
    }
#pragma unroll
    for (int off = 32; off > 0; off >>= 1) {
        m0 = fmaxf(m0, __shfl_xor(m0, off, 64));
        m1 = fmaxf(m1, __shfl_xor(m1, off, 64));
        m2 = fmaxf(m2, __shfl_xor(m2, off, 64));
        m3 = fmaxf(m3, __shfl_xor(m3, off, 64));
    }

    // ---- phase 2: 4 edges per iteration, 2 per half ----
    const int half = lane >> 5;
    const int l    = lane & 31;                 // 4 cols per lane: l*4..l*4+3
    const int hd   = l >> 3;                    // head of those cols
    const float adh = hd == 0 ? ad4.x : hd == 1 ? ad4.y : hd == 2 ? ad4.z : ad4.w;
    const float mh  = hd == 0 ? m0  : hd == 1 ? m1  : hd == 2 ? m2  : m3;

    float4 acc = {0.f, 0.f, 0.f, 0.f};
    float wsum = 0.f;
    for (int base = e0; base < e1; base += 4) {
        const int eA = base + half;             // covers base, base+1
        const int eB = base + 2 + half;         // covers base+2, base+3
        const bool vA = eA < e1, vB = eB < e1;
        const int sA = vA ? esrc[eA] : 0;
        const int sB = vB ? esrc[eB] : 0;
        const float4 aA = *(const float4*)&as[sA * 4];
        const float4 aB = *(const float4*)&as[sB * 4];
        const ushort4 hA = *(const ushort4*)&h[(long long)sA * 128 + l * 4];
        const ushort4 hB = *(const ushort4*)&h[(long long)sB * 128 + l * 4];

        float ashA = hd == 0 ? aA.x : hd == 1 ? aA.y : hd == 2 ? aA.z : aA.w;
        float evA = ashA + adh;
        evA = evA >= 0.f ? evA : NEG_SLOPE * evA;
        const float wA = vA ? __expf(evA - mh) : 0.f;

        float ashB = hd == 0 ? aB.x : hd == 1 ? aB.y : hd == 2 ? aB.z : aB.w;
        float evB = ashB + adh;
        evB = evB >= 0.f ? evB : NEG_SLOPE * evB;
        const float wB = vB ? __expf(evB - mh) : 0.f;

        acc.x = fmaf(wA, bf2f(hA.x), acc.x);
        acc.y = fmaf(wA, bf2f(hA.y), acc.y);
        acc.z = fmaf(wA, bf2f(hA.z), acc.z);
        acc.w = fmaf(wA, bf2f(hA.w), acc.w);
        acc.x = fmaf(wB, bf2f(hB.x), acc.x);
        acc.y = fmaf(wB, bf2f(hB.y), acc.y);
        acc.z = fmaf(wB, bf2f(hB.z), acc.z);
        acc.w = fmaf(wB, bf2f(hB.w), acc.w);
        wsum += wA + wB;
    }
    acc.x += __shfl_xor(acc.x, 32, 64);
    acc.y += __shfl_xor(acc.y, 32, 64);
    acc.z += __shfl_xor(acc.z, 32, 64);
    acc.w += __shfl_xor(acc.w, 32, 64);
    wsum  += __shfl_xor(wsum, 32, 64);

    if (half == 0) {
        const float inv = 1.f / (wsum + 1e-16f);
        float4 o; o.x = acc.x * inv; o.y = acc.y * inv; o.z = acc.z * inv; o.w = acc.w * inv;
        *(float4*)&out[(long long)n * 128 + l * 4] = o;
    }
}

// ========== Fused GAT aggregation, layer 2 (H=1, C=32): one wave per dst ==========
__global__ __launch_bounds__(256) void k_agg2(
    const int* __restrict__ row, const int* __restrict__ esrc,
    const float* __restrict__ as, const float* __restrict__ ad,   // [N]
    const float* __restrict__ h,                                  // [N][32]
    float* __restrict__ out, int N)                               // [N][32]
{
    const int lane = threadIdx.x & 63;
    const int wid  = threadIdx.x >> 6;
    const int n = blockIdx.x * 4 + wid;
    if (n >= N) return;
    const int e0 = row[n], e1 = row[n + 1];
    const float adv = ad[n];

    float m = -INFINITY;
    for (int e = e0 + lane; e < e1; e += 64) {
        float ev = as[esrc[e]] + adv;
        ev = ev >= 0.f ? ev : NEG_SLOPE * ev;
        m = fmaxf(m, ev);
    }
#pragma unroll
    for (int off = 32; off > 0; off >>= 1) m = fmaxf(m, __shfl_xor(m, off, 64));

    const int g  = lane >> 3;                    // edge slot 0..7
    const int l8 = lane & 7;                     // 4 cols: l8*4..l8*4+3
    float4 acc = {0.f, 0.f, 0.f, 0.f};
    float wsum = 0.f;
    for (int base = e0; base < e1; base += 16) {
        const int eA = base + g, eB = base + 8 + g;
        const bool vA = eA < e1, vB = eB < e1;
        const int sA = vA ? esrc[eA] : 0;
        const int sB = vB ? esrc[eB] : 0;
        const float asA = as[sA], asB = as[sB];
        const float4 hA = *(const float4*)&h[(long long)sA * 32 + l8 * 4];
        const float4 hB = *(const float4*)&h[(long long)sB * 32 + l8 * 4];

        float evA = asA + adv; evA = evA >= 0.f ? evA : NEG_SLOPE * evA;
        const float wA = vA ? __expf(evA - m) : 0.f;
        float evB = asB + adv; evB = evB >= 0.f ? evB : NEG_SLOPE * evB;
        const float wB = vB ? __expf(evB - m) : 0.f;

        acc.x = fmaf(wA, hA.x, acc.x);
        acc.y = fmaf(wA, hA.y, acc.y);
        acc.z = fmaf(wA, hA.z, acc.z);
        acc.w = fmaf(wA, hA.w, acc.w);
        acc.x = fmaf(wB, hB.x, acc.x);
        acc.y = fmaf(wB, hB.y, acc.y);
        acc.z = fmaf(wB, hB.z, acc.z);
        acc.w = fmaf(wB, hB.w, acc.w);
        wsum += wA + wB;
    }
#pragma unroll
    for (int off = 8; off < 64; off <<= 1) {
        acc.x += __shfl_xor(acc.x, off, 64);
        acc.y += __shfl_xor(acc.y, off, 64);
        acc.z += __shfl_xor(acc.z, off, 64);
        acc.w += __shfl_xor(acc.w, off, 64);
        wsum  += __shfl_xor(wsum, off, 64);
    }
    if (lane < 8) {
        const float inv = 1.f / (wsum + 1e-16f);
        float4 o; o.x = acc.x * inv; o.y = acc.y * inv; o.z = acc.z * inv; o.w = acc.w * inv;
        *(float4*)&out[(long long)n * 32 + lane * 4] = o;
    }
}

// ========== Gate MLP: full-grid parallel, one 32-lane group per node ==========
__global__ __launch_bounds__(256) void k_gate(
    const float* __restrict__ out2, const float* __restrict__ b2,
    const float* __restrict__ gw1, const float* __restrict__ gb1,
    const float* __restrict__ gw2, const float* __restrict__ gb2,
    float* __restrict__ gate, int N)
{
    const int c = threadIdx.x & 31, grp = threadIdx.x >> 5;
    const int n = blockIdx.x * 8 + grp;
    if (n >= N) return;
    float v = out2[(long long)n * 32 + c] + b2[c];
    v = elu1f(v);
    float t1 = gb1[c];
#pragma unroll
    for (int k = 0; k < 32; k++) {
        float hk = __shfl(v, k, 32);
        t1 = fmaf(hk, gw1[k * 32 + c], t1);
    }
    t1 = fmaxf(t1, 0.f);
    float gv = t1 * gw2[c];
#pragma unroll
    for (int off = 16; off > 0; off >>= 1) gv += __shfl_xor(gv, off, 32);
    if (c == 0) gate[n] = gv + gb2[0];
}

// ========== Pool reduce: one block per graph, zero atomics ==========
__global__ __launch_bounds__(256) void k_pool2(
    const float* __restrict__ out2, const float* __restrict__ b2,
    const float* __restrict__ gate, const int* __restrict__ batch,
    float* __restrict__ out, int N)
{
    const int g   = blockIdx.x;
    const int t   = threadIdx.x;
    const int c   = t & 31;
    const int grp = t >> 5;

    __shared__ int   sbound[2];
    __shared__ float sred[4];
    __shared__ float sacc[8][32];
    __shared__ float swsum[8];

    if (t < 2) {
        int target = g + t;
        int lo = 0, hi = N;
        while (lo < hi) { int mid = (lo + hi) >> 1; if (batch[mid] < target) lo = mid + 1; else hi = mid; }
        sbound[t] = lo;
    }
    __syncthreads();
    const int s0 = sbound[0], s1 = sbound[1];

    float mloc = -INFINITY;
    for (int n = s0 + t; n < s1; n += 256) mloc = fmaxf(mloc, gate[n]);
#pragma unroll
    for (int off = 32; off > 0; off >>= 1) mloc = fmaxf(mloc, __shfl_xor(mloc, off, 64));
    if ((t & 63) == 0) sred[t >> 6] = mloc;
    __syncthreads();
    const float gm = fmaxf(fmaxf(sred[0], sred[1]), fmaxf(sred[2], sred[3]));

    float acc = 0.f, wsum = 0.f;
    const float bc = b2[c];
    for (int n = s0 + grp; n < s1; n += 8) {
        float v = elu1f(out2[(long long)n * 32 + c] + bc);
        float ge = __expf(gate[n] - gm);
        acc = fmaf(ge, v, acc);
        wsum += ge;
    }
    sacc[grp][c] = acc;
    if (c == 0) swsum[grp] = wsum;
    __syncthreads();

    if (grp == 0) {
        float a = 0.f, wtot = 0.f;
#pragma unroll
        for (int i = 0; i < 8; i++) { a += sacc[i][c]; wtot += swsum[i]; }
        out[g * 32 + c] = a / (wtot + 1e-16f);
    }
}

extern "C" void kernel_launch(void* const* d_in, const int* in_sizes, int n_in,
                              void* d_out, int out_size, void* d_ws, size_t ws_size,
                              hipStream_t stream)
{
    const float* x    = (const float*)d_in[0];
    const int*   ei   = (const int*)d_in[1];
    const int*   batch= (const int*)d_in[2];
    const float* W1   = (const float*)d_in[3];
    const float* as1w = (const float*)d_in[4];
    const float* ad1w = (const float*)d_in[5];
    const float* b1   = (const float*)d_in[6];
    const float* W2   = (const float*)d_in[7];
    const float* as2w = (const float*)d_in[8];
    const float* ad2w = (const float*)d_in[9];
    const float* b2   = (const float*)d_in[10];
    const float* gw1  = (const float*)d_in[11];
    const float* gb1  = (const float*)d_in[12];
    const float* gw2  = (const float*)d_in[13];
    const float* gb2  = (const float*)d_in[14];

    const int N  = in_sizes[2];
    const int E  = in_sizes[1] / 2;
    const int Et = E + N;
    const int nb = (N + 255) / 256;

    float* ws = (float*)d_ws;
    size_t o = 0;
    ushort* h1 = (ushort*)(ws + o); o += (size_t)N * 64;   // bf16 [N][128]
    float* out1 = ws + o; o += (size_t)N * 128;
    float* h2   = ws + o; o += (size_t)N * 32;
    float* out2 = ws + o; o += (size_t)N * 32;
    float* a_s1 = ws + o; o += (size_t)N * 4;
    float* a_d1 = ws + o; o += (size_t)N * 4;
    float* a_s2 = ws + o; o += (size_t)N;
    float* a_d2 = ws + o; o += (size_t)N;
    float* gate = ws + o; o += (size_t)N;
    int*   rowp = (int*)(ws + o); o += (size_t)N + 1;
    int*   curs = (int*)(ws + o); o += (size_t)N;
    int*   esrc = (int*)(ws + o); o += (size_t)Et;
    int*   bsum = (int*)(ws + o); o += 256;
    // ---- zeroed region (one memset): deg ----
    size_t zstart = o;
    int*   deg  = (int*)(ws + o); o += (size_t)N;
    size_t zbytes = (o - zstart) * sizeof(float);

    hipMemsetAsync(ws + zstart, 0, zbytes, stream);

    // ---- CSR build (shared by both layers) ----
    k_deg    <<<(Et + 255) / 256, 256, 0, stream>>>(ei, E, Et, deg);
    k_scan1  <<<nb, 256, 0, stream>>>(deg, N, rowp, bsum);
    k_scan2  <<<1, 256, 0, stream>>>(bsum, nb);
    k_scan3  <<<nb, 256, 0, stream>>>(rowp, bsum, N, Et, curs);
    k_scatter<<<(Et + 255) / 256, 256, 0, stream>>>(ei, E, Et, curs, esrc);

    // ---- GAT layer 1 ----
    k_gemm1<<<(N + 31) / 32, 256, 0, stream>>>(x, W1, as1w, ad1w, h1, a_s1, a_d1, N);
    k_agg1 <<<(N + 3) / 4, 256, 0, stream>>>(rowp, esrc, a_s1, a_d1, h1, out1, N);

    // ---- GAT layer 2 (elu(out1+b1) fused into gemm2 load) ----
    k_gemm2<<<(N + 127) / 128, 256, 0, stream>>>(out1, W2, b1, as2w, ad2w, h2, a_s2, a_d2, N);
    k_agg2 <<<(N + 3) / 4, 256, 0, stream>>>(rowp, esrc, a_s2, a_d2, h2, out2, N);

    // ---- attentional pooling: parallel gate, then per-graph reduce ----
    k_gate <<<(N + 7) / 8, 256, 0, stream>>>(out2, b2, gw1, gb1, gw2, gb2, gate, N);
    k_pool2<<<64, 256, 0, stream>>>(out2, b2, gate, batch, (float*)d_out, N);
}

// Round 9
// 281.281 us; speedup vs baseline: 5.5111x; 1.1524x over previous
//
#include <hip/hip_runtime.h>
#include <hip/hip_bf16.h>

#define NEG_SLOPE 0.2f

__device__ __forceinline__ float elu1f(float v) {
    return v > 0.f ? v : expm1f(v);
}
__device__ __forceinline__ float bf2f(ushort u) {
    return __uint_as_float(((unsigned)u) << 16);
}
__device__ __forceinline__ ushort f2bf(float f) {
    return __bfloat16_as_ushort(__float2bfloat16(f));
}
__device__ __forceinline__ unsigned fflip(float f) {
    unsigned u = __float_as_uint(f);
    return (u & 0x80000000u) ? ~u : (u | 0x80000000u);
}
__device__ __forceinline__ float funflip(unsigned u) {
    u = (u & 0x80000000u) ? (u & 0x7FFFFFFFu) : ~u;
    return __uint_as_float(u);
}

// ======================= CSR build (by dst) =======================
__global__ void k_deg(const int* __restrict__ ei, int E, int Et, int* __restrict__ deg)
{
    int i = blockIdx.x * 256 + threadIdx.x;
    if (i >= Et) return;
    int d = (i < E) ? ei[E + i] : i - E;
    atomicAdd(&deg[d], 1);
}

__global__ __launch_bounds__(256) void k_scan1(const int* __restrict__ deg, int N,
                                               int* __restrict__ row, int* __restrict__ bsum)
{
    __shared__ int s[256];
    int i = blockIdx.x * 256 + threadIdx.x;
    int v = (i < N) ? deg[i] : 0;
    s[threadIdx.x] = v;
    __syncthreads();
#pragma unroll
    for (int off = 1; off < 256; off <<= 1) {
        int t = (threadIdx.x >= off) ? s[threadIdx.x - off] : 0;
        __syncthreads();
        s[threadIdx.x] += t;
        __syncthreads();
    }
    if (i < N) row[i] = s[threadIdx.x] - v;          // exclusive
    if (threadIdx.x == 255) bsum[blockIdx.x] = s[255];
}

__global__ __launch_bounds__(256) void k_scan2(int* __restrict__ bsum, int nb)
{
    __shared__ int s[256];
    int v = (threadIdx.x < nb) ? bsum[threadIdx.x] : 0;
    s[threadIdx.x] = v;
    __syncthreads();
#pragma unroll
    for (int off = 1; off < 256; off <<= 1) {
        int t = (threadIdx.x >= off) ? s[threadIdx.x - off] : 0;
        __syncthreads();
        s[threadIdx.x] += t;
        __syncthreads();
    }
    if (threadIdx.x < nb) bsum[threadIdx.x] = s[threadIdx.x] - v;   // exclusive
}

__global__ void k_scan3(int* __restrict__ row, const int* __restrict__ bsum,
                        int N, int Et, int* __restrict__ cursor)
{
    int i = blockIdx.x * 256 + threadIdx.x;
    if (i < N) {
        int r = row[i] + bsum[blockIdx.x];
        row[i] = r;
        cursor[i] = r;
    }
    if (i == 0) row[N] = Et;
}

__global__ void k_scatter(const int* __restrict__ ei, int E, int Et,
                          int* __restrict__ cursor, int* __restrict__ esrc)
{
    int i = blockIdx.x * 256 + threadIdx.x;
    if (i >= Et) return;
    int s, d;
    if (i < E) { s = ei[i]; d = ei[E + i]; } else { s = i - E; d = s; }
    int pos = atomicAdd(&cursor[d], 1);
    esrc[pos] = s;
}

// ---------------- GEMM1 v3: h1(bf16) = x @ W1 (128->128), 4x4 register blocking ------
__global__ __launch_bounds__(256) void k_gemm1(
    const float* __restrict__ x, const float* __restrict__ W,
    const float* __restrict__ att_s, const float* __restrict__ att_d,
    ushort* __restrict__ h1, float* __restrict__ as1, float* __restrict__ ad1, int N)
{
    __shared__ __align__(16) float sW[16][128];   // 8 KB
    __shared__ __align__(16) float sX[32][16];    // 2 KB
    const int t  = threadIdx.x;
    const int c4 = t & 31;             // col group (cols c4*4 .. c4*4+3)
    const int rg = t >> 5;             // row group (rows rg*4 .. rg*4+3)
    const int row0 = blockIdx.x * 32;
    const float4* W4 = (const float4*)W;   // W row = 32 float4

    float4 acc[4];
#pragma unroll
    for (int i = 0; i < 4; i++) acc[i] = {0.f, 0.f, 0.f, 0.f};

    for (int k0 = 0; k0 < 128; k0 += 16) {
        __syncthreads();
#pragma unroll
        for (int j = 0; j < 2; j++) {
            int idx = j * 256 + t;                 // 0..511
            int r = idx >> 5, cc = idx & 31;
            *(float4*)&sW[r][cc * 4] = W4[(k0 + r) * 32 + cc];
        }
        if (t < 128) {
            int r = t >> 2, q = t & 3;
            int row = row0 + r;
            float4 v = {0.f, 0.f, 0.f, 0.f};
            if (row < N) v = *(const float4*)&x[(long long)row * 128 + k0 + q * 4];
            *(float4*)&sX[r][q * 4] = v;
        }
        __syncthreads();
#pragma unroll
        for (int g = 0; g < 4; g++) {
            const int kk = g * 4;
            const float4 w0 = *(const float4*)&sW[kk + 0][c4 * 4];
            const float4 w1 = *(const float4*)&sW[kk + 1][c4 * 4];
            const float4 w2 = *(const float4*)&sW[kk + 2][c4 * 4];
            const float4 w3 = *(const float4*)&sW[kk + 3][c4 * 4];
#pragma unroll
            for (int i = 0; i < 4; i++) {
                const float4 xv = *(const float4*)&sX[rg * 4 + i][kk];  // broadcast
                acc[i].x = fmaf(xv.x, w0.x, acc[i].x);
                acc[i].y = fmaf(xv.x, w0.y, acc[i].y);
                acc[i].z = fmaf(xv.x, w0.z, acc[i].z);
                acc[i].w = fmaf(xv.x, w0.w, acc[i].w);
                acc[i].x = fmaf(xv.y, w1.x, acc[i].x);
                acc[i].y = fmaf(xv.y, w1.y, acc[i].y);
                acc[i].z = fmaf(xv.y, w1.z, acc[i].z);
                acc[i].w = fmaf(xv.y, w1.w, acc[i].w);
                acc[i].x = fmaf(xv.z, w2.x, acc[i].x);
                acc[i].y = fmaf(xv.z, w2.y, acc[i].y);
                acc[i].z = fmaf(xv.z, w2.z, acc[i].z);
                acc[i].w = fmaf(xv.z, w2.w, acc[i].w);
                acc[i].x = fmaf(xv.w, w3.x, acc[i].x);
                acc[i].y = fmaf(xv.w, w3.y, acc[i].y);
                acc[i].z = fmaf(xv.w, w3.z, acc[i].z);
                acc[i].w = fmaf(xv.w, w3.w, acc[i].w);
            }
        }
    }

    const float4 avs = *(const float4*)&att_s[c4 * 4];
    const float4 avd = *(const float4*)&att_d[c4 * 4];
    const int hd = c4 >> 3;                        // head of this thread's 4 cols
#pragma unroll
    for (int i = 0; i < 4; i++) {
        int row = row0 + rg * 4 + i;
        if (row < N) {
            ushort4 hb;
            hb.x = f2bf(acc[i].x); hb.y = f2bf(acc[i].y);
            hb.z = f2bf(acc[i].z); hb.w = f2bf(acc[i].w);
            *(ushort4*)&h1[(long long)row * 128 + c4 * 4] = hb;
            float s = acc[i].x * avs.x + acc[i].y * avs.y + acc[i].z * avs.z + acc[i].w * avs.w;
            float d = acc[i].x * avd.x + acc[i].y * avd.y + acc[i].z * avd.z + acc[i].w * avd.w;
#pragma unroll
            for (int off = 4; off > 0; off >>= 1) {    // reduce over 8 col-threads of head
                s += __shfl_xor(s, off, 64);
                d += __shfl_xor(d, off, 64);
            }
            if ((c4 & 7) == 0) { as1[row * 4 + hd] = s; ad1[row * 4 + hd] = d; }
        }
    }
}

// ---------------- GEMM2 v3: h2 = elu(out1+b1) @ W2 (128->32), 4x4 blocking -----------
__global__ __launch_bounds__(256) void k_gemm2(
    const float* __restrict__ xin, const float* __restrict__ W,
    const float* __restrict__ b1,
    const float* __restrict__ att_s, const float* __restrict__ att_d,
    float* __restrict__ h2, float* __restrict__ as2, float* __restrict__ ad2, int N)
{
    __shared__ __align__(16) float sW[16][32];    // 2 KB
    __shared__ __align__(16) float sX[128][16];   // 8 KB
    const int t  = threadIdx.x;
    const int c4 = t & 7;              // col group (cols c4*4 .. c4*4+3)
    const int rg = t >> 3;             // row group (rows rg*4 .. rg*4+3)
    const int row0 = blockIdx.x * 128;
    const float4* W4 = (const float4*)W;          // W row = 8 float4

    float4 acc[4];
#pragma unroll
    for (int i = 0; i < 4; i++) acc[i] = {0.f, 0.f, 0.f, 0.f};

    for (int k0 = 0; k0 < 128; k0 += 16) {
        __syncthreads();
        if (t < 128) {                 // stage W tile: 16x32 = 128 float4
            int r = t >> 3, cc = t & 7;
            *(float4*)&sW[r][cc * 4] = W4[(k0 + r) * 8 + cc];
        }
#pragma unroll
        for (int j = 0; j < 2; j++) {  // stage X tile: 128x16 = 512 float4
            int idx = j * 256 + t;
            int r = idx >> 2, q = idx & 3;
            int row = row0 + r;
            float4 v = {0.f, 0.f, 0.f, 0.f};
            if (row < N) {
                v = *(const float4*)&xin[(long long)row * 128 + k0 + q * 4];
                float4 b = *(const float4*)&b1[k0 + q * 4];
                v.x = elu1f(v.x + b.x); v.y = elu1f(v.y + b.y);
                v.z = elu1f(v.z + b.z); v.w = elu1f(v.w + b.w);
            }
            *(float4*)&sX[r][q * 4] = v;
        }
        __syncthreads();
#pragma unroll
        for (int g = 0; g < 4; g++) {
            const int kk = g * 4;
            const float4 w0 = *(const float4*)&sW[kk + 0][c4 * 4];
            const float4 w1 = *(const float4*)&sW[kk + 1][c4 * 4];
            const float4 w2 = *(const float4*)&sW[kk + 2][c4 * 4];
            const float4 w3 = *(const float4*)&sW[kk + 3][c4 * 4];
#pragma unroll
            for (int i = 0; i < 4; i++) {
                const float4 xv = *(const float4*)&sX[rg * 4 + i][kk];
                acc[i].x = fmaf(xv.x, w0.x, acc[i].x);
                acc[i].y = fmaf(xv.x, w0.y, acc[i].y);
                acc[i].z = fmaf(xv.x, w0.z, acc[i].z);
                acc[i].w = fmaf(xv.x, w0.w, acc[i].w);
                acc[i].x = fmaf(xv.y, w1.x, acc[i].x);
                acc[i].y = fmaf(xv.y, w1.y, acc[i].y);
                acc[i].z = fmaf(xv.y, w1.z, acc[i].z);
                acc[i].w = fmaf(xv.y, w1.w, acc[i].w);
                acc[i].x = fmaf(xv.z, w2.x, acc[i].x);
                acc[i].y = fmaf(xv.z, w2.y, acc[i].y);
                acc[i].z = fmaf(xv.z, w2.z, acc[i].z);
                acc[i].w = fmaf(xv.z, w2.w, acc[i].w);
                acc[i].x = fmaf(xv.w, w3.x, acc[i].x);
                acc[i].y = fmaf(xv.w, w3.y, acc[i].y);
                acc[i].z = fmaf(xv.w, w3.z, acc[i].z);
                acc[i].w = fmaf(xv.w, w3.w, acc[i].w);
            }
        }
    }

    const float4 avs = *(const float4*)&att_s[c4 * 4];
    const float4 avd = *(const float4*)&att_d[c4 * 4];
#pragma unroll
    for (int i = 0; i < 4; i++) {
        int row = row0 + rg * 4 + i;
        if (row < N) {
            *(float4*)&h2[(long long)row * 32 + c4 * 4] = acc[i];
            float s = acc[i].x * avs.x + acc[i].y * avs.y + acc[i].z * avs.z + acc[i].w * avs.w;
            float d = acc[i].x * avd.x + acc[i].y * avd.y + acc[i].z * avd.z + acc[i].w * avd.w;
#pragma unroll
            for (int off = 4; off > 0; off >>= 1) {    // reduce over 8 col-threads
                s += __shfl_xor(s, off, 64);
                d += __shfl_xor(d, off, 64);
            }
            if (c4 == 0) { as2[row] = s; ad2[row] = d; }
        }
    }
}

// ========== Fused GAT aggregation, layer 1 (H=4, C=32): one wave per dst ==========
__global__ __launch_bounds__(256) void k_agg1(
    const int* __restrict__ row, const int* __restrict__ esrc,
    const float* __restrict__ as, const float* __restrict__ ad,   // [N][4]
    const ushort* __restrict__ h,                                 // [N][128] bf16
    float* __restrict__ out, int N)                               // [N][128]
{
    const int lane = threadIdx.x & 63;
    const int wid  = threadIdx.x >> 6;
    const int n = blockIdx.x * 4 + wid;
    if (n >= N) return;
    const int e0 = row[n], e1 = row[n + 1];

    const float4 ad4 = *(const float4*)&ad[n * 4];

    // ---- phase 1: per-head max over in-edges ----
    float m0 = -INFINITY, m1 = -INFINITY, m2 = -INFINITY, m3 = -INFINITY;
    for (int e = e0 + lane; e < e1; e += 64) {
        const int s = esrc[e];
        const float4 a4 = *(const float4*)&as[s * 4];
        float v0 = a4.x + ad4.x; v0 = v0 >= 0.f ? v0 : NEG_SLOPE * v0;
        float v1 = a4.y + ad4.y; v1 = v1 >= 0.f ? v1 : NEG_SLOPE * v1;
        float v2 = a4.z + ad4.z; v2 = v2 >= 0.f ? v2 : NEG_SLOPE * v2;
        float v3 = a4.w + ad4.w; v3 = v3 >= 0.f ? v3 : NEG_SLOPE * v3;
        m0 = fmaxf(m0, v0); m1 = fmaxf(m1, v1);
        m2 = fmaxf(m2, v2); m3 = fmaxf(m3, v3);
    }
#pragma unroll
    for (int off = 32; off > 0; off >>= 1) {
        m0 = fmaxf(m0, __shfl_xor(m0, off, 64));
        m1 = fmaxf(m1, __shfl_xor(m1, off, 64));
        m2 = fmaxf(m2, __shfl_xor(m2, off, 64));
        m3 = fmaxf(m3, __shfl_xor(m3, off, 64));
    }

    // ---- phase 2: 4 edges per iteration, 2 per half ----
    const int half = lane >> 5;
    const int l    = lane & 31;                 // 4 cols per lane: l*4..l*4+3
    const int hd   = l >> 3;                    // head of those cols
    const float adh = hd == 0 ? ad4.x : hd == 1 ? ad4.y : hd == 2 ? ad4.z : ad4.w;
    const float mh  = hd == 0 ? m0  : hd == 1 ? m1  : hd == 2 ? m2  : m3;

    float4 acc = {0.f, 0.f, 0.f, 0.f};
    float wsum = 0.f;
    for (int base = e0; base < e1; base += 4) {
        const int eA = base + half;             // covers base, base+1
        const int eB = base + 2 + half;         // covers base+2, base+3
        const bool vA = eA < e1, vB = eB < e1;
        const int sA = vA ? esrc[eA] : 0;
        const int sB = vB ? esrc[eB] : 0;
        const float4 aA = *(const float4*)&as[sA * 4];
        const float4 aB = *(const float4*)&as[sB * 4];
        const ushort4 hA = *(const ushort4*)&h[(long long)sA * 128 + l * 4];
        const ushort4 hB = *(const ushort4*)&h[(long long)sB * 128 + l * 4];

        float ashA = hd == 0 ? aA.x : hd == 1 ? aA.y : hd == 2 ? aA.z : aA.w;
        float evA = ashA + adh;
        evA = evA >= 0.f ? evA : NEG_SLOPE * evA;
        const float wA = vA ? __expf(evA - mh) : 0.f;

        float ashB = hd == 0 ? aB.x : hd == 1 ? aB.y : hd == 2 ? aB.z : aB.w;
        float evB = ashB + adh;
        evB = evB >= 0.f ? evB : NEG_SLOPE * evB;
        const float wB = vB ? __expf(evB - mh) : 0.f;

        acc.x = fmaf(wA, bf2f(hA.x), acc.x);
        acc.y = fmaf(wA, bf2f(hA.y), acc.y);
        acc.z = fmaf(wA, bf2f(hA.z), acc.z);
        acc.w = fmaf(wA, bf2f(hA.w), acc.w);
        acc.x = fmaf(wB, bf2f(hB.x), acc.x);
        acc.y = fmaf(wB, bf2f(hB.y), acc.y);
        acc.z = fmaf(wB, bf2f(hB.z), acc.z);
        acc.w = fmaf(wB, bf2f(hB.w), acc.w);
        wsum += wA + wB;
    }
    acc.x += __shfl_xor(acc.x, 32, 64);
    acc.y += __shfl_xor(acc.y, 32, 64);
    acc.z += __shfl_xor(acc.z, 32, 64);
    acc.w += __shfl_xor(acc.w, 32, 64);
    wsum  += __shfl_xor(wsum, 32, 64);

    if (half == 0) {
        const float inv = 1.f / (wsum + 1e-16f);
        float4 o; o.x = acc.x * inv; o.y = acc.y * inv; o.z = acc.z * inv; o.w = acc.w * inv;
        *(float4*)&out[(long long)n * 128 + l * 4] = o;
    }
}

// ========== Fused GAT aggregation, layer 2 (H=1, C=32): one wave per dst ==========
__global__ __launch_bounds__(256) void k_agg2(
    const int* __restrict__ row, const int* __restrict__ esrc,
    const float* __restrict__ as, const float* __restrict__ ad,   // [N]
    const float* __restrict__ h,                                  // [N][32]
    float* __restrict__ out, int N)                               // [N][32]
{
    const int lane = threadIdx.x & 63;
    const int wid  = threadIdx.x >> 6;
    const int n = blockIdx.x * 4 + wid;
    if (n >= N) return;
    const int e0 = row[n], e1 = row[n + 1];
    const float adv = ad[n];

    float m = -INFINITY;
    for (int e = e0 + lane; e < e1; e += 64) {
        float ev = as[esrc[e]] + adv;
        ev = ev >= 0.f ? ev : NEG_SLOPE * ev;
        m = fmaxf(m, ev);
    }
#pragma unroll
    for (int off = 32; off > 0; off >>= 1) m = fmaxf(m, __shfl_xor(m, off, 64));

    const int g  = lane >> 3;                    // edge slot 0..7
    const int l8 = lane & 7;                     // 4 cols: l8*4..l8*4+3
    float4 acc = {0.f, 0.f, 0.f, 0.f};
    float wsum = 0.f;
    for (int base = e0; base < e1; base += 16) {
        const int eA = base + g, eB = base + 8 + g;
        const bool vA = eA < e1, vB = eB < e1;
        const int sA = vA ? esrc[eA] : 0;
        const int sB = vB ? esrc[eB] : 0;
        const float asA = as[sA], asB = as[sB];
        const float4 hA = *(const float4*)&h[(long long)sA * 32 + l8 * 4];
        const float4 hB = *(const float4*)&h[(long long)sB * 32 + l8 * 4];

        float evA = asA + adv; evA = evA >= 0.f ? evA : NEG_SLOPE * evA;
        const float wA = vA ? __expf(evA - m) : 0.f;
        float evB = asB + adv; evB = evB >= 0.f ? evB : NEG_SLOPE * evB;
        const float wB = vB ? __expf(evB - m) : 0.f;

        acc.x = fmaf(wA, hA.x, acc.x);
        acc.y = fmaf(wA, hA.y, acc.y);
        acc.z = fmaf(wA, hA.z, acc.z);
        acc.w = fmaf(wA, hA.w, acc.w);
        acc.x = fmaf(wB, hB.x, acc.x);
        acc.y = fmaf(wB, hB.y, acc.y);
        acc.z = fmaf(wB, hB.z, acc.z);
        acc.w = fmaf(wB, hB.w, acc.w);
        wsum += wA + wB;
    }
#pragma unroll
    for (int off = 8; off < 64; off <<= 1) {
        acc.x += __shfl_xor(acc.x, off, 64);
        acc.y += __shfl_xor(acc.y, off, 64);
        acc.z += __shfl_xor(acc.z, off, 64);
        acc.w += __shfl_xor(acc.w, off, 64);
        wsum  += __shfl_xor(wsum, off, 64);
    }
    if (lane < 8) {
        const float inv = 1.f / (wsum + 1e-16f);
        float4 o; o.x = acc.x * inv; o.y = acc.y * inv; o.z = acc.z * inv; o.w = acc.w * inv;
        *(float4*)&out[(long long)n * 32 + lane * 4] = o;
    }
}

// ========== Gate MLP: full-grid parallel, one 32-lane group per node ==========
__global__ __launch_bounds__(256) void k_gate(
    const float* __restrict__ out2, const float* __restrict__ b2,
    const float* __restrict__ gw1, const float* __restrict__ gb1,
    const float* __restrict__ gw2, const float* __restrict__ gb2,
    float* __restrict__ gate, int N)
{
    const int c = threadIdx.x & 31, grp = threadIdx.x >> 5;
    const int n = blockIdx.x * 8 + grp;
    if (n >= N) return;
    float v = out2[(long long)n * 32 + c] + b2[c];
    v = elu1f(v);
    float t1 = gb1[c];
#pragma unroll
    for (int k = 0; k < 32; k++) {
        float hk = __shfl(v, k, 32);
        t1 = fmaf(hk, gw1[k * 32 + c], t1);
    }
    t1 = fmaxf(t1, 0.f);
    float gv = t1 * gw2[c];
#pragma unroll
    for (int off = 16; off > 0; off >>= 1) gv += __shfl_xor(gv, off, 32);
    if (c == 0) gate[n] = gv + gb2[0];
}

// ========== Pool stage 0: graph boundaries (batch is sorted) ==========
__global__ __launch_bounds__(128) void k_bounds(
    const int* __restrict__ batch, int* __restrict__ gbound, int N, int G)
{
    int t = threadIdx.x;
    if (t > G) return;
    int lo = 0, hi = N;
    while (lo < hi) { int mid = (lo + hi) >> 1; if (batch[mid] < t) lo = mid + 1; else hi = mid; }
    gbound[t] = lo;
}

// ========== Pool stage 1: per-chunk max -> atomicMax per block (8 chunks/graph) =====
__global__ __launch_bounds__(256) void k_gmax(
    const float* __restrict__ gate, const int* __restrict__ gbound,
    unsigned* __restrict__ gmax)
{
    const int g  = blockIdx.x >> 3;
    const int ch = blockIdx.x & 7;
    const int s0 = gbound[g], s1 = gbound[g + 1];
    const int len = s1 - s0;
    const int c0 = s0 + (int)(((long long)len * ch) >> 3);
    const int c1 = s0 + (int)(((long long)len * (ch + 1)) >> 3);

    __shared__ float sred[4];
    float m = -INFINITY;
    for (int n = c0 + threadIdx.x; n < c1; n += 256) m = fmaxf(m, gate[n]);
#pragma unroll
    for (int off = 32; off > 0; off >>= 1) m = fmaxf(m, __shfl_xor(m, off, 64));
    if ((threadIdx.x & 63) == 0) sred[threadIdx.x >> 6] = m;
    __syncthreads();
    if (threadIdx.x == 0) {
        m = fmaxf(fmaxf(sred[0], sred[1]), fmaxf(sred[2], sred[3]));
        atomicMax(&gmax[g], fflip(m));
    }
}

// ========== Pool stage 2: per-chunk partial weighted sums (no atomics) ==========
__global__ __launch_bounds__(256) void k_pool3(
    const float* __restrict__ out2, const float* __restrict__ b2,
    const float* __restrict__ gate, const int* __restrict__ gbound,
    const unsigned* __restrict__ gmax, float* __restrict__ partials)
{
    const int g  = blockIdx.x >> 3;
    const int ch = blockIdx.x & 7;
    const int s0 = gbound[g], s1 = gbound[g + 1];
    const int len = s1 - s0;
    const int c0 = s0 + (int)(((long long)len * ch) >> 3);
    const int c1 = s0 + (int)(((long long)len * (ch + 1)) >> 3);

    const int c   = threadIdx.x & 31;
    const int grp = threadIdx.x >> 5;
    const float gm = funflip(gmax[g]);
    const float bc = b2[c];

    __shared__ float sacc[8][32];
    __shared__ float swsum[8];

    float acc = 0.f, wsum = 0.f;
    for (int n = c0 + grp; n < c1; n += 8) {
        float v = elu1f(out2[(long long)n * 32 + c] + bc);
        float ge = __expf(gate[n] - gm);
        acc = fmaf(ge, v, acc);
        wsum += ge;
    }
    sacc[grp][c] = acc;
    if (c == 0) swsum[grp] = wsum;
    __syncthreads();

    if (grp == 0) {
        float a = 0.f, wtot = 0.f;
#pragma unroll
        for (int i = 0; i < 8; i++) { a += sacc[i][c]; wtot += swsum[i]; }
        partials[(long long)blockIdx.x * 33 + c] = a;
        if (c == 0) partials[(long long)blockIdx.x * 33 + 32] = wtot;
    }
}

// ========== Pool stage 3: reduce 8 partials per graph, divide, write out ==========
__global__ __launch_bounds__(256) void k_pool4(
    const float* __restrict__ partials, float* __restrict__ out)
{
    const int g   = blockIdx.x;
    const int c   = threadIdx.x & 31;
    const int p   = threadIdx.x >> 5;

    __shared__ float sacc[8][32];
    __shared__ float swsum[8];

    sacc[p][c] = partials[(long long)(g * 8 + p) * 33 + c];
    if (c == 0) swsum[p] = partials[(long long)(g * 8 + p) * 33 + 32];
    __syncthreads();

    if (p == 0) {
        float a = 0.f, wtot = 0.f;
#pragma unroll
        for (int i = 0; i < 8; i++) { a += sacc[i][c]; wtot += swsum[i]; }
        out[g * 32 + c] = a / (wtot + 1e-16f);
    }
}

extern "C" void kernel_launch(void* const* d_in, const int* in_sizes, int n_in,
                              void* d_out, int out_size, void* d_ws, size_t ws_size,
                              hipStream_t stream)
{
    const float* x    = (const float*)d_in[0];
    const int*   ei   = (const int*)d_in[1];
    const int*   batch= (const int*)d_in[2];
    const float* W1   = (const float*)d_in[3];
    const float* as1w = (const float*)d_in[4];
    const float* ad1w = (const float*)d_in[5];
    const float* b1   = (const float*)d_in[6];
    const float* W2   = (const float*)d_in[7];
    const float* as2w = (const float*)d_in[8];
    const float* ad2w = (const float*)d_in[9];
    const float* b2   = (const float*)d_in[10];
    const float* gw1  = (const float*)d_in[11];
    const float* gb1  = (const float*)d_in[12];
    const float* gw2  = (const float*)d_in[13];
    const float* gb2  = (const float*)d_in[14];

    const int N  = in_sizes[2];
    const int E  = in_sizes[1] / 2;
    const int Et = E + N;
    const int nb = (N + 255) / 256;
    const int G  = 64;

    float* ws = (float*)d_ws;
    size_t o = 0;
    ushort* h1 = (ushort*)(ws + o); o += (size_t)N * 64;   // bf16 [N][128]
    float* out1 = ws + o; o += (size_t)N * 128;
    float* h2   = ws + o; o += (size_t)N * 32;
    float* out2 = ws + o; o += (size_t)N * 32;
    float* a_s1 = ws + o; o += (size_t)N * 4;
    float* a_d1 = ws + o; o += (size_t)N * 4;
    float* a_s2 = ws + o; o += (size_t)N;
    float* a_d2 = ws + o; o += (size_t)N;
    float* gate = ws + o; o += (size_t)N;
    int*   rowp = (int*)(ws + o); o += (size_t)N + 1;
    int*   curs = (int*)(ws + o); o += (size_t)N;
    int*   esrc = (int*)(ws + o); o += (size_t)Et;
    int*   bsum = (int*)(ws + o); o += 256;
    int*   gbound = (int*)(ws + o); o += G + 1;
    float* partials = ws + o; o += (size_t)G * 8 * 33;
    // ---- zeroed region (one memset): deg + gmax ----
    size_t zstart = o;
    int*      deg  = (int*)(ws + o); o += (size_t)N;
    unsigned* gmax = (unsigned*)(ws + o); o += G;
    size_t zbytes = (o - zstart) * sizeof(float);

    hipMemsetAsync(ws + zstart, 0, zbytes, stream);

    // ---- CSR build (shared by both layers) ----
    k_deg    <<<(Et + 255) / 256, 256, 0, stream>>>(ei, E, Et, deg);
    k_scan1  <<<nb, 256, 0, stream>>>(deg, N, rowp, bsum);
    k_scan2  <<<1, 256, 0, stream>>>(bsum, nb);
    k_scan3  <<<nb, 256, 0, stream>>>(rowp, bsum, N, Et, curs);
    k_scatter<<<(Et + 255) / 256, 256, 0, stream>>>(ei, E, Et, curs, esrc);
    k_bounds <<<1, 128, 0, stream>>>(batch, gbound, N, G);

    // ---- GAT layer 1 ----
    k_gemm1<<<(N + 31) / 32, 256, 0, stream>>>(x, W1, as1w, ad1w, h1, a_s1, a_d1, N);
    k_agg1 <<<(N + 3) / 4, 256, 0, stream>>>(rowp, esrc, a_s1, a_d1, h1, out1, N);

    // ---- GAT layer 2 (elu(out1+b1) fused into gemm2 load) ----
    k_gemm2<<<(N + 127) / 128, 256, 0, stream>>>(out1, W2, b1, as2w, ad2w, h2, a_s2, a_d2, N);
    k_agg2 <<<(N + 3) / 4, 256, 0, stream>>>(rowp, esrc, a_s2, a_d2, h2, out2, N);

    // ---- attentional pooling: gate, chunked max, partial sums, final reduce ----
    k_gate <<<(N + 7) / 8, 256, 0, stream>>>(out2, b2, gw1, gb1, gw2, gb2, gate, N);
    k_gmax <<<G * 8, 256, 0, stream>>>(gate, gbound, gmax);
    k_pool3<<<G * 8, 256, 0, stream>>>(out2, b2, gate, gbound, gmax, partials);
    k_pool4<<<G, 256, 0, stream>>>(partials, (float*)d_out);
}

// Round 10
// 281.194 us; speedup vs baseline: 5.5128x; 1.0003x over previous
//
#include <hip/hip_runtime.h>
#include <hip/hip_bf16.h>

#define NEG_SLOPE 0.2f

__device__ __forceinline__ float elu1f(float v) {
    return v > 0.f ? v : expm1f(v);
}
__device__ __forceinline__ float bf2f(ushort u) {
    return __uint_as_float(((unsigned)u) << 16);
}
__device__ __forceinline__ ushort f2bf(float f) {
    return __bfloat16_as_ushort(__float2bfloat16(f));
}
__device__ __forceinline__ unsigned fflip(float f) {
    unsigned u = __float_as_uint(f);
    return (u & 0x80000000u) ? ~u : (u | 0x80000000u);
}
__device__ __forceinline__ float funflip(unsigned u) {
    u = (u & 0x80000000u) ? (u & 0x7FFFFFFFu) : ~u;
    return __uint_as_float(u);
}

// ======================= CSR build (by dst) =======================
__global__ void k_deg(const int* __restrict__ ei, int E, int Et, int* __restrict__ deg)
{
    int i = blockIdx.x * 256 + threadIdx.x;
    if (i >= Et) return;
    int d = (i < E) ? ei[E + i] : i - E;
    atomicAdd(&deg[d], 1);
}

__global__ __launch_bounds__(256) void k_scan1(const int* __restrict__ deg, int N,
                                               int* __restrict__ row, int* __restrict__ bsum)
{
    __shared__ int s[256];
    int i = blockIdx.x * 256 + threadIdx.x;
    int v = (i < N) ? deg[i] : 0;
    s[threadIdx.x] = v;
    __syncthreads();
#pragma unroll
    for (int off = 1; off < 256; off <<= 1) {
        int t = (threadIdx.x >= off) ? s[threadIdx.x - off] : 0;
        __syncthreads();
        s[threadIdx.x] += t;
        __syncthreads();
    }
    if (i < N) row[i] = s[threadIdx.x] - v;          // exclusive
    if (threadIdx.x == 255) bsum[blockIdx.x] = s[255];
}

__global__ __launch_bounds__(256) void k_scan2(int* __restrict__ bsum, int nb)
{
    __shared__ int s[256];
    int v = (threadIdx.x < nb) ? bsum[threadIdx.x] : 0;
    s[threadIdx.x] = v;
    __syncthreads();
#pragma unroll
    for (int off = 1; off < 256; off <<= 1) {
        int t = (threadIdx.x >= off) ? s[threadIdx.x - off] : 0;
        __syncthreads();
        s[threadIdx.x] += t;
        __syncthreads();
    }
    if (threadIdx.x < nb) bsum[threadIdx.x] = s[threadIdx.x] - v;   // exclusive
}

__global__ void k_scan3(int* __restrict__ row, const int* __restrict__ bsum,
                        int N, int Et, int* __restrict__ cursor)
{
    int i = blockIdx.x * 256 + threadIdx.x;
    if (i < N) {
        int r = row[i] + bsum[blockIdx.x];
        row[i] = r;
        cursor[i] = r;
    }
    if (i == 0) row[N] = Et;
}

__global__ void k_scatter(const int* __restrict__ ei, int E, int Et,
                          int* __restrict__ cursor, int* __restrict__ esrc)
{
    int i = blockIdx.x * 256 + threadIdx.x;
    if (i >= Et) return;
    int s, d;
    if (i < E) { s = ei[i]; d = ei[E + i]; } else { s = i - E; d = s; }
    int pos = atomicAdd(&cursor[d], 1);
    esrc[pos] = s;
}

// ========== tiny reduce: per-block flipped maxes -> global max (plain float) ==========
template <int H>
__global__ __launch_bounds__(256) void k_redmax(const unsigned* __restrict__ in, int nblk,
                                                float* __restrict__ out)
{
    __shared__ unsigned sm[H];
    if (threadIdx.x < H) sm[threadIdx.x] = 0;
    __syncthreads();
    unsigned m[H];
#pragma unroll
    for (int h = 0; h < H; h++) m[h] = 0;
    for (int i = threadIdx.x; i < nblk; i += 256) {
#pragma unroll
        for (int h = 0; h < H; h++) m[h] = max(m[h], in[i * H + h]);
    }
#pragma unroll
    for (int h = 0; h < H; h++) atomicMax(&sm[h], m[h]);
    __syncthreads();
    if (threadIdx.x < H) out[threadIdx.x] = funflip(sm[threadIdx.x]);
}

// ---------------- GEMM1: h1(bf16) = x @ W1 (128->128), 4x4 blocking, + blkmax of as1 --
__global__ __launch_bounds__(256) void k_gemm1(
    const float* __restrict__ x, const float* __restrict__ W,
    const float* __restrict__ att_s, const float* __restrict__ att_d,
    ushort* __restrict__ h1, float* __restrict__ as1, float* __restrict__ ad1,
    unsigned* __restrict__ blkmax, int N)
{
    __shared__ __align__(16) float sW[16][128];   // 8 KB
    __shared__ __align__(16) float sX[32][16];    // 2 KB
    __shared__ unsigned smax[4];
    const int t  = threadIdx.x;
    const int c4 = t & 31;             // col group (cols c4*4 .. c4*4+3)
    const int rg = t >> 5;             // row group (rows rg*4 .. rg*4+3)
    const int row0 = blockIdx.x * 32;
    const float4* W4 = (const float4*)W;   // W row = 32 float4

    if (t < 4) smax[t] = 0;            // first loop barrier makes this visible

    float4 acc[4];
#pragma unroll
    for (int i = 0; i < 4; i++) acc[i] = {0.f, 0.f, 0.f, 0.f};

    for (int k0 = 0; k0 < 128; k0 += 16) {
        __syncthreads();
#pragma unroll
        for (int j = 0; j < 2; j++) {
            int idx = j * 256 + t;                 // 0..511
            int r = idx >> 5, cc = idx & 31;
            *(float4*)&sW[r][cc * 4] = W4[(k0 + r) * 32 + cc];
        }
        if (t < 128) {
            int r = t >> 2, q = t & 3;
            int row = row0 + r;
            float4 v = {0.f, 0.f, 0.f, 0.f};
            if (row < N) v = *(const float4*)&x[(long long)row * 128 + k0 + q * 4];
            *(float4*)&sX[r][q * 4] = v;
        }
        __syncthreads();
#pragma unroll
        for (int g = 0; g < 4; g++) {
            const int kk = g * 4;
            const float4 w0 = *(const float4*)&sW[kk + 0][c4 * 4];
            const float4 w1 = *(const float4*)&sW[kk + 1][c4 * 4];
            const float4 w2 = *(const float4*)&sW[kk + 2][c4 * 4];
            const float4 w3 = *(const float4*)&sW[kk + 3][c4 * 4];
#pragma unroll
            for (int i = 0; i < 4; i++) {
                const float4 xv = *(const float4*)&sX[rg * 4 + i][kk];  // broadcast
                acc[i].x = fmaf(xv.x, w0.x, acc[i].x);
                acc[i].y = fmaf(xv.x, w0.y, acc[i].y);
                acc[i].z = fmaf(xv.x, w0.z, acc[i].z);
                acc[i].w = fmaf(xv.x, w0.w, acc[i].w);
                acc[i].x = fmaf(xv.y, w1.x, acc[i].x);
                acc[i].y = fmaf(xv.y, w1.y, acc[i].y);
                acc[i].z = fmaf(xv.y, w1.z, acc[i].z);
                acc[i].w = fmaf(xv.y, w1.w, acc[i].w);
                acc[i].x = fmaf(xv.z, w2.x, acc[i].x);
                acc[i].y = fmaf(xv.z, w2.y, acc[i].y);
                acc[i].z = fmaf(xv.z, w2.z, acc[i].z);
                acc[i].w = fmaf(xv.z, w2.w, acc[i].w);
                acc[i].x = fmaf(xv.w, w3.x, acc[i].x);
                acc[i].y = fmaf(xv.w, w3.y, acc[i].y);
                acc[i].z = fmaf(xv.w, w3.z, acc[i].z);
                acc[i].w = fmaf(xv.w, w3.w, acc[i].w);
            }
        }
    }

    const float4 avs = *(const float4*)&att_s[c4 * 4];
    const float4 avd = *(const float4*)&att_d[c4 * 4];
    const int hd = c4 >> 3;                        // head of this thread's 4 cols
    float lmax = -INFINITY;
#pragma unroll
    for (int i = 0; i < 4; i++) {
        int row = row0 + rg * 4 + i;
        if (row < N) {
            ushort4 hb;
            hb.x = f2bf(acc[i].x); hb.y = f2bf(acc[i].y);
            hb.z = f2bf(acc[i].z); hb.w = f2bf(acc[i].w);
            *(ushort4*)&h1[(long long)row * 128 + c4 * 4] = hb;
            float s = acc[i].x * avs.x + acc[i].y * avs.y + acc[i].z * avs.z + acc[i].w * avs.w;
            float d = acc[i].x * avd.x + acc[i].y * avd.y + acc[i].z * avd.z + acc[i].w * avd.w;
#pragma unroll
            for (int off = 4; off > 0; off >>= 1) {    // reduce over 8 col-threads of head
                s += __shfl_xor(s, off, 64);
                d += __shfl_xor(d, off, 64);
            }
            if ((c4 & 7) == 0) {
                as1[row * 4 + hd] = s; ad1[row * 4 + hd] = d;
                lmax = fmaxf(lmax, s);
            }
        }
    }
    if ((c4 & 7) == 0) atomicMax(&smax[hd], fflip(lmax));
    __syncthreads();
    if (t < 4) blkmax[blockIdx.x * 4 + t] = smax[t];
}

// ---------------- GEMM2: h2 = elu(out1+b1) @ W2 (128->32), 4x4 blocking, + blkmax -----
__global__ __launch_bounds__(256) void k_gemm2(
    const float* __restrict__ xin, const float* __restrict__ W,
    const float* __restrict__ b1,
    const float* __restrict__ att_s, const float* __restrict__ att_d,
    float* __restrict__ h2, float* __restrict__ as2, float* __restrict__ ad2,
    unsigned* __restrict__ blkmax, int N)
{
    __shared__ __align__(16) float sW[16][32];    // 2 KB
    __shared__ __align__(16) float sX[128][16];   // 8 KB
    __shared__ unsigned smax1;
    const int t  = threadIdx.x;
    const int c4 = t & 7;              // col group (cols c4*4 .. c4*4+3)
    const int rg = t >> 3;             // row group (rows rg*4 .. rg*4+3)
    const int row0 = blockIdx.x * 128;
    const float4* W4 = (const float4*)W;          // W row = 8 float4

    if (t == 0) smax1 = 0;

    float4 acc[4];
#pragma unroll
    for (int i = 0; i < 4; i++) acc[i] = {0.f, 0.f, 0.f, 0.f};

    for (int k0 = 0; k0 < 128; k0 += 16) {
        __syncthreads();
        if (t < 128) {                 // stage W tile: 16x32 = 128 float4
            int r = t >> 3, cc = t & 7;
            *(float4*)&sW[r][cc * 4] = W4[(k0 + r) * 8 + cc];
        }
#pragma unroll
        for (int j = 0; j < 2; j++) {  // stage X tile: 128x16 = 512 float4
            int idx = j * 256 + t;
            int r = idx >> 2, q = idx & 3;
            int row = row0 + r;
            float4 v = {0.f, 0.f, 0.f, 0.f};
            if (row < N) {
                v = *(const float4*)&xin[(long long)row * 128 + k0 + q * 4];
                float4 b = *(const float4*)&b1[k0 + q * 4];
                v.x = elu1f(v.x + b.x); v.y = elu1f(v.y + b.y);
                v.z = elu1f(v.z + b.z); v.w = elu1f(v.w + b.w);
            }
            *(float4*)&sX[r][q * 4] = v;
        }
        __syncthreads();
#pragma unroll
        for (int g = 0; g < 4; g++) {
            const int kk = g * 4;
            const float4 w0 = *(const float4*)&sW[kk + 0][c4 * 4];
            const float4 w1 = *(const float4*)&sW[kk + 1][c4 * 4];
            const float4 w2 = *(const float4*)&sW[kk + 2][c4 * 4];
            const float4 w3 = *(const float4*)&sW[kk + 3][c4 * 4];
#pragma unroll
            for (int i = 0; i < 4; i++) {
                const float4 xv = *(const float4*)&sX[rg * 4 + i][kk];
                acc[i].x = fmaf(xv.x, w0.x, acc[i].x);
                acc[i].y = fmaf(xv.x, w0.y, acc[i].y);
                acc[i].z = fmaf(xv.x, w0.z, acc[i].z);
                acc[i].w = fmaf(xv.x, w0.w, acc[i].w);
                acc[i].x = fmaf(xv.y, w1.x, acc[i].x);
                acc[i].y = fmaf(xv.y, w1.y, acc[i].y);
                acc[i].z = fmaf(xv.y, w1.z, acc[i].z);
                acc[i].w = fmaf(xv.y, w1.w, acc[i].w);
                acc[i].x = fmaf(xv.z, w2.x, acc[i].x);
                acc[i].y = fmaf(xv.z, w2.y, acc[i].y);
                acc[i].z = fmaf(xv.z, w2.z, acc[i].z);
                acc[i].w = fmaf(xv.z, w2.w, acc[i].w);
                acc[i].x = fmaf(xv.w, w3.x, acc[i].x);
                acc[i].y = fmaf(xv.w, w3.y, acc[i].y);
                acc[i].z = fmaf(xv.w, w3.z, acc[i].z);
                acc[i].w = fmaf(xv.w, w3.w, acc[i].w);
            }
        }
    }

    const float4 avs = *(const float4*)&att_s[c4 * 4];
    const float4 avd = *(const float4*)&att_d[c4 * 4];
    float lmax = -INFINITY;
#pragma unroll
    for (int i = 0; i < 4; i++) {
        int row = row0 + rg * 4 + i;
        if (row < N) {
            *(float4*)&h2[(long long)row * 32 + c4 * 4] = acc[i];
            float s = acc[i].x * avs.x + acc[i].y * avs.y + acc[i].z * avs.z + acc[i].w * avs.w;
            float d = acc[i].x * avd.x + acc[i].y * avd.y + acc[i].z * avd.z + acc[i].w * avd.w;
#pragma unroll
            for (int off = 4; off > 0; off >>= 1) {    // reduce over 8 col-threads
                s += __shfl_xor(s, off, 64);
                d += __shfl_xor(d, off, 64);
            }
            if (c4 == 0) {
                as2[row] = s; ad2[row] = d;
                lmax = fmaxf(lmax, s);
            }
        }
    }
    if (c4 == 0) atomicMax(&smax1, fflip(lmax));
    __syncthreads();
    if (t == 0) blkmax[blockIdx.x] = smax1;
}

// ========== Fused GAT aggregation, layer 1 (H=4, C=32): one wave per dst ==========
// No per-node max pass: m = lrelu(global_max(as)[h] + ad[n][h]) is a safe upper bound
// (softmax is shift-invariant). 8 edges in flight per iteration (4 per 32-lane half).
__global__ __launch_bounds__(256) void k_agg1(
    const int* __restrict__ row, const int* __restrict__ esrc,
    const float* __restrict__ as, const float* __restrict__ ad,   // [N][4]
    const float* __restrict__ gmaxh,                              // [4]
    const ushort* __restrict__ h,                                 // [N][128] bf16
    float* __restrict__ out, int N)                               // [N][128]
{
    const int lane = threadIdx.x & 63;
    const int wid  = threadIdx.x >> 6;
    const int n = blockIdx.x * 4 + wid;
    if (n >= N) return;
    const int e0 = row[n], e1 = row[n + 1];

    const float4 ad4 = *(const float4*)&ad[n * 4];
    const int half = lane >> 5;
    const int l    = lane & 31;                 // 4 cols per lane: l*4..l*4+3
    const int hd   = l >> 3;                    // head of those cols
    const float adh = hd == 0 ? ad4.x : hd == 1 ? ad4.y : hd == 2 ? ad4.z : ad4.w;
    float mh = gmaxh[hd] + adh;
    mh = mh >= 0.f ? mh : NEG_SLOPE * mh;

    const unsigned lofs = (unsigned)(l * 4);
    float4 acc = {0.f, 0.f, 0.f, 0.f};
    float wsum = 0.f;
    for (int base = e0; base < e1; base += 8) {
        const int eA = base + half,     eB = base + 2 + half;
        const int eC = base + 4 + half, eD = base + 6 + half;
        const bool vA = eA < e1, vB = eB < e1, vC = eC < e1, vD = eD < e1;
        const int sA = vA ? esrc[eA] : 0;
        const int sB = vB ? esrc[eB] : 0;
        const int sC = vC ? esrc[eC] : 0;
        const int sD = vD ? esrc[eD] : 0;
        const float4 aA = *(const float4*)&as[sA * 4];
        const float4 aB = *(const float4*)&as[sB * 4];
        const float4 aC = *(const float4*)&as[sC * 4];
        const float4 aD = *(const float4*)&as[sD * 4];
        const ushort4 hA = *(const ushort4*)&h[(unsigned)sA * 128u + lofs];
        const ushort4 hB = *(const ushort4*)&h[(unsigned)sB * 128u + lofs];
        const ushort4 hC = *(const ushort4*)&h[(unsigned)sC * 128u + lofs];
        const ushort4 hD = *(const ushort4*)&h[(unsigned)sD * 128u + lofs];

        float evA = (hd == 0 ? aA.x : hd == 1 ? aA.y : hd == 2 ? aA.z : aA.w) + adh;
        evA = evA >= 0.f ? evA : NEG_SLOPE * evA;
        const float wA = vA ? __expf(evA - mh) : 0.f;
        float evB = (hd == 0 ? aB.x : hd == 1 ? aB.y : hd == 2 ? aB.z : aB.w) + adh;
        evB = evB >= 0.f ? evB : NEG_SLOPE * evB;
        const float wB = vB ? __expf(evB - mh) : 0.f;
        float evC = (hd == 0 ? aC.x : hd == 1 ? aC.y : hd == 2 ? aC.z : aC.w) + adh;
        evC = evC >= 0.f ? evC : NEG_SLOPE * evC;
        const float wC = vC ? __expf(evC - mh) : 0.f;
        float evD = (hd == 0 ? aD.x : hd == 1 ? aD.y : hd == 2 ? aD.z : aD.w) + adh;
        evD = evD >= 0.f ? evD : NEG_SLOPE * evD;
        const float wD = vD ? __expf(evD - mh) : 0.f;

        acc.x = fmaf(wA, bf2f(hA.x), acc.x);
        acc.y = fmaf(wA, bf2f(hA.y), acc.y);
        acc.z = fmaf(wA, bf2f(hA.z), acc.z);
        acc.w = fmaf(wA, bf2f(hA.w), acc.w);
        acc.x = fmaf(wB, bf2f(hB.x), acc.x);
        acc.y = fmaf(wB, bf2f(hB.y), acc.y);
        acc.z = fmaf(wB, bf2f(hB.z), acc.z);
        acc.w = fmaf(wB, bf2f(hB.w), acc.w);
        acc.x = fmaf(wC, bf2f(hC.x), acc.x);
        acc.y = fmaf(wC, bf2f(hC.y), acc.y);
        acc.z = fmaf(wC, bf2f(hC.z), acc.z);
        acc.w = fmaf(wC, bf2f(hC.w), acc.w);
        acc.x = fmaf(wD, bf2f(hD.x), acc.x);
        acc.y = fmaf(wD, bf2f(hD.y), acc.y);
        acc.z = fmaf(wD, bf2f(hD.z), acc.z);
        acc.w = fmaf(wD, bf2f(hD.w), acc.w);
        wsum += (wA + wB) + (wC + wD);
    }
    acc.x += __shfl_xor(acc.x, 32, 64);
    acc.y += __shfl_xor(acc.y, 32, 64);
    acc.z += __shfl_xor(acc.z, 32, 64);
    acc.w += __shfl_xor(acc.w, 32, 64);
    wsum  += __shfl_xor(wsum, 32, 64);

    if (half == 0) {
        const float inv = 1.f / (wsum + 1e-16f);
        float4 o; o.x = acc.x * inv; o.y = acc.y * inv; o.z = acc.z * inv; o.w = acc.w * inv;
        *(float4*)&out[(long long)n * 128 + l * 4] = o;
    }
}

// ========== Fused GAT aggregation, layer 2 (H=1, C=32): one wave per dst ==========
// Global-bound max, 32 edges in flight (8 slots x 4-deep), float4 per 8 lanes.
__global__ __launch_bounds__(256) void k_agg2(
    const int* __restrict__ row, const int* __restrict__ esrc,
    const float* __restrict__ as, const float* __restrict__ ad,   // [N]
    const float* __restrict__ gmax2,                              // [1]
    const float* __restrict__ h,                                  // [N][32]
    float* __restrict__ out, int N)                               // [N][32]
{
    const int lane = threadIdx.x & 63;
    const int wid  = threadIdx.x >> 6;
    const int n = blockIdx.x * 4 + wid;
    if (n >= N) return;
    const int e0 = row[n], e1 = row[n + 1];
    const float adv = ad[n];
    float m = gmax2[0] + adv;
    m = m >= 0.f ? m : NEG_SLOPE * m;

    const int g  = lane >> 3;                    // edge slot 0..7
    const int l8 = lane & 7;                     // 4 cols: l8*4..l8*4+3
    const unsigned lofs = (unsigned)(l8 * 4);
    float4 acc = {0.f, 0.f, 0.f, 0.f};
    float wsum = 0.f;
    for (int base = e0; base < e1; base += 32) {
        const int eA = base + g,      eB = base + 8 + g;
        const int eC = base + 16 + g, eD = base + 24 + g;
        const bool vA = eA < e1, vB = eB < e1, vC = eC < e1, vD = eD < e1;
        const int sA = vA ? esrc[eA] : 0;
        const int sB = vB ? esrc[eB] : 0;
        const int sC = vC ? esrc[eC] : 0;
        const int sD = vD ? esrc[eD] : 0;
        const float asA = as[sA], asB = as[sB], asC = as[sC], asD = as[sD];
        const float4 hA = *(const float4*)&h[(unsigned)sA * 32u + lofs];
        const float4 hB = *(const float4*)&h[(unsigned)sB * 32u + lofs];
        const float4 hC = *(const float4*)&h[(unsigned)sC * 32u + lofs];
        const float4 hD = *(const float4*)&h[(unsigned)sD * 32u + lofs];

        float evA = asA + adv; evA = evA >= 0.f ? evA : NEG_SLOPE * evA;
        const float wA = vA ? __expf(evA - m) : 0.f;
        float evB = asB + adv; evB = evB >= 0.f ? evB : NEG_SLOPE * evB;
        const float wB = vB ? __expf(evB - m) : 0.f;
        float evC = asC + adv; evC = evC >= 0.f ? evC : NEG_SLOPE * evC;
        const float wC = vC ? __expf(evC - m) : 0.f;
        float evD = asD + adv; evD = evD >= 0.f ? evD : NEG_SLOPE * evD;
        const float wD = vD ? __expf(evD - m) : 0.f;

        acc.x = fmaf(wA, hA.x, acc.x);
        acc.y = fmaf(wA, hA.y, acc.y);
        acc.z = fmaf(wA, hA.z, acc.z);
        acc.w = fmaf(wA, hA.w, acc.w);
        acc.x = fmaf(wB, hB.x, acc.x);
        acc.y = fmaf(wB, hB.y, acc.y);
        acc.z = fmaf(wB, hB.z, acc.z);
        acc.w = fmaf(wB, hB.w, acc.w);
        acc.x = fmaf(wC, hC.x, acc.x);
        acc.y = fmaf(wC, hC.y, acc.y);
        acc.z = fmaf(wC, hC.z, acc.z);
        acc.w = fmaf(wC, hC.w, acc.w);
        acc.x = fmaf(wD, hD.x, acc.x);
        acc.y = fmaf(wD, hD.y, acc.y);
        acc.z = fmaf(wD, hD.z, acc.z);
        acc.w = fmaf(wD, hD.w, acc.w);
        wsum += (wA + wB) + (wC + wD);
    }
#pragma unroll
    for (int off = 8; off < 64; off <<= 1) {
        acc.x += __shfl_xor(acc.x, off, 64);
        acc.y += __shfl_xor(acc.y, off, 64);
        acc.z += __shfl_xor(acc.z, off, 64);
        acc.w += __shfl_xor(acc.w, off, 64);
        wsum  += __shfl_xor(wsum, off, 64);
    }
    if (lane < 8) {
        const float inv = 1.f / (wsum + 1e-16f);
        float4 o; o.x = acc.x * inv; o.y = acc.y * inv; o.z = acc.z * inv; o.w = acc.w * inv;
        *(float4*)&out[(long long)n * 32 + lane * 4] = o;
    }
}

// ========== Gate MLP: full-grid parallel, one 32-lane group per node ==========
__global__ __launch_bounds__(256) void k_gate(
    const float* __restrict__ out2, const float* __restrict__ b2,
    const float* __restrict__ gw1, const float* __restrict__ gb1,
    const float* __restrict__ gw2, const float* __restrict__ gb2,
    float* __restrict__ gate, int N)
{
    const int c = threadIdx.x & 31, grp = threadIdx.x >> 5;
    const int n = blockIdx.x * 8 + grp;
    if (n >= N) return;
    float v = out2[(long long)n * 32 + c] + b2[c];
    v = elu1f(v);
    float t1 = gb1[c];
#pragma unroll
    for (int k = 0; k < 32; k++) {
        float hk = __shfl(v, k, 32);
        t1 = fmaf(hk, gw1[k * 32 + c], t1);
    }
    t1 = fmaxf(t1, 0.f);
    float gv = t1 * gw2[c];
#pragma unroll
    for (int off = 16; off > 0; off >>= 1) gv += __shfl_xor(gv, off, 32);
    if (c == 0) gate[n] = gv + gb2[0];
}

// ========== Pool stage 0: graph boundaries (batch is sorted) ==========
__global__ __launch_bounds__(128) void k_bounds(
    const int* __restrict__ batch, int* __restrict__ gbound, int N, int G)
{
    int t = threadIdx.x;
    if (t > G) return;
    int lo = 0, hi = N;
    while (lo < hi) { int mid = (lo + hi) >> 1; if (batch[mid] < t) lo = mid + 1; else hi = mid; }
    gbound[t] = lo;
}

// ========== Pool stage 1: per-chunk max -> atomicMax per block (8 chunks/graph) =====
__global__ __launch_bounds__(256) void k_gmax(
    const float* __restrict__ gate, const int* __restrict__ gbound,
    unsigned* __restrict__ gmax)
{
    const int g  = blockIdx.x >> 3;
    const int ch = blockIdx.x & 7;
    const int s0 = gbound[g], s1 = gbound[g + 1];
    const int len = s1 - s0;
    const int c0 = s0 + (int)(((long long)len * ch) >> 3);
    const int c1 = s0 + (int)(((long long)len * (ch + 1)) >> 3);

    __shared__ float sred[4];
    float m = -INFINITY;
    for (int n = c0 + threadIdx.x; n < c1; n += 256) m = fmaxf(m, gate[n]);
#pragma unroll
    for (int off = 32; off > 0; off >>= 1) m = fmaxf(m, __shfl_xor(m, off, 64));
    if ((threadIdx.x & 63) == 0) sred[threadIdx.x >> 6] = m;
    __syncthreads();
    if (threadIdx.x == 0) {
        m = fmaxf(fmaxf(sred[0], sred[1]), fmaxf(sred[2], sred[3]));
        atomicMax(&gmax[g], fflip(m));
    }
}

// ========== Pool stage 2: per-chunk partial weighted sums (no atomics) ==========
__global__ __launch_bounds__(256) void k_pool3(
    const float* __restrict__ out2, const float* __restrict__ b2,
    const float* __restrict__ gate, const int* __restrict__ gbound,
    const unsigned* __restrict__ gmax, float* __restrict__ partials)
{
    const int g  = blockIdx.x >> 3;
    const int ch = blockIdx.x & 7;
    const int s0 = gbound[g], s1 = gbound[g + 1];
    const int len = s1 - s0;
    const int c0 = s0 + (int)(((long long)len * ch) >> 3);
    const int c1 = s0 + (int)(((long long)len * (ch + 1)) >> 3);

    const int c   = threadIdx.x & 31;
    const int grp = threadIdx.x >> 5;
    const float gm = funflip(gmax[g]);
    const float bc = b2[c];

    __shared__ float sacc[8][32];
    __shared__ float swsum[8];

    float acc = 0.f, wsum = 0.f;
    for (int n = c0 + grp; n < c1; n += 8) {
        float v = elu1f(out2[(long long)n * 32 + c] + bc);
        float ge = __expf(gate[n] - gm);
        acc = fmaf(ge, v, acc);
        wsum += ge;
    }
    sacc[grp][c] = acc;
    if (c == 0) swsum[grp] = wsum;
    __syncthreads();

    if (grp == 0) {
        float a = 0.f, wtot = 0.f;
#pragma unroll
        for (int i = 0; i < 8; i++) { a += sacc[i][c]; wtot += swsum[i]; }
        partials[(long long)blockIdx.x * 33 + c] = a;
        if (c == 0) partials[(long long)blockIdx.x * 33 + 32] = wtot;
    }
}

// ========== Pool stage 3: reduce 8 partials per graph, divide, write out ==========
__global__ __launch_bounds__(256) void k_pool4(
    const float* __restrict__ partials, float* __restrict__ out)
{
    const int g   = blockIdx.x;
    const int c   = threadIdx.x & 31;
    const int p   = threadIdx.x >> 5;

    __shared__ float sacc[8][32];
    __shared__ float swsum[8];

    sacc[p][c] = partials[(long long)(g * 8 + p) * 33 + c];
    if (c == 0) swsum[p] = partials[(long long)(g * 8 + p) * 33 + 32];
    __syncthreads();

    if (p == 0) {
        float a = 0.f, wtot = 0.f;
#pragma unroll
        for (int i = 0; i < 8; i++) { a += sacc[i][c]; wtot += swsum[i]; }
        out[g * 32 + c] = a / (wtot + 1e-16f);
    }
}

extern "C" void kernel_launch(void* const* d_in, const int* in_sizes, int n_in,
                              void* d_out, int out_size, void* d_ws, size_t ws_size,
                              hipStream_t stream)
{
    const float* x    = (const float*)d_in[0];
    const int*   ei   = (const int*)d_in[1];
    const int*   batch= (const int*)d_in[2];
    const float* W1   = (const float*)d_in[3];
    const float* as1w = (const float*)d_in[4];
    const float* ad1w = (const float*)d_in[5];
    const float* b1   = (const float*)d_in[6];
    const float* W2   = (const float*)d_in[7];
    const float* as2w = (const float*)d_in[8];
    const float* ad2w = (const float*)d_in[9];
    const float* b2   = (const float*)d_in[10];
    const float* gw1  = (const float*)d_in[11];
    const float* gb1  = (const float*)d_in[12];
    const float* gw2  = (const float*)d_in[13];
    const float* gb2  = (const float*)d_in[14];

    const int N  = in_sizes[2];
    const int E  = in_sizes[1] / 2;
    const int Et = E + N;
    const int nb = (N + 255) / 256;
    const int G  = 64;
    const int nblk1 = (N + 31) / 32;     // gemm1 blocks
    const int nblk2 = (N + 127) / 128;   // gemm2 blocks

    float* ws = (float*)d_ws;
    size_t o = 0;
    ushort* h1 = (ushort*)(ws + o); o += (size_t)N * 64;   // bf16 [N][128]
    float* out1 = ws + o; o += (size_t)N * 128;
    float* h2   = ws + o; o += (size_t)N * 32;
    float* out2 = ws + o; o += (size_t)N * 32;
    float* a_s1 = ws + o; o += (size_t)N * 4;
    float* a_d1 = ws + o; o += (size_t)N * 4;
    float* a_s2 = ws + o; o += (size_t)N;
    float* a_d2 = ws + o; o += (size_t)N;
    float* gate = ws + o; o += (size_t)N;
    int*   rowp = (int*)(ws + o); o += (size_t)N + 1;
    int*   curs = (int*)(ws + o); o += (size_t)N;
    int*   esrc = (int*)(ws + o); o += (size_t)Et;
    int*   bsum = (int*)(ws + o); o += 256;
    int*   gbound = (int*)(ws + o); o += G + 1;
    float* partials = ws + o; o += (size_t)G * 8 * 33;
    unsigned* blkmax1 = (unsigned*)(ws + o); o += (size_t)nblk1 * 4;
    unsigned* blkmax2 = (unsigned*)(ws + o); o += (size_t)nblk2;
    float* gmaxh = ws + o; o += 4;
    float* gmax2 = ws + o; o += 4;
    // ---- zeroed region (one memset): deg + gmax ----
    size_t zstart = o;
    int*      deg  = (int*)(ws + o); o += (size_t)N;
    unsigned* gmax = (unsigned*)(ws + o); o += G;
    size_t zbytes = (o - zstart) * sizeof(float);

    hipMemsetAsync(ws + zstart, 0, zbytes, stream);

    // ---- CSR build (shared by both layers) ----
    k_deg    <<<(Et + 255) / 256, 256, 0, stream>>>(ei, E, Et, deg);
    k_scan1  <<<nb, 256, 0, stream>>>(deg, N, rowp, bsum);
    k_scan2  <<<1, 256, 0, stream>>>(bsum, nb);
    k_scan3  <<<nb, 256, 0, stream>>>(rowp, bsum, N, Et, curs);
    k_scatter<<<(Et + 255) / 256, 256, 0, stream>>>(ei, E, Et, curs, esrc);
    k_bounds <<<1, 128, 0, stream>>>(batch, gbound, N, G);

    // ---- GAT layer 1 ----
    k_gemm1<<<nblk1, 256, 0, stream>>>(x, W1, as1w, ad1w, h1, a_s1, a_d1, blkmax1, N);
    k_redmax<4><<<1, 256, 0, stream>>>(blkmax1, nblk1, gmaxh);
    k_agg1 <<<(N + 3) / 4, 256, 0, stream>>>(rowp, esrc, a_s1, a_d1, gmaxh, h1, out1, N);

    // ---- GAT layer 2 (elu(out1+b1) fused into gemm2 load) ----
    k_gemm2<<<nblk2, 256, 0, stream>>>(out1, W2, b1, as2w, ad2w, h2, a_s2, a_d2, blkmax2, N);
    k_redmax<1><<<1, 256, 0, stream>>>(blkmax2, nblk2, gmax2);
    k_agg2 <<<(N + 3) / 4, 256, 0, stream>>>(rowp, esrc, a_s2, a_d2, gmax2, h2, out2, N);

    // ---- attentional pooling: gate, chunked max, partial sums, final reduce ----
    k_gate <<<(N + 7) / 8, 256, 0, stream>>>(out2, b2, gw1, gb1, gw2, gb2, gate, N);
    k_gmax <<<G * 8, 256, 0, stream>>>(gate, gbound, gmax);
    k_pool3<<<G * 8, 256, 0, stream>>>(out2, b2, gate, gbound, gmax, partials);
    k_pool4<<<G, 256, 0, stream>>>(partials, (float*)d_out);
}

// Round 11
// 228.637 us; speedup vs baseline: 6.7800x; 1.2299x over previous
//
#include <hip/hip_runtime.h>
#include <hip/hip_bf16.h>

#define NEG_SLOPE 0.2f
#define BW  128              // bucket width in dst nodes
#define BSH 7

__device__ __forceinline__ float elu1f(float v) {
    return v > 0.f ? v : expm1f(v);
}
__device__ __forceinline__ float bf2f(ushort u) {
    return __uint_as_float(((unsigned)u) << 16);
}
__device__ __forceinline__ ushort f2bf(float f) {
    return __bfloat16_as_ushort(__float2bfloat16(f));
}
__device__ __forceinline__ unsigned fflip(float f) {
    unsigned u = __float_as_uint(f);
    return (u & 0x80000000u) ? ~u : (u | 0x80000000u);
}
__device__ __forceinline__ float funflip(unsigned u) {
    u = (u & 0x80000000u) ? (u & 0x7FFFFFFFu) : ~u;
    return __uint_as_float(u);
}

// ================= Bucketed CSR build (by dst) =================
// bucket b = dst >> 7; nbk = ceil(N/128) (<=512 for this problem size)

__global__ __launch_bounds__(256) void k_bcount(
    const int* __restrict__ ei, int E, int Et, int nbk, int* __restrict__ bcnt)
{
    __shared__ int h[512];
    for (int i = threadIdx.x; i < nbk; i += 256) h[i] = 0;
    __syncthreads();
    const int start = blockIdx.x * 4096;
    const int end   = min(start + 4096, Et);
    for (int i = start + threadIdx.x; i < end; i += 256) {
        int d = (i < E) ? ei[E + i] : i - E;
        atomicAdd(&h[d >> BSH], 1);
    }
    __syncthreads();
    for (int i = threadIdx.x; i < nbk; i += 256)
        if (h[i]) atomicAdd(&bcnt[i], h[i]);
}

__global__ __launch_bounds__(512) void k_bscan(
    const int* __restrict__ bcnt, int nbk, int Et,
    int* __restrict__ bbase, int* __restrict__ bcur)
{
    __shared__ int s[512];
    int v = (threadIdx.x < nbk) ? bcnt[threadIdx.x] : 0;
    s[threadIdx.x] = v;
    __syncthreads();
#pragma unroll
    for (int off = 1; off < 512; off <<= 1) {
        int t = (threadIdx.x >= off) ? s[threadIdx.x - off] : 0;
        __syncthreads();
        s[threadIdx.x] += t;
        __syncthreads();
    }
    if (threadIdx.x < nbk) {
        int ex = s[threadIdx.x] - v;
        bbase[threadIdx.x] = ex;
        bcur[threadIdx.x]  = ex;
    }
    if (threadIdx.x == 0) bbase[nbk] = Et;
}

__global__ __launch_bounds__(256) void k_bscatter(
    const int* __restrict__ ei, int E, int Et, int nbk,
    int* __restrict__ bcur, int2* __restrict__ ebuk)
{
    __shared__ int h[512];
    __shared__ int cur[512];
    for (int i = threadIdx.x; i < nbk; i += 256) h[i] = 0;
    __syncthreads();
    const int start = blockIdx.x * 4096;
    const int end   = min(start + 4096, Et);
    for (int i = start + threadIdx.x; i < end; i += 256) {
        int d = (i < E) ? ei[E + i] : i - E;
        atomicAdd(&h[d >> BSH], 1);
    }
    __syncthreads();
    for (int i = threadIdx.x; i < nbk; i += 256)
        cur[i] = h[i] ? atomicAdd(&bcur[i], h[i]) : 0;
    __syncthreads();
    for (int i = start + threadIdx.x; i < end; i += 256) {
        int s, d;
        if (i < E) { s = ei[i]; d = ei[E + i]; } else { s = i - E; d = s; }
        int p = atomicAdd(&cur[d >> BSH], 1);
        ebuk[p] = make_int2(s, d);
    }
}

__global__ __launch_bounds__(256) void k_bdeg(
    const int2* __restrict__ ebuk, const int* __restrict__ bbase,
    int N, int* __restrict__ deg)
{
    const int b = blockIdx.x;
    __shared__ int cnt[BW];
    if (threadIdx.x < BW) cnt[threadIdx.x] = 0;
    __syncthreads();
    const int d0 = b << BSH;
    const int e0 = bbase[b], e1 = bbase[b + 1];
    for (int i = e0 + threadIdx.x; i < e1; i += 256)
        atomicAdd(&cnt[ebuk[i].y - d0], 1);
    __syncthreads();
    if (threadIdx.x < BW) {
        int d = d0 + threadIdx.x;
        if (d < N) deg[d] = cnt[threadIdx.x];
    }
}

__global__ __launch_bounds__(256) void k_fine(
    const int2* __restrict__ ebuk, const int* __restrict__ bbase,
    const int* __restrict__ rowp, int N, int* __restrict__ esrc)
{
    const int b = blockIdx.x;
    __shared__ int lcur[BW];
    const int d0 = b << BSH;
    if (threadIdx.x < BW) {
        int d = d0 + threadIdx.x;
        lcur[threadIdx.x] = (d < N) ? rowp[d] : 0;
    }
    __syncthreads();
    const int e0 = bbase[b], e1 = bbase[b + 1];
    for (int i = e0 + threadIdx.x; i < e1; i += 256) {
        int2 e = ebuk[i];
        int p = atomicAdd(&lcur[e.y - d0], 1);
        esrc[p] = e.x;
    }
}

// ================= rowp scan over deg =================
__global__ __launch_bounds__(256) void k_scan1(const int* __restrict__ deg, int N,
                                               int* __restrict__ row, int* __restrict__ bsum)
{
    __shared__ int s[256];
    int i = blockIdx.x * 256 + threadIdx.x;
    int v = (i < N) ? deg[i] : 0;
    s[threadIdx.x] = v;
    __syncthreads();
#pragma unroll
    for (int off = 1; off < 256; off <<= 1) {
        int t = (threadIdx.x >= off) ? s[threadIdx.x - off] : 0;
        __syncthreads();
        s[threadIdx.x] += t;
        __syncthreads();
    }
    if (i < N) row[i] = s[threadIdx.x] - v;          // exclusive
    if (threadIdx.x == 255) bsum[blockIdx.x] = s[255];
}

__global__ __launch_bounds__(256) void k_scan2(int* __restrict__ bsum, int nb)
{
    __shared__ int s[256];
    int v = (threadIdx.x < nb) ? bsum[threadIdx.x] : 0;
    s[threadIdx.x] = v;
    __syncthreads();
#pragma unroll
    for (int off = 1; off < 256; off <<= 1) {
        int t = (threadIdx.x >= off) ? s[threadIdx.x - off] : 0;
        __syncthreads();
        s[threadIdx.x] += t;
        __syncthreads();
    }
    if (threadIdx.x < nb) bsum[threadIdx.x] = s[threadIdx.x] - v;   // exclusive
}

__global__ void k_scan3(int* __restrict__ row, const int* __restrict__ bsum, int N, int Et)
{
    int i = blockIdx.x * 256 + threadIdx.x;
    if (i < N) row[i] += bsum[blockIdx.x];
    if (i == 0) row[N] = Et;
}

// ========== tiny reduce: per-block flipped maxes -> global max (plain float) ==========
template <int H>
__global__ __launch_bounds__(256) void k_redmax(const unsigned* __restrict__ in, int nblk,
                                                float* __restrict__ out)
{
    __shared__ unsigned sm[H];
    if (threadIdx.x < H) sm[threadIdx.x] = 0;
    __syncthreads();
    unsigned m[H];
#pragma unroll
    for (int h = 0; h < H; h++) m[h] = 0;
    for (int i = threadIdx.x; i < nblk; i += 256) {
#pragma unroll
        for (int h = 0; h < H; h++) m[h] = max(m[h], in[i * H + h]);
    }
#pragma unroll
    for (int h = 0; h < H; h++) atomicMax(&sm[h], m[h]);
    __syncthreads();
    if (threadIdx.x < H) out[threadIdx.x] = funflip(sm[threadIdx.x]);
}

// ---------------- GEMM1: h1(bf16) = x @ W1 (128->128), 4x4 blocking, + blkmax of as1 --
__global__ __launch_bounds__(256) void k_gemm1(
    const float* __restrict__ x, const float* __restrict__ W,
    const float* __restrict__ att_s, const float* __restrict__ att_d,
    ushort* __restrict__ h1, float* __restrict__ as1, float* __restrict__ ad1,
    unsigned* __restrict__ blkmax, int N)
{
    __shared__ __align__(16) float sW[16][128];   // 8 KB
    __shared__ __align__(16) float sX[32][16];    // 2 KB
    __shared__ unsigned smax[4];
    const int t  = threadIdx.x;
    const int c4 = t & 31;             // col group (cols c4*4 .. c4*4+3)
    const int rg = t >> 5;             // row group (rows rg*4 .. rg*4+3)
    const int row0 = blockIdx.x * 32;
    const float4* W4 = (const float4*)W;   // W row = 32 float4

    if (t < 4) smax[t] = 0;            // first loop barrier makes this visible

    float4 acc[4];
#pragma unroll
    for (int i = 0; i < 4; i++) acc[i] = {0.f, 0.f, 0.f, 0.f};

    for (int k0 = 0; k0 < 128; k0 += 16) {
        __syncthreads();
#pragma unroll
        for (int j = 0; j < 2; j++) {
            int idx = j * 256 + t;                 // 0..511
            int r = idx >> 5, cc = idx & 31;
            *(float4*)&sW[r][cc * 4] = W4[(k0 + r) * 32 + cc];
        }
        if (t < 128) {
            int r = t >> 2, q = t & 3;
            int row = row0 + r;
            float4 v = {0.f, 0.f, 0.f, 0.f};
            if (row < N) v = *(const float4*)&x[(long long)row * 128 + k0 + q * 4];
            *(float4*)&sX[r][q * 4] = v;
        }
        __syncthreads();
#pragma unroll
        for (int g = 0; g < 4; g++) {
            const int kk = g * 4;
            const float4 w0 = *(const float4*)&sW[kk + 0][c4 * 4];
            const float4 w1 = *(const float4*)&sW[kk + 1][c4 * 4];
            const float4 w2 = *(const float4*)&sW[kk + 2][c4 * 4];
            const float4 w3 = *(const float4*)&sW[kk + 3][c4 * 4];
#pragma unroll
            for (int i = 0; i < 4; i++) {
                const float4 xv = *(const float4*)&sX[rg * 4 + i][kk];  // broadcast
                acc[i].x = fmaf(xv.x, w0.x, acc[i].x);
                acc[i].y = fmaf(xv.x, w0.y, acc[i].y);
                acc[i].z = fmaf(xv.x, w0.z, acc[i].z);
                acc[i].w = fmaf(xv.x, w0.w, acc[i].w);
                acc[i].x = fmaf(xv.y, w1.x, acc[i].x);
                acc[i].y = fmaf(xv.y, w1.y, acc[i].y);
                acc[i].z = fmaf(xv.y, w1.z, acc[i].z);
                acc[i].w = fmaf(xv.y, w1.w, acc[i].w);
                acc[i].x = fmaf(xv.z, w2.x, acc[i].x);
                acc[i].y = fmaf(xv.z, w2.y, acc[i].y);
                acc[i].z = fmaf(xv.z, w2.z, acc[i].z);
                acc[i].w = fmaf(xv.z, w2.w, acc[i].w);
                acc[i].x = fmaf(xv.w, w3.x, acc[i].x);
                acc[i].y = fmaf(xv.w, w3.y, acc[i].y);
                acc[i].z = fmaf(xv.w, w3.z, acc[i].z);
                acc[i].w = fmaf(xv.w, w3.w, acc[i].w);
            }
        }
    }

    const float4 avs = *(const float4*)&att_s[c4 * 4];
    const float4 avd = *(const float4*)&att_d[c4 * 4];
    const int hd = c4 >> 3;                        // head of this thread's 4 cols
    float lmax = -INFINITY;
#pragma unroll
    for (int i = 0; i < 4; i++) {
        int row = row0 + rg * 4 + i;
        if (row < N) {
            ushort4 hb;
            hb.x = f2bf(acc[i].x); hb.y = f2bf(acc[i].y);
            hb.z = f2bf(acc[i].z); hb.w = f2bf(acc[i].w);
            *(ushort4*)&h1[(long long)row * 128 + c4 * 4] = hb;
            float s = acc[i].x * avs.x + acc[i].y * avs.y + acc[i].z * avs.z + acc[i].w * avs.w;
            float d = acc[i].x * avd.x + acc[i].y * avd.y + acc[i].z * avd.z + acc[i].w * avd.w;
#pragma unroll
            for (int off = 4; off > 0; off >>= 1) {    // reduce over 8 col-threads of head
                s += __shfl_xor(s, off, 64);
                d += __shfl_xor(d, off, 64);
            }
            if ((c4 & 7) == 0) {
                as1[row * 4 + hd] = s; ad1[row * 4 + hd] = d;
                lmax = fmaxf(lmax, s);
            }
        }
    }
    if ((c4 & 7) == 0) atomicMax(&smax[hd], fflip(lmax));
    __syncthreads();
    if (t < 4) blkmax[blockIdx.x * 4 + t] = smax[t];
}

// ---------------- GEMM2: h2 = elu(out1+b1) @ W2 (128->32), 4x4 blocking, + blkmax -----
__global__ __launch_bounds__(256) void k_gemm2(
    const float* __restrict__ xin, const float* __restrict__ W,
    const float* __restrict__ b1,
    const float* __restrict__ att_s, const float* __restrict__ att_d,
    float* __restrict__ h2, float* __restrict__ as2, float* __restrict__ ad2,
    unsigned* __restrict__ blkmax, int N)
{
    __shared__ __align__(16) float sW[16][32];    // 2 KB
    __shared__ __align__(16) float sX[128][16];   // 8 KB
    __shared__ unsigned smax1;
    const int t  = threadIdx.x;
    const int c4 = t & 7;              // col group (cols c4*4 .. c4*4+3)
    const int rg = t >> 3;             // row group (rows rg*4 .. rg*4+3)
    const int row0 = blockIdx.x * 128;
    const float4* W4 = (const float4*)W;          // W row = 8 float4

    if (t == 0) smax1 = 0;

    float4 acc[4];
#pragma unroll
    for (int i = 0; i < 4; i++) acc[i] = {0.f, 0.f, 0.f, 0.f};

    for (int k0 = 0; k0 < 128; k0 += 16) {
        __syncthreads();
        if (t < 128) {                 // stage W tile: 16x32 = 128 float4
            int r = t >> 3, cc = t & 7;
            *(float4*)&sW[r][cc * 4] = W4[(k0 + r) * 8 + cc];
        }
#pragma unroll
        for (int j = 0; j < 2; j++) {  // stage X tile: 128x16 = 512 float4
            int idx = j * 256 + t;
            int r = idx >> 2, q = idx & 3;
            int row = row0 + r;
            float4 v = {0.f, 0.f, 0.f, 0.f};
            if (row < N) {
                v = *(const float4*)&xin[(long long)row * 128 + k0 + q * 4];
                float4 b = *(const float4*)&b1[k0 + q * 4];
                v.x = elu1f(v.x + b.x); v.y = elu1f(v.y + b.y);
                v.z = elu1f(v.z + b.z); v.w = elu1f(v.w + b.w);
            }
            *(float4*)&sX[r][q * 4] = v;
        }
        __syncthreads();
#pragma unroll
        for (int g = 0; g < 4; g++) {
            const int kk = g * 4;
            const float4 w0 = *(const float4*)&sW[kk + 0][c4 * 4];
            const float4 w1 = *(const float4*)&sW[kk + 1][c4 * 4];
            const float4 w2 = *(const float4*)&sW[kk + 2][c4 * 4];
            const float4 w3 = *(const float4*)&sW[kk + 3][c4 * 4];
#pragma unroll
            for (int i = 0; i < 4; i++) {
                const float4 xv = *(const float4*)&sX[rg * 4 + i][kk];
                acc[i].x = fmaf(xv.x, w0.x, acc[i].x);
                acc[i].y = fmaf(xv.x, w0.y, acc[i].y);
                acc[i].z = fmaf(xv.x, w0.z, acc[i].z);
                acc[i].w = fmaf(xv.x, w0.w, acc[i].w);
                acc[i].x = fmaf(xv.y, w1.x, acc[i].x);
                acc[i].y = fmaf(xv.y, w1.y, acc[i].y);
                acc[i].z = fmaf(xv.y, w1.z, acc[i].z);
                acc[i].w = fmaf(xv.y, w1.w, acc[i].w);
                acc[i].x = fmaf(xv.z, w2.x, acc[i].x);
                acc[i].y = fmaf(xv.z, w2.y, acc[i].y);
                acc[i].z = fmaf(xv.z, w2.z, acc[i].z);
                acc[i].w = fmaf(xv.z, w2.w, acc[i].w);
                acc[i].x = fmaf(xv.w, w3.x, acc[i].x);
                acc[i].y = fmaf(xv.w, w3.y, acc[i].y);
                acc[i].z = fmaf(xv.w, w3.z, acc[i].z);
                acc[i].w = fmaf(xv.w, w3.w, acc[i].w);
            }
        }
    }

    const float4 avs = *(const float4*)&att_s[c4 * 4];
    const float4 avd = *(const float4*)&att_d[c4 * 4];
    float lmax = -INFINITY;
#pragma unroll
    for (int i = 0; i < 4; i++) {
        int row = row0 + rg * 4 + i;
        if (row < N) {
            *(float4*)&h2[(long long)row * 32 + c4 * 4] = acc[i];
            float s = acc[i].x * avs.x + acc[i].y * avs.y + acc[i].z * avs.z + acc[i].w * avs.w;
            float d = acc[i].x * avd.x + acc[i].y * avd.y + acc[i].z * avd.z + acc[i].w * avd.w;
#pragma unroll
            for (int off = 4; off > 0; off >>= 1) {    // reduce over 8 col-threads
                s += __shfl_xor(s, off, 64);
                d += __shfl_xor(d, off, 64);
            }
            if (c4 == 0) {
                as2[row] = s; ad2[row] = d;
                lmax = fmaxf(lmax, s);
            }
        }
    }
    if (c4 == 0) atomicMax(&smax1, fflip(lmax));
    __syncthreads();
    if (t == 0) blkmax[blockIdx.x] = smax1;
}

// ========== Fused GAT aggregation, layer 1 (H=4, C=32): one wave per dst ==========
__global__ __launch_bounds__(256) void k_agg1(
    const int* __restrict__ row, const int* __restrict__ esrc,
    const float* __restrict__ as, const float* __restrict__ ad,   // [N][4]
    const float* __restrict__ gmaxh,                              // [4]
    const ushort* __restrict__ h,                                 // [N][128] bf16
    float* __restrict__ out, int N)                               // [N][128]
{
    const int lane = threadIdx.x & 63;
    const int wid  = threadIdx.x >> 6;
    const int n = blockIdx.x * 4 + wid;
    if (n >= N) return;
    const int e0 = row[n], e1 = row[n + 1];

    const float4 ad4 = *(const float4*)&ad[n * 4];
    const int half = lane >> 5;
    const int l    = lane & 31;                 // 4 cols per lane: l*4..l*4+3
    const int hd   = l >> 3;                    // head of those cols
    const float adh = hd == 0 ? ad4.x : hd == 1 ? ad4.y : hd == 2 ? ad4.z : ad4.w;
    float mh = gmaxh[hd] + adh;
    mh = mh >= 0.f ? mh : NEG_SLOPE * mh;

    const unsigned lofs = (unsigned)(l * 4);
    float4 acc = {0.f, 0.f, 0.f, 0.f};
    float wsum = 0.f;
    for (int base = e0; base < e1; base += 8) {
        const int eA = base + half,     eB = base + 2 + half;
        const int eC = base + 4 + half, eD = base + 6 + half;
        const bool vA = eA < e1, vB = eB < e1, vC = eC < e1, vD = eD < e1;
        const int sA = vA ? esrc[eA] : 0;
        const int sB = vB ? esrc[eB] : 0;
        const int sC = vC ? esrc[eC] : 0;
        const int sD = vD ? esrc[eD] : 0;
        const float4 aA = *(const float4*)&as[sA * 4];
        const float4 aB = *(const float4*)&as[sB * 4];
        const float4 aC = *(const float4*)&as[sC * 4];
        const float4 aD = *(const float4*)&as[sD * 4];
        const ushort4 hA = *(const ushort4*)&h[(unsigned)sA * 128u + lofs];
        const ushort4 hB = *(const ushort4*)&h[(unsigned)sB * 128u + lofs];
        const ushort4 hC = *(const ushort4*)&h[(unsigned)sC * 128u + lofs];
        const ushort4 hD = *(const ushort4*)&h[(unsigned)sD * 128u + lofs];

        float evA = (hd == 0 ? aA.x : hd == 1 ? aA.y : hd == 2 ? aA.z : aA.w) + adh;
        evA = evA >= 0.f ? evA : NEG_SLOPE * evA;
        const float wA = vA ? __expf(evA - mh) : 0.f;
        float evB = (hd == 0 ? aB.x : hd == 1 ? aB.y : hd == 2 ? aB.z : aB.w) + adh;
        evB = evB >= 0.f ? evB : NEG_SLOPE * evB;
        const float wB = vB ? __expf(evB - mh) : 0.f;
        float evC = (hd == 0 ? aC.x : hd == 1 ? aC.y : hd == 2 ? aC.z : aC.w) + adh;
        evC = evC >= 0.f ? evC : NEG_SLOPE * evC;
        const float wC = vC ? __expf(evC - mh) : 0.f;
        float evD = (hd == 0 ? aD.x : hd == 1 ? aD.y : hd == 2 ? aD.z : aD.w) + adh;
        evD = evD >= 0.f ? evD : NEG_SLOPE * evD;
        const float wD = vD ? __expf(evD - mh) : 0.f;

        acc.x = fmaf(wA, bf2f(hA.x), acc.x);
        acc.y = fmaf(wA, bf2f(hA.y), acc.y);
        acc.z = fmaf(wA, bf2f(hA.z), acc.z);
        acc.w = fmaf(wA, bf2f(hA.w), acc.w);
        acc.x = fmaf(wB, bf2f(hB.x), acc.x);
        acc.y = fmaf(wB, bf2f(hB.y), acc.y);
        acc.z = fmaf(wB, bf2f(hB.z), acc.z);
        acc.w = fmaf(wB, bf2f(hB.w), acc.w);
        acc.x = fmaf(wC, bf2f(hC.x), acc.x);
        acc.y = fmaf(wC, bf2f(hC.y), acc.y);
        acc.z = fmaf(wC, bf2f(hC.z), acc.z);
        acc.w = fmaf(wC, bf2f(hC.w), acc.w);
        acc.x = fmaf(wD, bf2f(hD.x), acc.x);
        acc.y = fmaf(wD, bf2f(hD.y), acc.y);
        acc.z = fmaf(wD, bf2f(hD.z), acc.z);
        acc.w = fmaf(wD, bf2f(hD.w), acc.w);
        wsum += (wA + wB) + (wC + wD);
    }
    acc.x += __shfl_xor(acc.x, 32, 64);
    acc.y += __shfl_xor(acc.y, 32, 64);
    acc.z += __shfl_xor(acc.z, 32, 64);
    acc.w += __shfl_xor(acc.w, 32, 64);
    wsum  += __shfl_xor(wsum, 32, 64);

    if (half == 0) {
        const float inv = 1.f / (wsum + 1e-16f);
        float4 o; o.x = acc.x * inv; o.y = acc.y * inv; o.z = acc.z * inv; o.w = acc.w * inv;
        *(float4*)&out[(long long)n * 128 + l * 4] = o;
    }
}

// ========== Fused GAT aggregation, layer 2 (H=1, C=32): one wave per dst ==========
__global__ __launch_bounds__(256) void k_agg2(
    const int* __restrict__ row, const int* __restrict__ esrc,
    const float* __restrict__ as, const float* __restrict__ ad,   // [N]
    const float* __restrict__ gmax2,                              // [1]
    const float* __restrict__ h,                                  // [N][32]
    float* __restrict__ out, int N)                               // [N][32]
{
    const int lane = threadIdx.x & 63;
    const int wid  = threadIdx.x >> 6;
    const int n = blockIdx.x * 4 + wid;
    if (n >= N) return;
    const int e0 = row[n], e1 = row[n + 1];
    const float adv = ad[n];
    float m = gmax2[0] + adv;
    m = m >= 0.f ? m : NEG_SLOPE * m;

    const int g  = lane >> 3;                    // edge slot 0..7
    const int l8 = lane & 7;                     // 4 cols: l8*4..l8*4+3
    const unsigned lofs = (unsigned)(l8 * 4);
    float4 acc = {0.f, 0.f, 0.f, 0.f};
    float wsum = 0.f;
    for (int base = e0; base < e1; base += 32) {
        const int eA = base + g,      eB = base + 8 + g;
        const int eC = base + 16 + g, eD = base + 24 + g;
        const bool vA = eA < e1, vB = eB < e1, vC = eC < e1, vD = eD < e1;
        const int sA = vA ? esrc[eA] : 0;
        const int sB = vB ? esrc[eB] : 0;
        const int sC = vC ? esrc[eC] : 0;
        const int sD = vD ? esrc[eD] : 0;
        const float asA = as[sA], asB = as[sB], asC = as[sC], asD = as[sD];
        const float4 hA = *(const float4*)&h[(unsigned)sA * 32u + lofs];
        const float4 hB = *(const float4*)&h[(unsigned)sB * 32u + lofs];
        const float4 hC = *(const float4*)&h[(unsigned)sC * 32u + lofs];
        const float4 hD = *(const float4*)&h[(unsigned)sD * 32u + lofs];

        float evA = asA + adv; evA = evA >= 0.f ? evA : NEG_SLOPE * evA;
        const float wA = vA ? __expf(evA - m) : 0.f;
        float evB = asB + adv; evB = evB >= 0.f ? evB : NEG_SLOPE * evB;
        const float wB = vB ? __expf(evB - m) : 0.f;
        float evC = asC + adv; evC = evC >= 0.f ? evC : NEG_SLOPE * evC;
        const float wC = vC ? __expf(evC - m) : 0.f;
        float evD = asD + adv; evD = evD >= 0.f ? evD : NEG_SLOPE * evD;
        const float wD = vD ? __expf(evD - m) : 0.f;

        acc.x = fmaf(wA, hA.x, acc.x);
        acc.y = fmaf(wA, hA.y, acc.y);
        acc.z = fmaf(wA, hA.z, acc.z);
        acc.w = fmaf(wA, hA.w, acc.w);
        acc.x = fmaf(wB, hB.x, acc.x);
        acc.y = fmaf(wB, hB.y, acc.y);
        acc.z = fmaf(wB, hB.z, acc.z);
        acc.w = fmaf(wB, hB.w, acc.w);
        acc.x = fmaf(wC, hC.x, acc.x);
        acc.y = fmaf(wC, hC.y, acc.y);
        acc.z = fmaf(wC, hC.z, acc.z);
        acc.w = fmaf(wC, hC.w, acc.w);
        acc.x = fmaf(wD, hD.x, acc.x);
        acc.y = fmaf(wD, hD.y, acc.y);
        acc.z = fmaf(wD, hD.z, acc.z);
        acc.w = fmaf(wD, hD.w, acc.w);
        wsum += (wA + wB) + (wC + wD);
    }
#pragma unroll
    for (int off = 8; off < 64; off <<= 1) {
        acc.x += __shfl_xor(acc.x, off, 64);
        acc.y += __shfl_xor(acc.y, off, 64);
        acc.z += __shfl_xor(acc.z, off, 64);
        acc.w += __shfl_xor(acc.w, off, 64);
        wsum  += __shfl_xor(wsum, off, 64);
    }
    if (lane < 8) {
        const float inv = 1.f / (wsum + 1e-16f);
        float4 o; o.x = acc.x * inv; o.y = acc.y * inv; o.z = acc.z * inv; o.w = acc.w * inv;
        *(float4*)&out[(long long)n * 32 + lane * 4] = o;
    }
}

// ========== Gate MLP: full-grid parallel, one 32-lane group per node ==========
__global__ __launch_bounds__(256) void k_gate(
    const float* __restrict__ out2, const float* __restrict__ b2,
    const float* __restrict__ gw1, const float* __restrict__ gb1,
    const float* __restrict__ gw2, const float* __restrict__ gb2,
    float* __restrict__ gate, int N)
{
    const int c = threadIdx.x & 31, grp = threadIdx.x >> 5;
    const int n = blockIdx.x * 8 + grp;
    if (n >= N) return;
    float v = out2[(long long)n * 32 + c] + b2[c];
    v = elu1f(v);
    float t1 = gb1[c];
#pragma unroll
    for (int k = 0; k < 32; k++) {
        float hk = __shfl(v, k, 32);
        t1 = fmaf(hk, gw1[k * 32 + c], t1);
    }
    t1 = fmaxf(t1, 0.f);
    float gv = t1 * gw2[c];
#pragma unroll
    for (int off = 16; off > 0; off >>= 1) gv += __shfl_xor(gv, off, 32);
    if (c == 0) gate[n] = gv + gb2[0];
}

// ========== Pool stage 0: graph boundaries (batch is sorted) ==========
__global__ __launch_bounds__(128) void k_bounds(
    const int* __restrict__ batch, int* __restrict__ gbound, int N, int G)
{
    int t = threadIdx.x;
    if (t > G) return;
    int lo = 0, hi = N;
    while (lo < hi) { int mid = (lo + hi) >> 1; if (batch[mid] < t) lo = mid + 1; else hi = mid; }
    gbound[t] = lo;
}

// ========== Pool stage 1: per-chunk max -> atomicMax per block (8 chunks/graph) =====
__global__ __launch_bounds__(256) void k_gmax(
    const float* __restrict__ gate, const int* __restrict__ gbound,
    unsigned* __restrict__ gmax)
{
    const int g  = blockIdx.x >> 3;
    const int ch = blockIdx.x & 7;
    const int s0 = gbound[g], s1 = gbound[g + 1];
    const int len = s1 - s0;
    const int c0 = s0 + (int)(((long long)len * ch) >> 3);
    const int c1 = s0 + (int)(((long long)len * (ch + 1)) >> 3);

    __shared__ float sred[4];
    float m = -INFINITY;
    for (int n = c0 + threadIdx.x; n < c1; n += 256) m = fmaxf(m, gate[n]);
#pragma unroll
    for (int off = 32; off > 0; off >>= 1) m = fmaxf(m, __shfl_xor(m, off, 64));
    if ((threadIdx.x & 63) == 0) sred[threadIdx.x >> 6] = m;
    __syncthreads();
    if (threadIdx.x == 0) {
        m = fmaxf(fmaxf(sred[0], sred[1]), fmaxf(sred[2], sred[3]));
        atomicMax(&gmax[g], fflip(m));
    }
}

// ========== Pool stage 2: per-chunk partial weighted sums (no atomics) ==========
__global__ __launch_bounds__(256) void k_pool3(
    const float* __restrict__ out2, const float* __restrict__ b2,
    const float* __restrict__ gate, const int* __restrict__ gbound,
    const unsigned* __restrict__ gmax, float* __restrict__ partials)
{
    const int g  = blockIdx.x >> 3;
    const int ch = blockIdx.x & 7;
    const int s0 = gbound[g], s1 = gbound[g + 1];
    const int len = s1 - s0;
    const int c0 = s0 + (int)(((long long)len * ch) >> 3);
    const int c1 = s0 + (int)(((long long)len * (ch + 1)) >> 3);

    const int c   = threadIdx.x & 31;
    const int grp = threadIdx.x >> 5;
    const float gm = funflip(gmax[g]);
    const float bc = b2[c];

    __shared__ float sacc[8][32];
    __shared__ float swsum[8];

    float acc = 0.f, wsum = 0.f;
    for (int n = c0 + grp; n < c1; n += 8) {
        float v = elu1f(out2[(long long)n * 32 + c] + bc);
        float ge = __expf(gate[n] - gm);
        acc = fmaf(ge, v, acc);
        wsum += ge;
    }
    sacc[grp][c] = acc;
    if (c == 0) swsum[grp] = wsum;
    __syncthreads();

    if (grp == 0) {
        float a = 0.f, wtot = 0.f;
#pragma unroll
        for (int i = 0; i < 8; i++) { a += sacc[i][c]; wtot += swsum[i]; }
        partials[(long long)blockIdx.x * 33 + c] = a;
        if (c == 0) partials[(long long)blockIdx.x * 33 + 32] = wtot;
    }
}

// ========== Pool stage 3: reduce 8 partials per graph, divide, write out ==========
__global__ __launch_bounds__(256) void k_pool4(
    const float* __restrict__ partials, float* __restrict__ out)
{
    const int g   = blockIdx.x;
    const int c   = threadIdx.x & 31;
    const int p   = threadIdx.x >> 5;

    __shared__ float sacc[8][32];
    __shared__ float swsum[8];

    sacc[p][c] = partials[(long long)(g * 8 + p) * 33 + c];
    if (c == 0) swsum[p] = partials[(long long)(g * 8 + p) * 33 + 32];
    __syncthreads();

    if (p == 0) {
        float a = 0.f, wtot = 0.f;
#pragma unroll
        for (int i = 0; i < 8; i++) { a += sacc[i][c]; wtot += swsum[i]; }
        out[g * 32 + c] = a / (wtot + 1e-16f);
    }
}

extern "C" void kernel_launch(void* const* d_in, const int* in_sizes, int n_in,
                              void* d_out, int out_size, void* d_ws, size_t ws_size,
                              hipStream_t stream)
{
    const float* x    = (const float*)d_in[0];
    const int*   ei   = (const int*)d_in[1];
    const int*   batch= (const int*)d_in[2];
    const float* W1   = (const float*)d_in[3];
    const float* as1w = (const float*)d_in[4];
    const float* ad1w = (const float*)d_in[5];
    const float* b1   = (const float*)d_in[6];
    const float* W2   = (const float*)d_in[7];
    const float* as2w = (const float*)d_in[8];
    const float* ad2w = (const float*)d_in[9];
    const float* b2   = (const float*)d_in[10];
    const float* gw1  = (const float*)d_in[11];
    const float* gb1  = (const float*)d_in[12];
    const float* gw2  = (const float*)d_in[13];
    const float* gb2  = (const float*)d_in[14];

    const int N  = in_sizes[2];
    const int E  = in_sizes[1] / 2;
    const int Et = E + N;
    const int nb = (N + 255) / 256;
    const int G  = 64;
    const int nbk   = (N + BW - 1) >> BSH;   // 391 buckets (<=512)
    const int nchk  = (Et + 4095) / 4096;    // bucket-build chunks
    const int nblk1 = (N + 31) / 32;         // gemm1 blocks
    const int nblk2 = (N + 127) / 128;       // gemm2 blocks

    float* ws = (float*)d_ws;
    size_t o = 0;
    int2*  ebuk = (int2*)(ws + o); o += (size_t)Et * 2;    // 8B-aligned (o even)
    ushort* h1 = (ushort*)(ws + o); o += (size_t)N * 64;   // bf16 [N][128]
    float* out1 = ws + o; o += (size_t)N * 128;
    float* h2   = ws + o; o += (size_t)N * 32;
    float* out2 = ws + o; o += (size_t)N * 32;
    float* a_s1 = ws + o; o += (size_t)N * 4;
    float* a_d1 = ws + o; o += (size_t)N * 4;
    float* a_s2 = ws + o; o += (size_t)N;
    float* a_d2 = ws + o; o += (size_t)N;
    float* gate = ws + o; o += (size_t)N;
    int*   deg  = (int*)(ws + o); o += (size_t)N;          // fully written by k_bdeg
    int*   rowp = (int*)(ws + o); o += (size_t)N + 1;
    int*   esrc = (int*)(ws + o); o += (size_t)Et;
    int*   bsum = (int*)(ws + o); o += 256;
    int*   bbase= (int*)(ws + o); o += (size_t)nbk + 1;
    int*   bcur = (int*)(ws + o); o += (size_t)nbk;        // init by k_bscan
    int*   gbound = (int*)(ws + o); o += G + 1;
    float* partials = ws + o; o += (size_t)G * 8 * 33;
    unsigned* blkmax1 = (unsigned*)(ws + o); o += (size_t)nblk1 * 4;
    unsigned* blkmax2 = (unsigned*)(ws + o); o += (size_t)nblk2;
    float* gmaxh = ws + o; o += 4;
    float* gmax2 = ws + o; o += 4;
    // ---- zeroed region (one memset): bcnt + gmax ----
    size_t zstart = o;
    int*      bcnt = (int*)(ws + o); o += (size_t)nbk;
    unsigned* gmax = (unsigned*)(ws + o); o += G;
    size_t zbytes = (o - zstart) * sizeof(float);

    hipMemsetAsync(ws + zstart, 0, zbytes, stream);

    // ---- bucketed CSR build (shared by both layers) ----
    k_bcount  <<<nchk, 256, 0, stream>>>(ei, E, Et, nbk, bcnt);
    k_bscan   <<<1, 512, 0, stream>>>(bcnt, nbk, Et, bbase, bcur);
    k_bscatter<<<nchk, 256, 0, stream>>>(ei, E, Et, nbk, bcur, ebuk);
    k_bdeg    <<<nbk, 256, 0, stream>>>(ebuk, bbase, N, deg);
    k_scan1   <<<nb, 256, 0, stream>>>(deg, N, rowp, bsum);
    k_scan2   <<<1, 256, 0, stream>>>(bsum, nb);
    k_scan3   <<<nb, 256, 0, stream>>>(rowp, bsum, N, Et);
    k_fine    <<<nbk, 256, 0, stream>>>(ebuk, bbase, rowp, N, esrc);
    k_bounds  <<<1, 128, 0, stream>>>(batch, gbound, N, G);

    // ---- GAT layer 1 ----
    k_gemm1<<<nblk1, 256, 0, stream>>>(x, W1, as1w, ad1w, h1, a_s1, a_d1, blkmax1, N);
    k_redmax<4><<<1, 256, 0, stream>>>(blkmax1, nblk1, gmaxh);
    k_agg1 <<<(N + 3) / 4, 256, 0, stream>>>(rowp, esrc, a_s1, a_d1, gmaxh, h1, out1, N);

    // ---- GAT layer 2 (elu(out1+b1) fused into gemm2 load) ----
    k_gemm2<<<nblk2, 256, 0, stream>>>(out1, W2, b1, as2w, ad2w, h2, a_s2, a_d2, blkmax2, N);
    k_redmax<1><<<1, 256, 0, stream>>>(blkmax2, nblk2, gmax2);
    k_agg2 <<<(N + 3) / 4, 256, 0, stream>>>(rowp, esrc, a_s2, a_d2, gmax2, h2, out2, N);

    // ---- attentional pooling: gate, chunked max, partial sums, final reduce ----
    k_gate <<<(N + 7) / 8, 256, 0, stream>>>(out2, b2, gw1, gb1, gw2, gb2, gate, N);
    k_gmax <<<G * 8, 256, 0, stream>>>(gate, gbound, gmax);
    k_pool3<<<G * 8, 256, 0, stream>>>(out2, b2, gate, gbound, gmax, partials);
    k_pool4<<<G, 256, 0, stream>>>(partials, (float*)d_out);
}